// Round 6
// baseline (3007.825 us; speedup 1.0000x reference)
//
#include <hip/hip_runtime.h>
#include <hip/hip_bf16.h>
#include <hip/hip_fp16.h>

// Problem constants
#define N_PTS_IN   20000
#define CAP0C      540000
#define CAP1C      352000
#define ZD 10
#define YD 200
#define XD 704
#define Z1D 5
#define Y1D 100
#define X1D 352
#define HWOUT (YD*XD)   // 140800

typedef _Float16 f16x8 __attribute__((ext_vector_type(8)));
typedef float    f32x4 __attribute__((ext_vector_type(4)));

// ---------------------------------------------------------------------------
// f_in = sp_feats @ w_in   (20000x64 @ 64x32), f16 output rows
__global__ __launch_bounds__(256) void gemm_in(const float* __restrict__ sp,
                                               const float* __restrict__ w,
                                               __half* __restrict__ fout) {
    int tid = blockIdx.x * 256 + threadIdx.x;
    int row = tid >> 3;
    int c4  = (tid & 7) * 4;
    if (row >= N_PTS_IN) return;
    float4 acc = {0.f, 0.f, 0.f, 0.f};
    const float* sr = sp + (size_t)row * 64;
#pragma unroll
    for (int ci = 0; ci < 64; ci += 4) {
        float4 fv = *(const float4*)(sr + ci);
        const float* wp = w + ci * 32 + c4;
        float4 w0 = *(const float4*)(wp);
        float4 w1 = *(const float4*)(wp + 32);
        float4 w2 = *(const float4*)(wp + 64);
        float4 w3 = *(const float4*)(wp + 96);
        acc.x += fv.x*w0.x + fv.y*w1.x + fv.z*w2.x + fv.w*w3.x;
        acc.y += fv.x*w0.y + fv.y*w1.y + fv.z*w2.y + fv.w*w3.y;
        acc.z += fv.x*w0.z + fv.y*w1.z + fv.z*w2.z + fv.w*w3.z;
        acc.w += fv.x*w0.w + fv.y*w1.w + fv.z*w2.w + fv.w*w3.w;
    }
    __half* fo = fout + (size_t)row * 32 + c4;
    fo[0] = __float2half(acc.x);
    fo[1] = __float2half(acc.y);
    fo[2] = __float2half(acc.z);
    fo[3] = __float2half(acc.w);
}

// ---------------------------------------------------------------------------
// Weight convert+transpose: src f32 [27][CIN][COUT] -> dst f16 [27][COUT][CIN]
__global__ __launch_bounds__(256) void cvt_w(const float* __restrict__ src,
                                             __half* __restrict__ dst,
                                             int CIN, int COUT) {
    int i = blockIdx.x * 256 + threadIdx.x;
    if (i >= 27 * CIN * COUT) return;
    int ci = i % CIN;
    int t  = i / CIN;
    int co = t % COUT;
    int k  = t / COUT;
    dst[i] = __float2half(src[((size_t)k * CIN + ci) * COUT + co]);
}

// ct0_w f32 [320][64] (ci=c*10+z) -> f16 [co][zc=z*32+c]
__global__ __launch_bounds__(256) void cvt_ct0(const float* __restrict__ src,
                                               __half* __restrict__ dst) {
    int i = blockIdx.x * 256 + threadIdx.x;
    if (i >= 64 * 320) return;
    int zc = i % 320, co = i / 320;
    int z = zc >> 5, c = zc & 31;
    dst[i] = __float2half(src[(c * 10 + z) * 64 + co]);
}

// ct1_w f32 [320][64][2][2] (ci=c*5+z) -> f16 [kq][co][zc=z*64+c]
__global__ __launch_bounds__(256) void cvt_ct1(const float* __restrict__ src,
                                               __half* __restrict__ dst) {
    int i = blockIdx.x * 256 + threadIdx.x;
    if (i >= 4 * 64 * 320) return;
    int zc = i % 320;
    int t  = i / 320;
    int co = t & 63;
    int kq = t >> 6;
    int z = zc >> 6, c = zc & 63;
    dst[i] = __float2half(src[((c * 5 + z) * 64 + co) * 4 + kq]);
}

// ---------------------------------------------------------------------------
// Rulebook inversion, TRANSPOSED: nbrT[k*cap + s] = g.
// v12: also computes n_act = max(sv)+1 (active rows are exactly [0,n_act))
// via wave-reduce + one atomicMax per wave.
__global__ __launch_bounds__(256) void build_nbr(const int* __restrict__ g,
                                                 const int* __restrict__ s,
                                                 int* __restrict__ nbrT,
                                                 int P, int cap,
                                                 int* __restrict__ nA) {
    int i = blockIdx.x * 256 + threadIdx.x;
    int v = 0;
    if (i < 27 * P) {
        int k = i / P, p = i - k * P;
        int sv = s[(size_t)k * P + p];
        if (sv < cap) {                 // real pair
            nbrT[(size_t)k * cap + sv] = g[(size_t)k * P + p];
            v = sv + 1;
        }
    }
#pragma unroll
    for (int o = 32; o > 0; o >>= 1)
        v = max(v, __shfl_xor(v, o));
    if ((threadIdx.x & 63) == 0 && v > 0) atomicMax(nA, v);
}

// voxel -> sparse-row index (pad coords have z == Zdim, dropped like JAX OOB)
__global__ __launch_bounds__(256) void build_vox(const int* __restrict__ coords,
                                                 int* __restrict__ v2r,
                                                 int cap, int Zdim, int Ydim, int Xdim) {
    int r = blockIdx.x * 256 + threadIdx.x;
    if (r >= cap) return;
    int b = coords[4*r], z = coords[4*r+1], y = coords[4*r+2], x = coords[4*r+3];
    if (z >= Zdim) return;
    v2r[(((size_t)b * Zdim + z) * Ydim + y) * Xdim + x] = r;
}

// ---------------------------------------------------------------------------
// Implicit-GEMM sparse conv via f16 MFMA 16x16x32, + BN + ReLU.
// v12 = v11 (weights-via-LDS, TA relief: 360->137us confirmed) + dead-block
// early exit:
//   - active output rows are exactly [0, n_act); blocks with sb*128 >= n_act
//     have no rulebook entries for ANY k (48% of blocks at level 1 per
//     WRITE_SIZE arithmetic) yet previously ran the full 27-iter staging
//     loop. Now: one scalar compare, uniform return (no barrier divergence).
//   - XCD swizzle REPLACED: the contiguous-chunk form would put the live
//     prefix [0,L) entirely on XCDs 0..3. New 64-block interleaved groups:
//     each XCD gets 8 consecutive tiles per supergroup (bijective, identity
//     tail), live work spread across all 8 XCDs at any L.
template <int CIN, int COUT>
__global__ __launch_bounds__(256) void spconv_reg(const __half* __restrict__ f,
                                                  const __half* __restrict__ wt,
                                                  const float* __restrict__ bnp,
                                                  const int* __restrict__ nbrT,
                                                  __half* __restrict__ fout,
                                                  int ncap,
                                                  const int* __restrict__ nA) {
    constexpr int NT = COUT / 16;       // 16-col output tiles
    constexpr int KT = CIN / 32;        // K=32 MFMA steps per k-offset
    constexpr int NCHUNK = CIN / 8;     // 16B chunks per weight row
    constexpr int MASK = NCHUNK - 1;
    constexpr int LCH  = (NCHUNK == 8) ? 3 : 2;
    constexpr int TILE_H = COUT * CIN;  // halves per weight tile
    constexpr int TB = TILE_H * 2 / 256; // stage bytes per thread (8/16/32)
    constexpr int OST_H = 4 * 32 * COUT;
    constexpr int SH_H = (2 * TILE_H > OST_H) ? 2 * TILE_H : OST_H;
    __shared__ __align__(16) __half S[SH_H];

    int tid = threadIdx.x;
    int wv = tid >> 6, lane = tid & 63;
    int quad = lane >> 4, l16 = lane & 15;

    // interleaved-group XCD swizzle (live-prefix-safe, bijective)
    int bid = blockIdx.x;
    int nfull = (int)gridDim.x & ~63;
    int sb;
    if (bid < nfull) {
        int grp = bid >> 6, w = bid & 63;
        sb = grp * 64 + (w & 7) * 8 + (w >> 3);
    } else {
        sb = bid;
    }

    // dead-block early exit: rows >= n_act have no pairs for any k
    if (sb * 128 >= *nA) return;

    int m0 = sb * 128 + wv * 32;       // wave's first output row
    int r0 = m0 + l16;                 // this lane's row for m=0
    int r1 = m0 + 16 + l16;            // this lane's row for m=1
    bool ok0 = r0 < ncap, ok1 = r1 < ncap;

    f32x4 acc[2][NT] = {};

    // index pipeline depth 2
    int gC0 = ok0 ? nbrT[r0] : -1;
    int gC1 = ok1 ? nbrT[r1] : -1;
    int gN0 = ok0 ? nbrT[(size_t)ncap + r0] : -1;
    int gN1 = ok1 ? nbrT[(size_t)ncap + r1] : -1;
    bool ever = false;

    // ---- prologue: stage weight tile k=0 into buffer 0 ----
    {
        const char* src = (const char*)(wt) + tid * TB;
        if constexpr (TB == 32) {
            uint4 w0 = *(const uint4*)src;
            uint4 w1 = *(const uint4*)(src + 16);
            int p0 = tid * 2;
#pragma unroll
            for (int j = 0; j < 2; ++j) {
                int p = p0 + j;
                int row = p >> LCH, c = p & MASK;
                *(uint4*)(S + (row * NCHUNK + (c ^ (row & MASK))) * 8) = (j ? w1 : w0);
            }
        } else if constexpr (TB == 16) {
            uint4 w0 = *(const uint4*)src;
            int p = tid;
            int row = p >> LCH, c = p & MASK;
            *(uint4*)(S + (row * NCHUNK + (c ^ (row & MASK))) * 8) = w0;
        } else {
            uint2 w0 = *(const uint2*)src;
            int p = tid >> 1, half = tid & 1;
            int row = p >> LCH, c = p & MASK;
            *(uint2*)(S + (row * NCHUNK + (c ^ (row & MASK))) * 8 + half * 4) = w0;
        }
    }
    __syncthreads();

#pragma unroll 1
    for (int k = 0; k < 27; ++k) {
        // (1) idx k+2 (oldest in-flight: retired before barrier drain)
        int gNN0 = -1, gNN1 = -1;
        if (k + 2 < 27) {
            if (ok0) gNN0 = nbrT[(size_t)(k + 2) * ncap + r0];
            if (ok1) gNN1 = nbrT[(size_t)(k + 2) * ncap + r1];
        }
        // (2) gathers k -> regs
        bool anyC = __ballot((gC0 >= 0) || (gC1 >= 0)) != 0ull;
        f16x8 a0[KT], a1[KT];
        if (anyC) {
            const __half* p0 = f + (size_t)((gC0 < 0) ? 0 : gC0) * CIN + quad * 8;
            const __half* p1 = f + (size_t)((gC1 < 0) ? 0 : gC1) * CIN + quad * 8;
#pragma unroll
            for (int kt = 0; kt < KT; ++kt) {
                uint4 u0 = {0u,0u,0u,0u}, u1 = {0u,0u,0u,0u};
                if (gC0 >= 0) u0 = *(const uint4*)(p0 + kt * 32);
                if (gC1 >= 0) u1 = *(const uint4*)(p1 + kt * 32);
                a0[kt] = *(f16x8*)&u0;
                a1[kt] = *(f16x8*)&u1;
            }
        }
        // (3) stage loads for k+1 -> regs (youngest: stays in flight
        //     across the MFMA's gather-wait)
        bool doStage = (k + 1 < 27);
        uint4 w0{}, w1{}; uint2 w2{};
        if (doStage) {
            const char* src = (const char*)(wt + (size_t)(k + 1) * TILE_H) + tid * TB;
            if constexpr (TB == 32)      { w0 = *(const uint4*)src; w1 = *(const uint4*)(src + 16); }
            else if constexpr (TB == 16) { w0 = *(const uint4*)src; }
            else                         { w2 = *(const uint2*)src; }
        }
        // (4) ds_read B + (5) MFMA
        if (anyC) {
            ever = true;
            const __half* Wb = S + (k & 1) * TILE_H;
#pragma unroll
            for (int kt = 0; kt < KT; ++kt) {
#pragma unroll
                for (int nt = 0; nt < NT; ++nt) {
                    int row = nt * 16 + l16;
                    int c   = kt * 4 + quad;
                    f16x8 b = *(const f16x8*)(Wb + (row * NCHUNK + (c ^ (row & MASK))) * 8);
                    acc[0][nt] = __builtin_amdgcn_mfma_f32_16x16x32_f16(a0[kt], b, acc[0][nt], 0, 0, 0);
                    acc[1][nt] = __builtin_amdgcn_mfma_f32_16x16x32_f16(a1[kt], b, acc[1][nt], 0, 0, 0);
                }
            }
        }
        // (6) ds_write staging into the other buffer
        if (doStage) {
            __half* dst = S + ((k + 1) & 1) * TILE_H;
            if constexpr (TB == 32) {
                int p0 = tid * 2;
#pragma unroll
                for (int j = 0; j < 2; ++j) {
                    int p = p0 + j;
                    int row = p >> LCH, c = p & MASK;
                    *(uint4*)(dst + (row * NCHUNK + (c ^ (row & MASK))) * 8) = (j ? w1 : w0);
                }
            } else if constexpr (TB == 16) {
                int p = tid;
                int row = p >> LCH, c = p & MASK;
                *(uint4*)(dst + (row * NCHUNK + (c ^ (row & MASK))) * 8) = w0;
            } else {
                int p = tid >> 1, half = tid & 1;
                int row = p >> LCH, c = p & MASK;
                *(uint2*)(dst + (row * NCHUNK + (c ^ (row & MASK))) * 8 + half * 4) = w2;
            }
        }
        __syncthreads();
        gC0 = gN0; gC1 = gN1; gN0 = gNN0; gN1 = gNN1;
    }

    // epilogue: BN + ReLU -> wave-private LDS (weight bufs dead) -> store.
    if (!ever) return;
    __half* O = S + wv * (32 * COUT);
#pragma unroll
    for (int nt = 0; nt < NT; ++nt) {
        int co = nt * 16 + l16;
        float g = bnp[co], b = bnp[COUT + co];
        float mn = bnp[2*COUT + co], vv = bnp[3*COUT + co];
        float s  = g * rsqrtf(vv + 1e-5f);
        float sh = b - mn * s;
#pragma unroll
        for (int m = 0; m < 2; ++m)
#pragma unroll
            for (int r_ = 0; r_ < 4; ++r_) {
                int row = m * 16 + quad * 4 + r_;
                O[row * COUT + co] = __float2half(fmaxf(acc[m][nt][r_] * s + sh, 0.f));
            }
    }
    constexpr int OCH = COUT / 8;              // 16B chunks per out row
#pragma unroll
    for (int j = 0; j < 32 * OCH / 64; ++j) {
        int idx = j * 64 + lane;
        int r = idx / OCH, c = idx % OCH;
        if (m0 + r < ncap)
            *(uint4*)(fout + (size_t)(m0 + r) * COUT + c * 8) =
                *(const uint4*)(O + r * COUT + c * 8);
    }
}

// ---------------------------------------------------------------------------
// BEV head 0: fused gather + GEMM [64rows x 320] @ [320 x 64] via f16 MFMA,
// + BN + ReLU + 2-agent attention + coalesced store.
__global__ __launch_bounds__(256) void bev0_mfma(const __half* __restrict__ f0,
                                                 const __half* __restrict__ wtT,  // [64][320] zc=z*32+c
                                                 const float* __restrict__ bias,
                                                 const float* __restrict__ bnp,
                                                 const int* __restrict__ v2r,
                                                 float* __restrict__ out) {
    constexpr int AST = 328;
    __shared__ __align__(16) __half Al[64 * AST];   // 41,984 B
    __shared__ float Cl[64][65];                     // wave-private rows
    __shared__ float Ot[64][33];
    int tid = threadIdx.x;
    int y = blockIdx.x / 22, x0 = (blockIdx.x % 22) * 32;
    int wv = tid >> 6, lane = tid & 63;
    int quad = lane >> 4, l16 = lane & 15;

    for (int it = 0; it < 3; ++it) {
        int task = it * 256 + tid;
        if (task < 640) {
            int row = task & 63, z = task >> 6;
            int b = row & 1, p = row >> 1;
            int r = v2r[((b * ZD + z) * YD + y) * XD + x0 + p];
            uint4 v0 = {0,0,0,0}, v1 = {0,0,0,0}, v2 = {0,0,0,0}, v3 = {0,0,0,0};
            if (r >= 0) {
                const uint4* src = (const uint4*)(f0 + (size_t)r * 32);
                v0 = src[0]; v1 = src[1]; v2 = src[2]; v3 = src[3];
            }
            uint4* dst = (uint4*)(Al + row * AST + z * 32);
            dst[0] = v0; dst[1] = v1; dst[2] = v2; dst[3] = v3;
        }
    }
    __syncthreads();

    f32x4 acc[4] = {};
#pragma unroll
    for (int ks = 0; ks < 10; ++ks) {
        f16x8 a = *(const f16x8*)(Al + (wv * 16 + l16) * AST + ks * 32 + quad * 8);
#pragma unroll
        for (int nt = 0; nt < 4; ++nt) {
            f16x8 bfr = *(const f16x8*)(wtT + (size_t)(nt * 16 + l16) * 320 + ks * 32 + quad * 8);
            acc[nt] = __builtin_amdgcn_mfma_f32_16x16x32_f16(a, bfr, acc[nt], 0, 0, 0);
        }
    }
#pragma unroll
    for (int nt = 0; nt < 4; ++nt) {
        int co = nt * 16 + l16;
        float s  = bnp[co] * rsqrtf(bnp[192 + co] + 1e-5f);
        float sh = (bias[co] - bnp[128 + co]) * s + bnp[64 + co];
#pragma unroll
        for (int r_ = 0; r_ < 4; ++r_)
            Cl[wv * 16 + quad * 4 + r_][co] = fmaxf(acc[nt][r_] * s + sh, 0.f);
    }
#pragma unroll
    for (int pi = 0; pi < 8; ++pi) {
        int p = wv * 8 + pi;
        float x0v = Cl[2 * p][lane], x1v = Cl[2 * p + 1][lane];
        float s00 = x0v * x0v, s01 = x0v * x1v;
#pragma unroll
        for (int o = 32; o > 0; o >>= 1) {
            s00 += __shfl_xor(s00, o);
            s01 += __shfl_xor(s01, o);
        }
        float a0 = s00 * 0.125f, a1 = s01 * 0.125f;
        float mx = fmaxf(a0, a1);
        float e0 = expf(a0 - mx), e1 = expf(a1 - mx);
        float inv = 1.f / (e0 + e1);
        Ot[lane][p] = (e0 * x0v + e1 * x1v) * inv;
    }
    __syncthreads();
#pragma unroll
    for (int i = 0; i < 8; ++i) {
        int idx = i * 256 + tid;
        int co = idx >> 5, px = idx & 31;
        out[(size_t)co * HWOUT + (size_t)y * XD + x0 + px] = Ot[co][px];
    }
}

// ---------------------------------------------------------------------------
// BEV head 1: fused gather + 4x (GEMM [64x320]@[320x64]) for the 2x2 s2 convT
// kernel positions + BN + ReLU + attention + coalesced store.
__global__ __launch_bounds__(256) void bev1_mfma(const __half* __restrict__ f1,
                                                 const __half* __restrict__ wtT,  // [4][64][320] zc=z*64+c
                                                 const float* __restrict__ bias,
                                                 const float* __restrict__ bnp,
                                                 const int* __restrict__ v2r,
                                                 float* __restrict__ out) {
    constexpr int AST = 328;
    __shared__ __align__(16) __half Al[64 * AST];
    __shared__ float Cl[64][65];
    __shared__ float Ot[64][65];
    int tid = threadIdx.x;
    int iy = blockIdx.x / 11, j0 = (blockIdx.x % 11) * 32;
    int wv = tid >> 6, lane = tid & 63;
    int quad = lane >> 4, l16 = lane & 15;

    for (int it = 0; it < 3; ++it) {
        int task = it * 256 + tid;
        if (task < 640) {
            int row = task & 63, zh = task >> 6;   // 0..9
            int z = zh >> 1, hf = zh & 1;
            int b = row & 1, p = row >> 1;
            int r = v2r[((b * Z1D + z) * Y1D + iy) * X1D + j0 + p];
            uint4 v0 = {0,0,0,0}, v1 = {0,0,0,0}, v2 = {0,0,0,0}, v3 = {0,0,0,0};
            if (r >= 0) {
                const uint4* src = (const uint4*)(f1 + (size_t)r * 64 + hf * 32);
                v0 = src[0]; v1 = src[1]; v2 = src[2]; v3 = src[3];
            }
            uint4* dst = (uint4*)(Al + row * AST + z * 64 + hf * 32);
            dst[0] = v0; dst[1] = v1; dst[2] = v2; dst[3] = v3;
        }
    }
    __syncthreads();

#pragma unroll 1
    for (int ky = 0; ky < 2; ++ky) {
#pragma unroll 1
        for (int kx = 0; kx < 2; ++kx) {
            const __half* wk = wtT + (size_t)(ky * 2 + kx) * 64 * 320;
            f32x4 acc[4] = {};
#pragma unroll
            for (int ks = 0; ks < 10; ++ks) {
                f16x8 a = *(const f16x8*)(Al + (wv * 16 + l16) * AST + ks * 32 + quad * 8);
#pragma unroll
                for (int nt = 0; nt < 4; ++nt) {
                    f16x8 bfr = *(const f16x8*)(wk + (size_t)(nt * 16 + l16) * 320 + ks * 32 + quad * 8);
                    acc[nt] = __builtin_amdgcn_mfma_f32_16x16x32_f16(a, bfr, acc[nt], 0, 0, 0);
                }
            }
#pragma unroll
            for (int nt = 0; nt < 4; ++nt) {
                int co = nt * 16 + l16;
                float s  = bnp[co] * rsqrtf(bnp[192 + co] + 1e-5f);
                float sh = (bias[co] - bnp[128 + co]) * s + bnp[64 + co];
#pragma unroll
                for (int r_ = 0; r_ < 4; ++r_)
                    Cl[wv * 16 + quad * 4 + r_][co] = fmaxf(acc[nt][r_] * s + sh, 0.f);
            }
#pragma unroll
            for (int pi = 0; pi < 8; ++pi) {
                int p = wv * 8 + pi;
                float x0v = Cl[2 * p][lane], x1v = Cl[2 * p + 1][lane];
                float s00 = x0v * x0v, s01 = x0v * x1v;
#pragma unroll
                for (int o = 32; o > 0; o >>= 1) {
                    s00 += __shfl_xor(s00, o);
                    s01 += __shfl_xor(s01, o);
                }
                float a0 = s00 * 0.125f, a1 = s01 * 0.125f;
                float mx = fmaxf(a0, a1);
                float e0 = expf(a0 - mx), e1 = expf(a1 - mx);
                float inv = 1.f / (e0 + e1);
                Ot[lane][2 * p + kx] = (e0 * x0v + e1 * x1v) * inv;
            }
        }
        __syncthreads();
        int yo = 2 * iy + ky;
#pragma unroll
        for (int i = 0; i < 16; ++i) {
            int idx = i * 256 + tid;
            int co = idx >> 6, xx = idx & 63;
            out[(size_t)co * HWOUT + (size_t)yo * XD + 2 * j0 + xx] = Ot[co][xx];
        }
        __syncthreads();
    }
}

// ---------------------------------------------------------------------------
extern "C" void kernel_launch(void* const* d_in, const int* in_sizes, int n_in,
                              void* d_out, int out_size, void* d_ws, size_t ws_size,
                              hipStream_t stream) {
    const float* sp    = (const float*)d_in[0];
    const float* w_in  = (const float*)d_in[1];
    const float* w0    = (const float*)d_in[2];
    const float* bnp0  = (const float*)d_in[3];
    const float* w0a   = (const float*)d_in[4];
    const float* bnp0a = (const float*)d_in[5];
    const float* w0b   = (const float*)d_in[6];
    const float* bnp0b = (const float*)d_in[7];
    const float* w1    = (const float*)d_in[8];
    const float* bnp1  = (const float*)d_in[9];
    const float* w1a   = (const float*)d_in[10];
    const float* bnp1a = (const float*)d_in[11];
    const float* w1b   = (const float*)d_in[12];
    const float* bnp1b = (const float*)d_in[13];
    const float* ct0w  = (const float*)d_in[14];
    const float* ct0b  = (const float*)d_in[15];
    const float* bnt0  = (const float*)d_in[16];
    const float* ct1w  = (const float*)d_in[17];
    const float* ct1b  = (const float*)d_in[18];
    const float* bnt1  = (const float*)d_in[19];
    const int* coords0 = (const int*)d_in[20];
    const int* coords1 = (const int*)d_in[21];
    const int* g0 = (const int*)d_in[22];
    const int* s0 = (const int*)d_in[23];
    const int* ga = (const int*)d_in[24];
    const int* sa = (const int*)d_in[25];
    const int* g1 = (const int*)d_in[26];
    const int* s1 = (const int*)d_in[27];
    const int* gb = (const int*)d_in[28];
    const int* sb = (const int*)d_in[29];
    float* out = (float*)d_out;

    // -------- workspace carve --------
    __half* fInH = (__half*)d_ws;
    __half* R1h  = fInH + 640000;
    __half* R2h  = R1h + 22528000;
    __half* wt0  = R2h + 22528000;
    __half* wt0a = wt0  + 27648;
    __half* wt0b = wt0a + 27648;
    __half* wt1  = wt0b + 27648;          // [27][64][32]
    __half* wt1a = wt1  + 55296;          // [27][64][64]
    __half* wt1b = wt1a + 110592;
    __half* wtT0 = wt1b + 110592;         // [64][320]
    __half* wtT1 = wtT0 + 20480;          // [4][64][320]
    int*   nbrT = (int*)(wtT1 + 81920);   // 27*CAP0C ints = 14,580,000
    int*   v2r0 = nbrT;                          // 2,816,000 ints (aliases)
    int*   v2r1 = nbrT + 2816000;                //   352,000 ints (aliases)
    int*   nAct = nbrT + 14580000;               // 4 ints, beyond nbrT region

    // 0) weight conversion + n_act reset
    hipMemsetAsync(nAct, 0, 16, stream);
    cvt_w<<<(27*32*32 + 255) / 256, 256, 0, stream>>>(w0,  wt0,  32, 32);
    cvt_w<<<(27*32*32 + 255) / 256, 256, 0, stream>>>(w0a, wt0a, 32, 32);
    cvt_w<<<(27*32*32 + 255) / 256, 256, 0, stream>>>(w0b, wt0b, 32, 32);
    cvt_w<<<(27*32*64 + 255) / 256, 256, 0, stream>>>(w1,  wt1,  32, 64);
    cvt_w<<<(27*64*64 + 255) / 256, 256, 0, stream>>>(w1a, wt1a, 64, 64);
    cvt_w<<<(27*64*64 + 255) / 256, 256, 0, stream>>>(w1b, wt1b, 64, 64);
    cvt_ct0<<<(64*320 + 255) / 256, 256, 0, stream>>>(ct0w, wtT0);
    cvt_ct1<<<(4*64*320 + 255) / 256, 256, 0, stream>>>(ct1w, wtT1);

    // 1) input channel lift (f16 rows out)
    gemm_in<<<(N_PTS_IN * 8 + 255) / 256, 256, 0, stream>>>(sp, w_in, fInH);

    // 2) conv0 (stride-1 spconv, 32->32): fInH -> R1h
    hipMemsetAsync(nbrT, 0xFF, (size_t)CAP0C * 27 * 4, stream);
    build_nbr<<<(27 * N_PTS_IN + 255) / 256, 256, 0, stream>>>(g0, s0, nbrT, N_PTS_IN, CAP0C, nAct + 0);
    spconv_reg<32, 32><<<(CAP0C + 127) / 128, 256, 0, stream>>>(fInH, wt0, bnp0, nbrT, R1h, CAP0C, nAct + 0);

    // 3) subm a/b (32->32), shared rulebook: R1h -> R2h -> R1h
    hipMemsetAsync(nbrT, 0xFF, (size_t)CAP0C * 27 * 4, stream);
    build_nbr<<<(27 * CAP0C + 255) / 256, 256, 0, stream>>>(ga, sa, nbrT, CAP0C, CAP0C, nAct + 1);
    spconv_reg<32, 32><<<(CAP0C + 127) / 128, 256, 0, stream>>>(R1h, wt0a, bnp0a, nbrT, R2h, CAP0C, nAct + 1);
    spconv_reg<32, 32><<<(CAP0C + 127) / 128, 256, 0, stream>>>(R2h, wt0b, bnp0b, nbrT, R1h, CAP0C, nAct + 1);

    // 4) BEV head 0 (reads R1h) -> out channels [0,64)
    hipMemsetAsync(v2r0, 0xFF, (size_t)2816000 * 4, stream);
    build_vox<<<(CAP0C + 255) / 256, 256, 0, stream>>>(coords0, v2r0, CAP0C, ZD, YD, XD);
    bev0_mfma<<<YD * 22, 256, 0, stream>>>(R1h, wtT0, ct0b, bnt0, v2r0, out);

    // 5) conv1 (stride-2 spconv, 32->64): R1h -> R2h
    hipMemsetAsync(nbrT, 0xFF, (size_t)CAP1C * 27 * 4, stream);
    build_nbr<<<(27 * CAP0C + 255) / 256, 256, 0, stream>>>(g1, s1, nbrT, CAP0C, CAP1C, nAct + 2);
    spconv_reg<32, 64><<<(CAP1C + 127) / 128, 256, 0, stream>>>(R1h, wt1, bnp1, nbrT, R2h, CAP1C, nAct + 2);

    // 6) subm 1a/1b (64->64), shared rulebook: R2h -> R1h -> R2h
    hipMemsetAsync(nbrT, 0xFF, (size_t)CAP1C * 27 * 4, stream);
    build_nbr<<<(27 * CAP1C + 255) / 256, 256, 0, stream>>>(gb, sb, nbrT, CAP1C, CAP1C, nAct + 3);
    spconv_reg<64, 64><<<(CAP1C + 127) / 128, 256, 0, stream>>>(R2h, wt1a, bnp1a, nbrT, R1h, CAP1C, nAct + 3);
    spconv_reg<64, 64><<<(CAP1C + 127) / 128, 256, 0, stream>>>(R1h, wt1b, bnp1b, nbrT, R2h, CAP1C, nAct + 3);

    // 7) BEV head 1 (reads R2h) -> out channels [64,128)
    hipMemsetAsync(v2r1, 0xFF, (size_t)352000 * 4, stream);
    build_vox<<<(CAP1C + 255) / 256, 256, 0, stream>>>(coords1, v2r1, CAP1C, Z1D, Y1D, X1D);
    bev1_mfma<<<Y1D * 11, 256, 0, stream>>>(R2h, wtT1, ct1b, bnt1, v2r1, out + (size_t)64 * HWOUT);
}

// Round 7
// 1024.263 us; speedup vs baseline: 2.9366x; 2.9366x over previous
//
#include <hip/hip_runtime.h>
#include <hip/hip_bf16.h>
#include <hip/hip_fp16.h>

// Problem constants
#define N_PTS_IN   20000
#define CAP0C      540000
#define CAP1C      352000
#define ZD 10
#define YD 200
#define XD 704
#define Z1D 5
#define Y1D 100
#define X1D 352
#define HWOUT (YD*XD)   // 140800

typedef _Float16 f16x8 __attribute__((ext_vector_type(8)));
typedef float    f32x4 __attribute__((ext_vector_type(4)));

// ---------------------------------------------------------------------------
// f_in = sp_feats @ w_in   (20000x64 @ 64x32), f16 output rows
__global__ __launch_bounds__(256) void gemm_in(const float* __restrict__ sp,
                                               const float* __restrict__ w,
                                               __half* __restrict__ fout) {
    int tid = blockIdx.x * 256 + threadIdx.x;
    int row = tid >> 3;
    int c4  = (tid & 7) * 4;
    if (row >= N_PTS_IN) return;
    float4 acc = {0.f, 0.f, 0.f, 0.f};
    const float* sr = sp + (size_t)row * 64;
#pragma unroll
    for (int ci = 0; ci < 64; ci += 4) {
        float4 fv = *(const float4*)(sr + ci);
        const float* wp = w + ci * 32 + c4;
        float4 w0 = *(const float4*)(wp);
        float4 w1 = *(const float4*)(wp + 32);
        float4 w2 = *(const float4*)(wp + 64);
        float4 w3 = *(const float4*)(wp + 96);
        acc.x += fv.x*w0.x + fv.y*w1.x + fv.z*w2.x + fv.w*w3.x;
        acc.y += fv.x*w0.y + fv.y*w1.y + fv.z*w2.y + fv.w*w3.y;
        acc.z += fv.x*w0.z + fv.y*w1.z + fv.z*w2.z + fv.w*w3.z;
        acc.w += fv.x*w0.w + fv.y*w1.w + fv.z*w2.w + fv.w*w3.w;
    }
    __half* fo = fout + (size_t)row * 32 + c4;
    fo[0] = __float2half(acc.x);
    fo[1] = __float2half(acc.y);
    fo[2] = __float2half(acc.z);
    fo[3] = __float2half(acc.w);
}

// ---------------------------------------------------------------------------
// Weight convert+transpose: src f32 [27][CIN][COUT] -> dst f16 [27][COUT][CIN]
__global__ __launch_bounds__(256) void cvt_w(const float* __restrict__ src,
                                             __half* __restrict__ dst,
                                             int CIN, int COUT) {
    int i = blockIdx.x * 256 + threadIdx.x;
    if (i >= 27 * CIN * COUT) return;
    int ci = i % CIN;
    int t  = i / CIN;
    int co = t % COUT;
    int k  = t / COUT;
    dst[i] = __float2half(src[((size_t)k * CIN + ci) * COUT + co]);
}

// ct0_w f32 [320][64] (ci=c*10+z) -> f16 [co][zc=z*32+c]
__global__ __launch_bounds__(256) void cvt_ct0(const float* __restrict__ src,
                                               __half* __restrict__ dst) {
    int i = blockIdx.x * 256 + threadIdx.x;
    if (i >= 64 * 320) return;
    int zc = i % 320, co = i / 320;
    int z = zc >> 5, c = zc & 31;
    dst[i] = __float2half(src[(c * 10 + z) * 64 + co]);
}

// ct1_w f32 [320][64][2][2] (ci=c*5+z) -> f16 [kq][co][zc=z*64+c]
__global__ __launch_bounds__(256) void cvt_ct1(const float* __restrict__ src,
                                               __half* __restrict__ dst) {
    int i = blockIdx.x * 256 + threadIdx.x;
    if (i >= 4 * 64 * 320) return;
    int zc = i % 320;
    int t  = i / 320;
    int co = t & 63;
    int kq = t >> 6;
    int z = zc >> 6, c = zc & 63;
    dst[i] = __float2half(src[((c * 5 + z) * 64 + co) * 4 + kq]);
}

// ---------------------------------------------------------------------------
// Rulebook inversion, TRANSPOSED: nbrT[k*cap + s] = g.
// v13: reverted to scatter-only (v12's per-wave atomicMax on ONE address
// serialized 228k atomics -> 1160us; Guideline 12).
__global__ __launch_bounds__(256) void build_nbr(const int* __restrict__ g,
                                                 const int* __restrict__ s,
                                                 int* __restrict__ nbrT,
                                                 int P, int cap) {
    int i = blockIdx.x * 256 + threadIdx.x;
    if (i >= 27 * P) return;
    int k = i / P, p = i - k * P;
    int sv = s[(size_t)k * P + p];
    if (sv >= cap) return;              // dummy pair
    nbrT[(size_t)k * cap + sv] = g[(size_t)k * P + p];
}

// ---------------------------------------------------------------------------
// n_act via binary search: coords arrays are [real..., pad...] with pad rows
// marked z == Zdim (monotonic predicate). n_act(level0 convs) = #real coords0
// rows; n_act(level1 convs) = #real coords1 rows. Two concurrent waves,
// ~20 dependent loads each, zero atomics.
__global__ __launch_bounds__(128) void find_nact(const int* __restrict__ c0,
                                                 const int* __restrict__ c1,
                                                 int* __restrict__ nA) {
    int t = threadIdx.x;
    if (t == 0) {
        int lo = 0, hi = CAP0C;
        while (lo < hi) {
            int mid = (lo + hi) >> 1;
            if (c0[4 * mid + 1] >= ZD) hi = mid; else lo = mid + 1;
        }
        nA[0] = lo;
    } else if (t == 64) {
        int lo = 0, hi = CAP1C;
        while (lo < hi) {
            int mid = (lo + hi) >> 1;
            if (c1[4 * mid + 1] >= Z1D) hi = mid; else lo = mid + 1;
        }
        nA[1] = lo;
    }
}

// voxel -> sparse-row index (pad coords have z == Zdim, dropped like JAX OOB)
__global__ __launch_bounds__(256) void build_vox(const int* __restrict__ coords,
                                                 int* __restrict__ v2r,
                                                 int cap, int Zdim, int Ydim, int Xdim) {
    int r = blockIdx.x * 256 + threadIdx.x;
    if (r >= cap) return;
    int b = coords[4*r], z = coords[4*r+1], y = coords[4*r+2], x = coords[4*r+3];
    if (z >= Zdim) return;
    v2r[(((size_t)b * Zdim + z) * Ydim + y) * Xdim + x] = r;
}

// ---------------------------------------------------------------------------
// Implicit-GEMM sparse conv via f16 MFMA 16x16x32, + BN + ReLU.
// v13 = v11 (weights-via-LDS, TA relief: 360->137us confirmed) + v12
// dead-block early exit (n_act now computed atomic-free by find_nact):
//   - active output rows are exactly [0, n_act); blocks with sb*128 >= n_act
//     (48% at level 1, 32% at level 0 per WRITE_SIZE) return after one
//     scalar compare (uniform, no barrier divergence).
//   - interleaved-group XCD swizzle: live-prefix-safe, bijective.
template <int CIN, int COUT>
__global__ __launch_bounds__(256) void spconv_reg(const __half* __restrict__ f,
                                                  const __half* __restrict__ wt,
                                                  const float* __restrict__ bnp,
                                                  const int* __restrict__ nbrT,
                                                  __half* __restrict__ fout,
                                                  int ncap,
                                                  const int* __restrict__ nA) {
    constexpr int NT = COUT / 16;       // 16-col output tiles
    constexpr int KT = CIN / 32;        // K=32 MFMA steps per k-offset
    constexpr int NCHUNK = CIN / 8;     // 16B chunks per weight row
    constexpr int MASK = NCHUNK - 1;
    constexpr int LCH  = (NCHUNK == 8) ? 3 : 2;
    constexpr int TILE_H = COUT * CIN;  // halves per weight tile
    constexpr int TB = TILE_H * 2 / 256; // stage bytes per thread (8/16/32)
    constexpr int OST_H = 4 * 32 * COUT;
    constexpr int SH_H = (2 * TILE_H > OST_H) ? 2 * TILE_H : OST_H;
    __shared__ __align__(16) __half S[SH_H];

    int tid = threadIdx.x;
    int wv = tid >> 6, lane = tid & 63;
    int quad = lane >> 4, l16 = lane & 15;

    // interleaved-group XCD swizzle (live-prefix-safe, bijective)
    int bid = blockIdx.x;
    int nfull = (int)gridDim.x & ~63;
    int sb;
    if (bid < nfull) {
        int grp = bid >> 6, w = bid & 63;
        sb = grp * 64 + (w & 7) * 8 + (w >> 3);
    } else {
        sb = bid;
    }

    // dead-block early exit: rows >= n_act have no pairs for any k
    if (sb * 128 >= *nA) return;

    int m0 = sb * 128 + wv * 32;       // wave's first output row
    int r0 = m0 + l16;                 // this lane's row for m=0
    int r1 = m0 + 16 + l16;            // this lane's row for m=1
    bool ok0 = r0 < ncap, ok1 = r1 < ncap;

    f32x4 acc[2][NT] = {};

    // index pipeline depth 2
    int gC0 = ok0 ? nbrT[r0] : -1;
    int gC1 = ok1 ? nbrT[r1] : -1;
    int gN0 = ok0 ? nbrT[(size_t)ncap + r0] : -1;
    int gN1 = ok1 ? nbrT[(size_t)ncap + r1] : -1;
    bool ever = false;

    // ---- prologue: stage weight tile k=0 into buffer 0 ----
    {
        const char* src = (const char*)(wt) + tid * TB;
        if constexpr (TB == 32) {
            uint4 w0 = *(const uint4*)src;
            uint4 w1 = *(const uint4*)(src + 16);
            int p0 = tid * 2;
#pragma unroll
            for (int j = 0; j < 2; ++j) {
                int p = p0 + j;
                int row = p >> LCH, c = p & MASK;
                *(uint4*)(S + (row * NCHUNK + (c ^ (row & MASK))) * 8) = (j ? w1 : w0);
            }
        } else if constexpr (TB == 16) {
            uint4 w0 = *(const uint4*)src;
            int p = tid;
            int row = p >> LCH, c = p & MASK;
            *(uint4*)(S + (row * NCHUNK + (c ^ (row & MASK))) * 8) = w0;
        } else {
            uint2 w0 = *(const uint2*)src;
            int p = tid >> 1, half = tid & 1;
            int row = p >> LCH, c = p & MASK;
            *(uint2*)(S + (row * NCHUNK + (c ^ (row & MASK))) * 8 + half * 4) = w0;
        }
    }
    __syncthreads();

#pragma unroll 1
    for (int k = 0; k < 27; ++k) {
        // (1) idx k+2 (oldest in-flight: retired before barrier drain)
        int gNN0 = -1, gNN1 = -1;
        if (k + 2 < 27) {
            if (ok0) gNN0 = nbrT[(size_t)(k + 2) * ncap + r0];
            if (ok1) gNN1 = nbrT[(size_t)(k + 2) * ncap + r1];
        }
        // (2) gathers k -> regs
        bool anyC = __ballot((gC0 >= 0) || (gC1 >= 0)) != 0ull;
        f16x8 a0[KT], a1[KT];
        if (anyC) {
            const __half* p0 = f + (size_t)((gC0 < 0) ? 0 : gC0) * CIN + quad * 8;
            const __half* p1 = f + (size_t)((gC1 < 0) ? 0 : gC1) * CIN + quad * 8;
#pragma unroll
            for (int kt = 0; kt < KT; ++kt) {
                uint4 u0 = {0u,0u,0u,0u}, u1 = {0u,0u,0u,0u};
                if (gC0 >= 0) u0 = *(const uint4*)(p0 + kt * 32);
                if (gC1 >= 0) u1 = *(const uint4*)(p1 + kt * 32);
                a0[kt] = *(f16x8*)&u0;
                a1[kt] = *(f16x8*)&u1;
            }
        }
        // (3) stage loads for k+1 -> regs (youngest: stays in flight
        //     across the MFMA's gather-wait)
        bool doStage = (k + 1 < 27);
        uint4 w0{}, w1{}; uint2 w2{};
        if (doStage) {
            const char* src = (const char*)(wt + (size_t)(k + 1) * TILE_H) + tid * TB;
            if constexpr (TB == 32)      { w0 = *(const uint4*)src; w1 = *(const uint4*)(src + 16); }
            else if constexpr (TB == 16) { w0 = *(const uint4*)src; }
            else                         { w2 = *(const uint2*)src; }
        }
        // (4) ds_read B + (5) MFMA
        if (anyC) {
            ever = true;
            const __half* Wb = S + (k & 1) * TILE_H;
#pragma unroll
            for (int kt = 0; kt < KT; ++kt) {
#pragma unroll
                for (int nt = 0; nt < NT; ++nt) {
                    int row = nt * 16 + l16;
                    int c   = kt * 4 + quad;
                    f16x8 b = *(const f16x8*)(Wb + (row * NCHUNK + (c ^ (row & MASK))) * 8);
                    acc[0][nt] = __builtin_amdgcn_mfma_f32_16x16x32_f16(a0[kt], b, acc[0][nt], 0, 0, 0);
                    acc[1][nt] = __builtin_amdgcn_mfma_f32_16x16x32_f16(a1[kt], b, acc[1][nt], 0, 0, 0);
                }
            }
        }
        // (6) ds_write staging into the other buffer
        if (doStage) {
            __half* dst = S + ((k + 1) & 1) * TILE_H;
            if constexpr (TB == 32) {
                int p0 = tid * 2;
#pragma unroll
                for (int j = 0; j < 2; ++j) {
                    int p = p0 + j;
                    int row = p >> LCH, c = p & MASK;
                    *(uint4*)(dst + (row * NCHUNK + (c ^ (row & MASK))) * 8) = (j ? w1 : w0);
                }
            } else if constexpr (TB == 16) {
                int p = tid;
                int row = p >> LCH, c = p & MASK;
                *(uint4*)(dst + (row * NCHUNK + (c ^ (row & MASK))) * 8) = w0;
            } else {
                int p = tid >> 1, half = tid & 1;
                int row = p >> LCH, c = p & MASK;
                *(uint2*)(dst + (row * NCHUNK + (c ^ (row & MASK))) * 8 + half * 4) = w2;
            }
        }
        __syncthreads();
        gC0 = gN0; gC1 = gN1; gN0 = gNN0; gN1 = gNN1;
    }

    // epilogue: BN + ReLU -> wave-private LDS (weight bufs dead) -> store.
    if (!ever) return;
    __half* O = S + wv * (32 * COUT);
#pragma unroll
    for (int nt = 0; nt < NT; ++nt) {
        int co = nt * 16 + l16;
        float g = bnp[co], b = bnp[COUT + co];
        float mn = bnp[2*COUT + co], vv = bnp[3*COUT + co];
        float s  = g * rsqrtf(vv + 1e-5f);
        float sh = b - mn * s;
#pragma unroll
        for (int m = 0; m < 2; ++m)
#pragma unroll
            for (int r_ = 0; r_ < 4; ++r_) {
                int row = m * 16 + quad * 4 + r_;
                O[row * COUT + co] = __float2half(fmaxf(acc[m][nt][r_] * s + sh, 0.f));
            }
    }
    constexpr int OCH = COUT / 8;              // 16B chunks per out row
#pragma unroll
    for (int j = 0; j < 32 * OCH / 64; ++j) {
        int idx = j * 64 + lane;
        int r = idx / OCH, c = idx % OCH;
        if (m0 + r < ncap)
            *(uint4*)(fout + (size_t)(m0 + r) * COUT + c * 8) =
                *(const uint4*)(O + r * COUT + c * 8);
    }
}

// ---------------------------------------------------------------------------
// BEV head 0: fused gather + GEMM [64rows x 320] @ [320 x 64] via f16 MFMA,
// + BN + ReLU + 2-agent attention + coalesced store.
__global__ __launch_bounds__(256) void bev0_mfma(const __half* __restrict__ f0,
                                                 const __half* __restrict__ wtT,  // [64][320] zc=z*32+c
                                                 const float* __restrict__ bias,
                                                 const float* __restrict__ bnp,
                                                 const int* __restrict__ v2r,
                                                 float* __restrict__ out) {
    constexpr int AST = 328;
    __shared__ __align__(16) __half Al[64 * AST];   // 41,984 B
    __shared__ float Cl[64][65];                     // wave-private rows
    __shared__ float Ot[64][33];
    int tid = threadIdx.x;
    int y = blockIdx.x / 22, x0 = (blockIdx.x % 22) * 32;
    int wv = tid >> 6, lane = tid & 63;
    int quad = lane >> 4, l16 = lane & 15;

    for (int it = 0; it < 3; ++it) {
        int task = it * 256 + tid;
        if (task < 640) {
            int row = task & 63, z = task >> 6;
            int b = row & 1, p = row >> 1;
            int r = v2r[((b * ZD + z) * YD + y) * XD + x0 + p];
            uint4 v0 = {0,0,0,0}, v1 = {0,0,0,0}, v2 = {0,0,0,0}, v3 = {0,0,0,0};
            if (r >= 0) {
                const uint4* src = (const uint4*)(f0 + (size_t)r * 32);
                v0 = src[0]; v1 = src[1]; v2 = src[2]; v3 = src[3];
            }
            uint4* dst = (uint4*)(Al + row * AST + z * 32);
            dst[0] = v0; dst[1] = v1; dst[2] = v2; dst[3] = v3;
        }
    }
    __syncthreads();

    f32x4 acc[4] = {};
#pragma unroll
    for (int ks = 0; ks < 10; ++ks) {
        f16x8 a = *(const f16x8*)(Al + (wv * 16 + l16) * AST + ks * 32 + quad * 8);
#pragma unroll
        for (int nt = 0; nt < 4; ++nt) {
            f16x8 bfr = *(const f16x8*)(wtT + (size_t)(nt * 16 + l16) * 320 + ks * 32 + quad * 8);
            acc[nt] = __builtin_amdgcn_mfma_f32_16x16x32_f16(a, bfr, acc[nt], 0, 0, 0);
        }
    }
#pragma unroll
    for (int nt = 0; nt < 4; ++nt) {
        int co = nt * 16 + l16;
        float s  = bnp[co] * rsqrtf(bnp[192 + co] + 1e-5f);
        float sh = (bias[co] - bnp[128 + co]) * s + bnp[64 + co];
#pragma unroll
        for (int r_ = 0; r_ < 4; ++r_)
            Cl[wv * 16 + quad * 4 + r_][co] = fmaxf(acc[nt][r_] * s + sh, 0.f);
    }
#pragma unroll
    for (int pi = 0; pi < 8; ++pi) {
        int p = wv * 8 + pi;
        float x0v = Cl[2 * p][lane], x1v = Cl[2 * p + 1][lane];
        float s00 = x0v * x0v, s01 = x0v * x1v;
#pragma unroll
        for (int o = 32; o > 0; o >>= 1) {
            s00 += __shfl_xor(s00, o);
            s01 += __shfl_xor(s01, o);
        }
        float a0 = s00 * 0.125f, a1 = s01 * 0.125f;
        float mx = fmaxf(a0, a1);
        float e0 = expf(a0 - mx), e1 = expf(a1 - mx);
        float inv = 1.f / (e0 + e1);
        Ot[lane][p] = (e0 * x0v + e1 * x1v) * inv;
    }
    __syncthreads();
#pragma unroll
    for (int i = 0; i < 8; ++i) {
        int idx = i * 256 + tid;
        int co = idx >> 5, px = idx & 31;
        out[(size_t)co * HWOUT + (size_t)y * XD + x0 + px] = Ot[co][px];
    }
}

// ---------------------------------------------------------------------------
// BEV head 1: fused gather + 4x (GEMM [64x320]@[320x64]) for the 2x2 s2 convT
// kernel positions + BN + ReLU + attention + coalesced store.
__global__ __launch_bounds__(256) void bev1_mfma(const __half* __restrict__ f1,
                                                 const __half* __restrict__ wtT,  // [4][64][320] zc=z*64+c
                                                 const float* __restrict__ bias,
                                                 const float* __restrict__ bnp,
                                                 const int* __restrict__ v2r,
                                                 float* __restrict__ out) {
    constexpr int AST = 328;
    __shared__ __align__(16) __half Al[64 * AST];
    __shared__ float Cl[64][65];
    __shared__ float Ot[64][65];
    int tid = threadIdx.x;
    int iy = blockIdx.x / 11, j0 = (blockIdx.x % 11) * 32;
    int wv = tid >> 6, lane = tid & 63;
    int quad = lane >> 4, l16 = lane & 15;

    for (int it = 0; it < 3; ++it) {
        int task = it * 256 + tid;
        if (task < 640) {
            int row = task & 63, zh = task >> 6;   // 0..9
            int z = zh >> 1, hf = zh & 1;
            int b = row & 1, p = row >> 1;
            int r = v2r[((b * Z1D + z) * Y1D + iy) * X1D + j0 + p];
            uint4 v0 = {0,0,0,0}, v1 = {0,0,0,0}, v2 = {0,0,0,0}, v3 = {0,0,0,0};
            if (r >= 0) {
                const uint4* src = (const uint4*)(f1 + (size_t)r * 64 + hf * 32);
                v0 = src[0]; v1 = src[1]; v2 = src[2]; v3 = src[3];
            }
            uint4* dst = (uint4*)(Al + row * AST + z * 64 + hf * 32);
            dst[0] = v0; dst[1] = v1; dst[2] = v2; dst[3] = v3;
        }
    }
    __syncthreads();

#pragma unroll 1
    for (int ky = 0; ky < 2; ++ky) {
#pragma unroll 1
        for (int kx = 0; kx < 2; ++kx) {
            const __half* wk = wtT + (size_t)(ky * 2 + kx) * 64 * 320;
            f32x4 acc[4] = {};
#pragma unroll
            for (int ks = 0; ks < 10; ++ks) {
                f16x8 a = *(const f16x8*)(Al + (wv * 16 + l16) * AST + ks * 32 + quad * 8);
#pragma unroll
                for (int nt = 0; nt < 4; ++nt) {
                    f16x8 bfr = *(const f16x8*)(wk + (size_t)(nt * 16 + l16) * 320 + ks * 32 + quad * 8);
                    acc[nt] = __builtin_amdgcn_mfma_f32_16x16x32_f16(a, bfr, acc[nt], 0, 0, 0);
                }
            }
#pragma unroll
            for (int nt = 0; nt < 4; ++nt) {
                int co = nt * 16 + l16;
                float s  = bnp[co] * rsqrtf(bnp[192 + co] + 1e-5f);
                float sh = (bias[co] - bnp[128 + co]) * s + bnp[64 + co];
#pragma unroll
                for (int r_ = 0; r_ < 4; ++r_)
                    Cl[wv * 16 + quad * 4 + r_][co] = fmaxf(acc[nt][r_] * s + sh, 0.f);
            }
#pragma unroll
            for (int pi = 0; pi < 8; ++pi) {
                int p = wv * 8 + pi;
                float x0v = Cl[2 * p][lane], x1v = Cl[2 * p + 1][lane];
                float s00 = x0v * x0v, s01 = x0v * x1v;
#pragma unroll
                for (int o = 32; o > 0; o >>= 1) {
                    s00 += __shfl_xor(s00, o);
                    s01 += __shfl_xor(s01, o);
                }
                float a0 = s00 * 0.125f, a1 = s01 * 0.125f;
                float mx = fmaxf(a0, a1);
                float e0 = expf(a0 - mx), e1 = expf(a1 - mx);
                float inv = 1.f / (e0 + e1);
                Ot[lane][2 * p + kx] = (e0 * x0v + e1 * x1v) * inv;
            }
        }
        __syncthreads();
        int yo = 2 * iy + ky;
#pragma unroll
        for (int i = 0; i < 16; ++i) {
            int idx = i * 256 + tid;
            int co = idx >> 6, xx = idx & 63;
            out[(size_t)co * HWOUT + (size_t)yo * XD + 2 * j0 + xx] = Ot[co][xx];
        }
        __syncthreads();
    }
}

// ---------------------------------------------------------------------------
extern "C" void kernel_launch(void* const* d_in, const int* in_sizes, int n_in,
                              void* d_out, int out_size, void* d_ws, size_t ws_size,
                              hipStream_t stream) {
    const float* sp    = (const float*)d_in[0];
    const float* w_in  = (const float*)d_in[1];
    const float* w0    = (const float*)d_in[2];
    const float* bnp0  = (const float*)d_in[3];
    const float* w0a   = (const float*)d_in[4];
    const float* bnp0a = (const float*)d_in[5];
    const float* w0b   = (const float*)d_in[6];
    const float* bnp0b = (const float*)d_in[7];
    const float* w1    = (const float*)d_in[8];
    const float* bnp1  = (const float*)d_in[9];
    const float* w1a   = (const float*)d_in[10];
    const float* bnp1a = (const float*)d_in[11];
    const float* w1b   = (const float*)d_in[12];
    const float* bnp1b = (const float*)d_in[13];
    const float* ct0w  = (const float*)d_in[14];
    const float* ct0b  = (const float*)d_in[15];
    const float* bnt0  = (const float*)d_in[16];
    const float* ct1w  = (const float*)d_in[17];
    const float* ct1b  = (const float*)d_in[18];
    const float* bnt1  = (const float*)d_in[19];
    const int* coords0 = (const int*)d_in[20];
    const int* coords1 = (const int*)d_in[21];
    const int* g0 = (const int*)d_in[22];
    const int* s0 = (const int*)d_in[23];
    const int* ga = (const int*)d_in[24];
    const int* sa = (const int*)d_in[25];
    const int* g1 = (const int*)d_in[26];
    const int* s1 = (const int*)d_in[27];
    const int* gb = (const int*)d_in[28];
    const int* sb = (const int*)d_in[29];
    float* out = (float*)d_out;

    // -------- workspace carve --------
    __half* fInH = (__half*)d_ws;
    __half* R1h  = fInH + 640000;
    __half* R2h  = R1h + 22528000;
    __half* wt0  = R2h + 22528000;
    __half* wt0a = wt0  + 27648;
    __half* wt0b = wt0a + 27648;
    __half* wt1  = wt0b + 27648;          // [27][64][32]
    __half* wt1a = wt1  + 55296;          // [27][64][64]
    __half* wt1b = wt1a + 110592;
    __half* wtT0 = wt1b + 110592;         // [64][320]
    __half* wtT1 = wtT0 + 20480;          // [4][64][320]
    int*   nbrT = (int*)(wtT1 + 81920);   // 27*CAP0C ints = 14,580,000
    int*   v2r0 = nbrT;                          // 2,816,000 ints (aliases)
    int*   v2r1 = nbrT + 2816000;                //   352,000 ints (aliases)
    int*   nAct = nbrT + 14580000;               // 2 ints, beyond nbrT region

    // 0) weight conversion + n_act (binary search on coords pad boundary)
    find_nact<<<1, 128, 0, stream>>>(coords0, coords1, nAct);
    cvt_w<<<(27*32*32 + 255) / 256, 256, 0, stream>>>(w0,  wt0,  32, 32);
    cvt_w<<<(27*32*32 + 255) / 256, 256, 0, stream>>>(w0a, wt0a, 32, 32);
    cvt_w<<<(27*32*32 + 255) / 256, 256, 0, stream>>>(w0b, wt0b, 32, 32);
    cvt_w<<<(27*32*64 + 255) / 256, 256, 0, stream>>>(w1,  wt1,  32, 64);
    cvt_w<<<(27*64*64 + 255) / 256, 256, 0, stream>>>(w1a, wt1a, 64, 64);
    cvt_w<<<(27*64*64 + 255) / 256, 256, 0, stream>>>(w1b, wt1b, 64, 64);
    cvt_ct0<<<(64*320 + 255) / 256, 256, 0, stream>>>(ct0w, wtT0);
    cvt_ct1<<<(4*64*320 + 255) / 256, 256, 0, stream>>>(ct1w, wtT1);

    // 1) input channel lift (f16 rows out)
    gemm_in<<<(N_PTS_IN * 8 + 255) / 256, 256, 0, stream>>>(sp, w_in, fInH);

    // 2) conv0 (stride-1 spconv, 32->32): fInH -> R1h
    hipMemsetAsync(nbrT, 0xFF, (size_t)CAP0C * 27 * 4, stream);
    build_nbr<<<(27 * N_PTS_IN + 255) / 256, 256, 0, stream>>>(g0, s0, nbrT, N_PTS_IN, CAP0C);
    spconv_reg<32, 32><<<(CAP0C + 127) / 128, 256, 0, stream>>>(fInH, wt0, bnp0, nbrT, R1h, CAP0C, nAct + 0);

    // 3) subm a/b (32->32), shared rulebook: R1h -> R2h -> R1h
    hipMemsetAsync(nbrT, 0xFF, (size_t)CAP0C * 27 * 4, stream);
    build_nbr<<<(27 * CAP0C + 255) / 256, 256, 0, stream>>>(ga, sa, nbrT, CAP0C, CAP0C);
    spconv_reg<32, 32><<<(CAP0C + 127) / 128, 256, 0, stream>>>(R1h, wt0a, bnp0a, nbrT, R2h, CAP0C, nAct + 0);
    spconv_reg<32, 32><<<(CAP0C + 127) / 128, 256, 0, stream>>>(R2h, wt0b, bnp0b, nbrT, R1h, CAP0C, nAct + 0);

    // 4) BEV head 0 (reads R1h) -> out channels [0,64)
    hipMemsetAsync(v2r0, 0xFF, (size_t)2816000 * 4, stream);
    build_vox<<<(CAP0C + 255) / 256, 256, 0, stream>>>(coords0, v2r0, CAP0C, ZD, YD, XD);
    bev0_mfma<<<YD * 22, 256, 0, stream>>>(R1h, wtT0, ct0b, bnt0, v2r0, out);

    // 5) conv1 (stride-2 spconv, 32->64): R1h -> R2h
    hipMemsetAsync(nbrT, 0xFF, (size_t)CAP1C * 27 * 4, stream);
    build_nbr<<<(27 * CAP0C + 255) / 256, 256, 0, stream>>>(g1, s1, nbrT, CAP0C, CAP1C);
    spconv_reg<32, 64><<<(CAP1C + 127) / 128, 256, 0, stream>>>(R1h, wt1, bnp1, nbrT, R2h, CAP1C, nAct + 1);

    // 6) subm 1a/1b (64->64), shared rulebook: R2h -> R1h -> R2h
    hipMemsetAsync(nbrT, 0xFF, (size_t)CAP1C * 27 * 4, stream);
    build_nbr<<<(27 * CAP1C + 255) / 256, 256, 0, stream>>>(gb, sb, nbrT, CAP1C, CAP1C);
    spconv_reg<64, 64><<<(CAP1C + 127) / 128, 256, 0, stream>>>(R2h, wt1a, bnp1a, nbrT, R1h, CAP1C, nAct + 1);
    spconv_reg<64, 64><<<(CAP1C + 127) / 128, 256, 0, stream>>>(R1h, wt1b, bnp1b, nbrT, R2h, CAP1C, nAct + 1);

    // 7) BEV head 1 (reads R2h) -> out channels [64,128)
    hipMemsetAsync(v2r1, 0xFF, (size_t)352000 * 4, stream);
    build_vox<<<(CAP1C + 255) / 256, 256, 0, stream>>>(coords1, v2r1, CAP1C, Z1D, Y1D, X1D);
    bev1_mfma<<<Y1D * 11, 256, 0, stream>>>(R2h, wtT1, ct1b, bnt1, v2r1, out + (size_t)64 * HWOUT);
}

// Round 8
// 977.242 us; speedup vs baseline: 3.0779x; 1.0481x over previous
//
#include <hip/hip_runtime.h>
#include <hip/hip_bf16.h>
#include <hip/hip_fp16.h>

// Problem constants
#define N_PTS_IN   20000
#define CAP0C      540000
#define CAP1C      352000
#define ZD 10
#define YD 200
#define XD 704
#define Z1D 5
#define Y1D 100
#define X1D 352
#define HWOUT (YD*XD)   // 140800

typedef _Float16 f16x8 __attribute__((ext_vector_type(8)));
typedef float    f32x4 __attribute__((ext_vector_type(4)));

// ---------------------------------------------------------------------------
// f_in = sp_feats @ w_in   (20000x64 @ 64x32), f16 output rows
__global__ __launch_bounds__(256) void gemm_in(const float* __restrict__ sp,
                                               const float* __restrict__ w,
                                               __half* __restrict__ fout) {
    int tid = blockIdx.x * 256 + threadIdx.x;
    int row = tid >> 3;
    int c4  = (tid & 7) * 4;
    if (row >= N_PTS_IN) return;
    float4 acc = {0.f, 0.f, 0.f, 0.f};
    const float* sr = sp + (size_t)row * 64;
#pragma unroll
    for (int ci = 0; ci < 64; ci += 4) {
        float4 fv = *(const float4*)(sr + ci);
        const float* wp = w + ci * 32 + c4;
        float4 w0 = *(const float4*)(wp);
        float4 w1 = *(const float4*)(wp + 32);
        float4 w2 = *(const float4*)(wp + 64);
        float4 w3 = *(const float4*)(wp + 96);
        acc.x += fv.x*w0.x + fv.y*w1.x + fv.z*w2.x + fv.w*w3.x;
        acc.y += fv.x*w0.y + fv.y*w1.y + fv.z*w2.y + fv.w*w3.y;
        acc.z += fv.x*w0.z + fv.y*w1.z + fv.z*w2.z + fv.w*w3.z;
        acc.w += fv.x*w0.w + fv.y*w1.w + fv.z*w2.w + fv.w*w3.w;
    }
    __half* fo = fout + (size_t)row * 32 + c4;
    fo[0] = __float2half(acc.x);
    fo[1] = __float2half(acc.y);
    fo[2] = __float2half(acc.z);
    fo[3] = __float2half(acc.w);
}

// ---------------------------------------------------------------------------
// Weight convert+transpose: src f32 [27][CIN][COUT] -> dst f16 [27][COUT][CIN]
__global__ __launch_bounds__(256) void cvt_w(const float* __restrict__ src,
                                             __half* __restrict__ dst,
                                             int CIN, int COUT) {
    int i = blockIdx.x * 256 + threadIdx.x;
    if (i >= 27 * CIN * COUT) return;
    int ci = i % CIN;
    int t  = i / CIN;
    int co = t % COUT;
    int k  = t / COUT;
    dst[i] = __float2half(src[((size_t)k * CIN + ci) * COUT + co]);
}

// ct0_w f32 [320][64] (ci=c*10+z) -> f16 [co][zc=z*32+c]
__global__ __launch_bounds__(256) void cvt_ct0(const float* __restrict__ src,
                                               __half* __restrict__ dst) {
    int i = blockIdx.x * 256 + threadIdx.x;
    if (i >= 64 * 320) return;
    int zc = i % 320, co = i / 320;
    int z = zc >> 5, c = zc & 31;
    dst[i] = __float2half(src[(c * 10 + z) * 64 + co]);
}

// ct1_w f32 [320][64][2][2] (ci=c*5+z) -> f16 [kq][co][zc=z*64+c]
__global__ __launch_bounds__(256) void cvt_ct1(const float* __restrict__ src,
                                               __half* __restrict__ dst) {
    int i = blockIdx.x * 256 + threadIdx.x;
    if (i >= 4 * 64 * 320) return;
    int zc = i % 320;
    int t  = i / 320;
    int co = t & 63;
    int kq = t >> 6;
    int z = zc >> 6, c = zc & 63;
    dst[i] = __float2half(src[((c * 5 + z) * 64 + co) * 4 + kq]);
}

// ---------------------------------------------------------------------------
// Rulebook inversion, TRANSPOSED: nbrT[k*cap + s] = g. Scatter-only.
__global__ __launch_bounds__(256) void build_nbr(const int* __restrict__ g,
                                                 const int* __restrict__ s,
                                                 int* __restrict__ nbrT,
                                                 int P, int cap) {
    int i = blockIdx.x * 256 + threadIdx.x;
    if (i >= 27 * P) return;
    int k = i / P, p = i - k * P;
    int sv = s[(size_t)k * P + p];
    if (sv >= cap) return;              // dummy pair
    nbrT[(size_t)k * cap + sv] = g[(size_t)k * P + p];
}

// ---------------------------------------------------------------------------
// n_act via binary search on the coords pad boundary (z == Zdim marks pad).
__global__ __launch_bounds__(128) void find_nact(const int* __restrict__ c0,
                                                 const int* __restrict__ c1,
                                                 int* __restrict__ nA) {
    int t = threadIdx.x;
    if (t == 0) {
        int lo = 0, hi = CAP0C;
        while (lo < hi) {
            int mid = (lo + hi) >> 1;
            if (c0[4 * mid + 1] >= ZD) hi = mid; else lo = mid + 1;
        }
        nA[0] = lo;
    } else if (t == 64) {
        int lo = 0, hi = CAP1C;
        while (lo < hi) {
            int mid = (lo + hi) >> 1;
            if (c1[4 * mid + 1] >= Z1D) hi = mid; else lo = mid + 1;
        }
        nA[1] = lo;
    }
}

// voxel -> sparse-row index (pad coords have z == Zdim, dropped like JAX OOB)
__global__ __launch_bounds__(256) void build_vox(const int* __restrict__ coords,
                                                 int* __restrict__ v2r,
                                                 int cap, int Zdim, int Ydim, int Xdim) {
    int r = blockIdx.x * 256 + threadIdx.x;
    if (r >= cap) return;
    int b = coords[4*r], z = coords[4*r+1], y = coords[4*r+2], x = coords[4*r+3];
    if (z >= Zdim) return;
    v2r[(((size_t)b * Zdim + z) * Ydim + y) * Xdim + x] = r;
}

// ---------------------------------------------------------------------------
// Implicit-GEMM sparse conv via f16 MFMA 16x16x32, + BN + ReLU.
// v13 structure (weights-via-LDS + dead-block early exit) -- unchanged.
template <int CIN, int COUT>
__global__ __launch_bounds__(256) void spconv_reg(const __half* __restrict__ f,
                                                  const __half* __restrict__ wt,
                                                  const float* __restrict__ bnp,
                                                  const int* __restrict__ nbrT,
                                                  __half* __restrict__ fout,
                                                  int ncap,
                                                  const int* __restrict__ nA) {
    constexpr int NT = COUT / 16;       // 16-col output tiles
    constexpr int KT = CIN / 32;        // K=32 MFMA steps per k-offset
    constexpr int NCHUNK = CIN / 8;     // 16B chunks per weight row
    constexpr int MASK = NCHUNK - 1;
    constexpr int LCH  = (NCHUNK == 8) ? 3 : 2;
    constexpr int TILE_H = COUT * CIN;  // halves per weight tile
    constexpr int TB = TILE_H * 2 / 256; // stage bytes per thread (8/16/32)
    constexpr int OST_H = 4 * 32 * COUT;
    constexpr int SH_H = (2 * TILE_H > OST_H) ? 2 * TILE_H : OST_H;
    __shared__ __align__(16) __half S[SH_H];

    int tid = threadIdx.x;
    int wv = tid >> 6, lane = tid & 63;
    int quad = lane >> 4, l16 = lane & 15;

    // interleaved-group XCD swizzle (live-prefix-safe, bijective)
    int bid = blockIdx.x;
    int nfull = (int)gridDim.x & ~63;
    int sb;
    if (bid < nfull) {
        int grp = bid >> 6, w = bid & 63;
        sb = grp * 64 + (w & 7) * 8 + (w >> 3);
    } else {
        sb = bid;
    }

    // dead-block early exit: rows >= n_act have no pairs for any k
    if (sb * 128 >= *nA) return;

    int m0 = sb * 128 + wv * 32;       // wave's first output row
    int r0 = m0 + l16;                 // this lane's row for m=0
    int r1 = m0 + 16 + l16;            // this lane's row for m=1
    bool ok0 = r0 < ncap, ok1 = r1 < ncap;

    f32x4 acc[2][NT] = {};

    // index pipeline depth 2
    int gC0 = ok0 ? nbrT[r0] : -1;
    int gC1 = ok1 ? nbrT[r1] : -1;
    int gN0 = ok0 ? nbrT[(size_t)ncap + r0] : -1;
    int gN1 = ok1 ? nbrT[(size_t)ncap + r1] : -1;
    bool ever = false;

    // ---- prologue: stage weight tile k=0 into buffer 0 ----
    {
        const char* src = (const char*)(wt) + tid * TB;
        if constexpr (TB == 32) {
            uint4 w0 = *(const uint4*)src;
            uint4 w1 = *(const uint4*)(src + 16);
            int p0 = tid * 2;
#pragma unroll
            for (int j = 0; j < 2; ++j) {
                int p = p0 + j;
                int row = p >> LCH, c = p & MASK;
                *(uint4*)(S + (row * NCHUNK + (c ^ (row & MASK))) * 8) = (j ? w1 : w0);
            }
        } else if constexpr (TB == 16) {
            uint4 w0 = *(const uint4*)src;
            int p = tid;
            int row = p >> LCH, c = p & MASK;
            *(uint4*)(S + (row * NCHUNK + (c ^ (row & MASK))) * 8) = w0;
        } else {
            uint2 w0 = *(const uint2*)src;
            int p = tid >> 1, half = tid & 1;
            int row = p >> LCH, c = p & MASK;
            *(uint2*)(S + (row * NCHUNK + (c ^ (row & MASK))) * 8 + half * 4) = w0;
        }
    }
    __syncthreads();

#pragma unroll 1
    for (int k = 0; k < 27; ++k) {
        // (1) idx k+2 (oldest in-flight: retired before barrier drain)
        int gNN0 = -1, gNN1 = -1;
        if (k + 2 < 27) {
            if (ok0) gNN0 = nbrT[(size_t)(k + 2) * ncap + r0];
            if (ok1) gNN1 = nbrT[(size_t)(k + 2) * ncap + r1];
        }
        // (2) gathers k -> regs
        bool anyC = __ballot((gC0 >= 0) || (gC1 >= 0)) != 0ull;
        f16x8 a0[KT], a1[KT];
        if (anyC) {
            const __half* p0 = f + (size_t)((gC0 < 0) ? 0 : gC0) * CIN + quad * 8;
            const __half* p1 = f + (size_t)((gC1 < 0) ? 0 : gC1) * CIN + quad * 8;
#pragma unroll
            for (int kt = 0; kt < KT; ++kt) {
                uint4 u0 = {0u,0u,0u,0u}, u1 = {0u,0u,0u,0u};
                if (gC0 >= 0) u0 = *(const uint4*)(p0 + kt * 32);
                if (gC1 >= 0) u1 = *(const uint4*)(p1 + kt * 32);
                a0[kt] = *(f16x8*)&u0;
                a1[kt] = *(f16x8*)&u1;
            }
        }
        // (3) stage loads for k+1 -> regs (youngest: stays in flight
        //     across the MFMA's gather-wait)
        bool doStage = (k + 1 < 27);
        uint4 w0{}, w1{}; uint2 w2{};
        if (doStage) {
            const char* src = (const char*)(wt + (size_t)(k + 1) * TILE_H) + tid * TB;
            if constexpr (TB == 32)      { w0 = *(const uint4*)src; w1 = *(const uint4*)(src + 16); }
            else if constexpr (TB == 16) { w0 = *(const uint4*)src; }
            else                         { w2 = *(const uint2*)src; }
        }
        // (4) ds_read B + (5) MFMA
        if (anyC) {
            ever = true;
            const __half* Wb = S + (k & 1) * TILE_H;
#pragma unroll
            for (int kt = 0; kt < KT; ++kt) {
#pragma unroll
                for (int nt = 0; nt < NT; ++nt) {
                    int row = nt * 16 + l16;
                    int c   = kt * 4 + quad;
                    f16x8 b = *(const f16x8*)(Wb + (row * NCHUNK + (c ^ (row & MASK))) * 8);
                    acc[0][nt] = __builtin_amdgcn_mfma_f32_16x16x32_f16(a0[kt], b, acc[0][nt], 0, 0, 0);
                    acc[1][nt] = __builtin_amdgcn_mfma_f32_16x16x32_f16(a1[kt], b, acc[1][nt], 0, 0, 0);
                }
            }
        }
        // (6) ds_write staging into the other buffer
        if (doStage) {
            __half* dst = S + ((k + 1) & 1) * TILE_H;
            if constexpr (TB == 32) {
                int p0 = tid * 2;
#pragma unroll
                for (int j = 0; j < 2; ++j) {
                    int p = p0 + j;
                    int row = p >> LCH, c = p & MASK;
                    *(uint4*)(dst + (row * NCHUNK + (c ^ (row & MASK))) * 8) = (j ? w1 : w0);
                }
            } else if constexpr (TB == 16) {
                int p = tid;
                int row = p >> LCH, c = p & MASK;
                *(uint4*)(dst + (row * NCHUNK + (c ^ (row & MASK))) * 8) = w0;
            } else {
                int p = tid >> 1, half = tid & 1;
                int row = p >> LCH, c = p & MASK;
                *(uint2*)(dst + (row * NCHUNK + (c ^ (row & MASK))) * 8 + half * 4) = w2;
            }
        }
        __syncthreads();
        gC0 = gN0; gC1 = gN1; gN0 = gNN0; gN1 = gNN1;
    }

    // epilogue: BN + ReLU -> wave-private LDS (weight bufs dead) -> store.
    if (!ever) return;
    __half* O = S + wv * (32 * COUT);
#pragma unroll
    for (int nt = 0; nt < NT; ++nt) {
        int co = nt * 16 + l16;
        float g = bnp[co], b = bnp[COUT + co];
        float mn = bnp[2*COUT + co], vv = bnp[3*COUT + co];
        float s  = g * rsqrtf(vv + 1e-5f);
        float sh = b - mn * s;
#pragma unroll
        for (int m = 0; m < 2; ++m)
#pragma unroll
            for (int r_ = 0; r_ < 4; ++r_) {
                int row = m * 16 + quad * 4 + r_;
                O[row * COUT + co] = __float2half(fmaxf(acc[m][nt][r_] * s + sh, 0.f));
            }
    }
    constexpr int OCH = COUT / 8;              // 16B chunks per out row
#pragma unroll
    for (int j = 0; j < 32 * OCH / 64; ++j) {
        int idx = j * 64 + lane;
        int r = idx / OCH, c = idx % OCH;
        if (m0 + r < ncap)
            *(uint4*)(fout + (size_t)(m0 + r) * COUT + c * 8) =
                *(const uint4*)(O + r * COUT + c * 8);
    }
}

// ---------------------------------------------------------------------------
// BEV head 0, v14: registers-only. 64 px per block (2200 blocks).
// R7 post-mortem: 67KB LDS capped bev0 at 2 blocks/CU; Cl roundtrip + serial
// per-lane attention (8px x 12-shuffle chains) dominated the critical path.
// Key layout fact: MFMA C-rows 2p and 2p+1 (the agent pair of pixel p) live
// in the SAME lane (rows differ only in bit0=r_ parity) -> attention is
// lane-local + one 16-lane shfl_xor reduce over the channel groups.
// A-fragments are gathered DIRECTLY into MFMA regs (v2r preloaded, 20 regs);
// 2 m-tiles per wave share every B fragment (B TA-lines per output halved).
// LDS: Ot staging only (16.9KB) -> ~5 blocks/CU. One barrier total.
__global__ __launch_bounds__(256) void bev0_mfma(const __half* __restrict__ f0,
                                                 const __half* __restrict__ wtT,  // [64][320] zc=z*32+c
                                                 const float* __restrict__ bias,
                                                 const float* __restrict__ bnp,
                                                 const int* __restrict__ v2r,
                                                 float* __restrict__ out) {
    __shared__ float Ot[64][66];
    int tid = threadIdx.x;
    int y = blockIdx.x / 11, x0 = (blockIdx.x % 11) * 64;
    int wv = tid >> 6, lane = tid & 63;
    int quad = lane >> 4, l16 = lane & 15;

    // v2r preload: 2 m-tiles x 10 z-slices (static-indexed -> registers)
    int rz[2][10];
#pragma unroll
    for (int m = 0; m < 2; ++m) {
        int row = wv * 32 + m * 16 + l16;
        int b = row & 1, p = row >> 1;
#pragma unroll
        for (int z = 0; z < 10; ++z)
            rz[m][z] = v2r[((b * ZD + z) * YD + y) * XD + x0 + p];
    }

    f32x4 acc[2][4] = {};
#pragma unroll
    for (int ks = 0; ks < 10; ++ks) {
        f16x8 a[2];
#pragma unroll
        for (int m = 0; m < 2; ++m) {
            uint4 u = {0u,0u,0u,0u};
            int r = rz[m][ks];
            if (r >= 0) u = *(const uint4*)(f0 + (size_t)r * 32 + quad * 8);
            a[m] = *(f16x8*)&u;
        }
#pragma unroll
        for (int nt = 0; nt < 4; ++nt) {
            f16x8 b = *(const f16x8*)(wtT + (size_t)(nt * 16 + l16) * 320 + ks * 32 + quad * 8);
            acc[0][nt] = __builtin_amdgcn_mfma_f32_16x16x32_f16(a[0], b, acc[0][nt], 0, 0, 0);
            acc[1][nt] = __builtin_amdgcn_mfma_f32_16x16x32_f16(a[1], b, acc[1][nt], 0, 0, 0);
        }
    }

    // BN + ReLU in-place (channels are lane-local: co = nt*16 + l16)
#pragma unroll
    for (int nt = 0; nt < 4; ++nt) {
        int co = nt * 16 + l16;
        float s  = bnp[co] * rsqrtf(bnp[192 + co] + 1e-5f);
        float sh = (bias[co] - bnp[128 + co]) * s + bnp[64 + co];
#pragma unroll
        for (int m = 0; m < 2; ++m)
#pragma unroll
            for (int r_ = 0; r_ < 4; ++r_)
                acc[m][nt][r_] = fmaxf(acc[m][nt][r_] * s + sh, 0.f);
    }

    // lane-local pair attention: rows 2jj/2jj+1 of each quad-block are the
    // two agents of one pixel; channel sum = 4 lane-local + 16-lane reduce.
#pragma unroll
    for (int m = 0; m < 2; ++m)
#pragma unroll
        for (int jj = 0; jj < 2; ++jj) {
            float s00 = 0.f, s01 = 0.f;
#pragma unroll
            for (int nt = 0; nt < 4; ++nt) {
                float xv0 = acc[m][nt][2 * jj], xv1 = acc[m][nt][2 * jj + 1];
                s00 += xv0 * xv0;
                s01 += xv0 * xv1;
            }
#pragma unroll
            for (int o = 8; o > 0; o >>= 1) {
                s00 += __shfl_xor(s00, o);
                s01 += __shfl_xor(s01, o);
            }
            float a0 = s00 * 0.125f, a1 = s01 * 0.125f;
            float mx = fmaxf(a0, a1);
            float e0 = expf(a0 - mx), e1 = expf(a1 - mx);
            float inv = 1.f / (e0 + e1);
            int pl = wv * 16 + m * 8 + quad * 2 + jj;
#pragma unroll
            for (int nt = 0; nt < 4; ++nt)
                Ot[nt * 16 + l16][pl] =
                    (e0 * acc[m][nt][2 * jj] + e1 * acc[m][nt][2 * jj + 1]) * inv;
        }
    __syncthreads();

#pragma unroll
    for (int i = 0; i < 16; ++i) {
        int idx = i * 256 + tid;
        int co = idx >> 6, px = idx & 63;
        out[(size_t)co * HWOUT + (size_t)y * XD + x0 + px] = Ot[co][px];
    }
}

// ---------------------------------------------------------------------------
// BEV head 1, v14: registers-only (same technique as bev0). 32 in-px per
// block, 4 convT kernel positions sequentially; A re-gathered per position
// (L1/L2-hot after the first). LDS: Ot only.
__global__ __launch_bounds__(256) void bev1_mfma(const __half* __restrict__ f1,
                                                 const __half* __restrict__ wtT,  // [4][64][320] zc=z*64+c
                                                 const float* __restrict__ bias,
                                                 const float* __restrict__ bnp,
                                                 const int* __restrict__ v2r,
                                                 float* __restrict__ out) {
    __shared__ float Ot[64][66];
    int tid = threadIdx.x;
    int iy = blockIdx.x / 11, j0 = (blockIdx.x % 11) * 32;
    int wv = tid >> 6, lane = tid & 63;
    int quad = lane >> 4, l16 = lane & 15;

    int row = wv * 16 + l16;
    int b = row & 1, p = row >> 1;
    int rz[5];
#pragma unroll
    for (int z = 0; z < 5; ++z)
        rz[z] = v2r[((b * Z1D + z) * Y1D + iy) * X1D + j0 + p];

#pragma unroll 1
    for (int ky = 0; ky < 2; ++ky) {
#pragma unroll 1
        for (int kx = 0; kx < 2; ++kx) {
            const __half* wk = wtT + (size_t)(ky * 2 + kx) * 64 * 320;
            f32x4 acc[4] = {};
#pragma unroll
            for (int ks = 0; ks < 10; ++ks) {
                int z = ks >> 1, hf = ks & 1;
                uint4 u = {0u,0u,0u,0u};
                int r = rz[z];
                if (r >= 0) u = *(const uint4*)(f1 + (size_t)r * 64 + hf * 32 + quad * 8);
                f16x8 a = *(f16x8*)&u;
#pragma unroll
                for (int nt = 0; nt < 4; ++nt) {
                    f16x8 bf = *(const f16x8*)(wk + (size_t)(nt * 16 + l16) * 320 + ks * 32 + quad * 8);
                    acc[nt] = __builtin_amdgcn_mfma_f32_16x16x32_f16(a, bf, acc[nt], 0, 0, 0);
                }
            }
            // BN + ReLU in-place
#pragma unroll
            for (int nt = 0; nt < 4; ++nt) {
                int co = nt * 16 + l16;
                float s  = bnp[co] * rsqrtf(bnp[192 + co] + 1e-5f);
                float sh = (bias[co] - bnp[128 + co]) * s + bnp[64 + co];
#pragma unroll
                for (int r_ = 0; r_ < 4; ++r_)
                    acc[nt][r_] = fmaxf(acc[nt][r_] * s + sh, 0.f);
            }
            // lane-local pair attention
#pragma unroll
            for (int jj = 0; jj < 2; ++jj) {
                float s00 = 0.f, s01 = 0.f;
#pragma unroll
                for (int nt = 0; nt < 4; ++nt) {
                    float xv0 = acc[nt][2 * jj], xv1 = acc[nt][2 * jj + 1];
                    s00 += xv0 * xv0;
                    s01 += xv0 * xv1;
                }
#pragma unroll
                for (int o = 8; o > 0; o >>= 1) {
                    s00 += __shfl_xor(s00, o);
                    s01 += __shfl_xor(s01, o);
                }
                float a0 = s00 * 0.125f, a1 = s01 * 0.125f;
                float mx = fmaxf(a0, a1);
                float e0 = expf(a0 - mx), e1 = expf(a1 - mx);
                float inv = 1.f / (e0 + e1);
                int pl = wv * 8 + quad * 2 + jj;    // 0..31
#pragma unroll
                for (int nt = 0; nt < 4; ++nt)
                    Ot[nt * 16 + l16][2 * pl + kx] =
                        (e0 * acc[nt][2 * jj] + e1 * acc[nt][2 * jj + 1]) * inv;
            }
        }
        __syncthreads();
        int yo = 2 * iy + ky;
#pragma unroll
        for (int i = 0; i < 16; ++i) {
            int idx = i * 256 + tid;
            int co = idx >> 6, xx = idx & 63;
            out[(size_t)co * HWOUT + (size_t)yo * XD + 2 * j0 + xx] = Ot[co][xx];
        }
        __syncthreads();
    }
}

// ---------------------------------------------------------------------------
extern "C" void kernel_launch(void* const* d_in, const int* in_sizes, int n_in,
                              void* d_out, int out_size, void* d_ws, size_t ws_size,
                              hipStream_t stream) {
    const float* sp    = (const float*)d_in[0];
    const float* w_in  = (const float*)d_in[1];
    const float* w0    = (const float*)d_in[2];
    const float* bnp0  = (const float*)d_in[3];
    const float* w0a   = (const float*)d_in[4];
    const float* bnp0a = (const float*)d_in[5];
    const float* w0b   = (const float*)d_in[6];
    const float* bnp0b = (const float*)d_in[7];
    const float* w1    = (const float*)d_in[8];
    const float* bnp1  = (const float*)d_in[9];
    const float* w1a   = (const float*)d_in[10];
    const float* bnp1a = (const float*)d_in[11];
    const float* w1b   = (const float*)d_in[12];
    const float* bnp1b = (const float*)d_in[13];
    const float* ct0w  = (const float*)d_in[14];
    const float* ct0b  = (const float*)d_in[15];
    const float* bnt0  = (const float*)d_in[16];
    const float* ct1w  = (const float*)d_in[17];
    const float* ct1b  = (const float*)d_in[18];
    const float* bnt1  = (const float*)d_in[19];
    const int* coords0 = (const int*)d_in[20];
    const int* coords1 = (const int*)d_in[21];
    const int* g0 = (const int*)d_in[22];
    const int* s0 = (const int*)d_in[23];
    const int* ga = (const int*)d_in[24];
    const int* sa = (const int*)d_in[25];
    const int* g1 = (const int*)d_in[26];
    const int* s1 = (const int*)d_in[27];
    const int* gb = (const int*)d_in[28];
    const int* sb = (const int*)d_in[29];
    float* out = (float*)d_out;

    // -------- workspace carve --------
    __half* fInH = (__half*)d_ws;
    __half* R1h  = fInH + 640000;
    __half* R2h  = R1h + 22528000;
    __half* wt0  = R2h + 22528000;
    __half* wt0a = wt0  + 27648;
    __half* wt0b = wt0a + 27648;
    __half* wt1  = wt0b + 27648;          // [27][64][32]
    __half* wt1a = wt1  + 55296;          // [27][64][64]
    __half* wt1b = wt1a + 110592;
    __half* wtT0 = wt1b + 110592;         // [64][320]
    __half* wtT1 = wtT0 + 20480;          // [4][64][320]
    int*   nbrT = (int*)(wtT1 + 81920);   // 27*CAP0C ints = 14,580,000
    int*   v2r0 = nbrT;                          // 2,816,000 ints (aliases)
    int*   v2r1 = nbrT + 2816000;                //   352,000 ints (aliases)
    int*   nAct = nbrT + 14580000;               // 2 ints, beyond nbrT region

    // 0) weight conversion + n_act (binary search on coords pad boundary)
    find_nact<<<1, 128, 0, stream>>>(coords0, coords1, nAct);
    cvt_w<<<(27*32*32 + 255) / 256, 256, 0, stream>>>(w0,  wt0,  32, 32);
    cvt_w<<<(27*32*32 + 255) / 256, 256, 0, stream>>>(w0a, wt0a, 32, 32);
    cvt_w<<<(27*32*32 + 255) / 256, 256, 0, stream>>>(w0b, wt0b, 32, 32);
    cvt_w<<<(27*32*64 + 255) / 256, 256, 0, stream>>>(w1,  wt1,  32, 64);
    cvt_w<<<(27*64*64 + 255) / 256, 256, 0, stream>>>(w1a, wt1a, 64, 64);
    cvt_w<<<(27*64*64 + 255) / 256, 256, 0, stream>>>(w1b, wt1b, 64, 64);
    cvt_ct0<<<(64*320 + 255) / 256, 256, 0, stream>>>(ct0w, wtT0);
    cvt_ct1<<<(4*64*320 + 255) / 256, 256, 0, stream>>>(ct1w, wtT1);

    // 1) input channel lift (f16 rows out)
    gemm_in<<<(N_PTS_IN * 8 + 255) / 256, 256, 0, stream>>>(sp, w_in, fInH);

    // 2) conv0 (stride-1 spconv, 32->32): fInH -> R1h
    hipMemsetAsync(nbrT, 0xFF, (size_t)CAP0C * 27 * 4, stream);
    build_nbr<<<(27 * N_PTS_IN + 255) / 256, 256, 0, stream>>>(g0, s0, nbrT, N_PTS_IN, CAP0C);
    spconv_reg<32, 32><<<(CAP0C + 127) / 128, 256, 0, stream>>>(fInH, wt0, bnp0, nbrT, R1h, CAP0C, nAct + 0);

    // 3) subm a/b (32->32), shared rulebook: R1h -> R2h -> R1h
    hipMemsetAsync(nbrT, 0xFF, (size_t)CAP0C * 27 * 4, stream);
    build_nbr<<<(27 * CAP0C + 255) / 256, 256, 0, stream>>>(ga, sa, nbrT, CAP0C, CAP0C);
    spconv_reg<32, 32><<<(CAP0C + 127) / 128, 256, 0, stream>>>(R1h, wt0a, bnp0a, nbrT, R2h, CAP0C, nAct + 0);
    spconv_reg<32, 32><<<(CAP0C + 127) / 128, 256, 0, stream>>>(R2h, wt0b, bnp0b, nbrT, R1h, CAP0C, nAct + 0);

    // 4) BEV head 0 (reads R1h) -> out channels [0,64)
    hipMemsetAsync(v2r0, 0xFF, (size_t)2816000 * 4, stream);
    build_vox<<<(CAP0C + 255) / 256, 256, 0, stream>>>(coords0, v2r0, CAP0C, ZD, YD, XD);
    bev0_mfma<<<YD * 11, 256, 0, stream>>>(R1h, wtT0, ct0b, bnt0, v2r0, out);

    // 5) conv1 (stride-2 spconv, 32->64): R1h -> R2h
    hipMemsetAsync(nbrT, 0xFF, (size_t)CAP1C * 27 * 4, stream);
    build_nbr<<<(27 * CAP0C + 255) / 256, 256, 0, stream>>>(g1, s1, nbrT, CAP0C, CAP1C);
    spconv_reg<32, 64><<<(CAP1C + 127) / 128, 256, 0, stream>>>(R1h, wt1, bnp1, nbrT, R2h, CAP1C, nAct + 1);

    // 6) subm 1a/1b (64->64), shared rulebook: R2h -> R1h -> R2h
    hipMemsetAsync(nbrT, 0xFF, (size_t)CAP1C * 27 * 4, stream);
    build_nbr<<<(27 * CAP1C + 255) / 256, 256, 0, stream>>>(gb, sb, nbrT, CAP1C, CAP1C);
    spconv_reg<64, 64><<<(CAP1C + 127) / 128, 256, 0, stream>>>(R2h, wt1a, bnp1a, nbrT, R1h, CAP1C, nAct + 1);
    spconv_reg<64, 64><<<(CAP1C + 127) / 128, 256, 0, stream>>>(R1h, wt1b, bnp1b, nbrT, R2h, CAP1C, nAct + 1);

    // 7) BEV head 1 (reads R2h) -> out channels [64,128)
    hipMemsetAsync(v2r1, 0xFF, (size_t)352000 * 4, stream);
    build_vox<<<(CAP1C + 255) / 256, 256, 0, stream>>>(coords1, v2r1, CAP1C, Z1D, Y1D, X1D);
    bev1_mfma<<<Y1D * 11, 256, 0, stream>>>(R2h, wtT1, ct1b, bnt1, v2r1, out + (size_t)64 * HWOUT);
}

// Round 9
// 945.425 us; speedup vs baseline: 3.1815x; 1.0337x over previous
//
#include <hip/hip_runtime.h>
#include <hip/hip_bf16.h>
#include <hip/hip_fp16.h>

// Problem constants
#define N_PTS_IN   20000
#define CAP0C      540000
#define CAP1C      352000
#define ZD 10
#define YD 200
#define XD 704
#define Z1D 5
#define Y1D 100
#define X1D 352
#define HWOUT (YD*XD)   // 140800

typedef _Float16 f16x8 __attribute__((ext_vector_type(8)));
typedef float    f32x4 __attribute__((ext_vector_type(4)));

// ---------------------------------------------------------------------------
// f_in = sp_feats @ w_in   (20000x64 @ 64x32), f16 output rows
__global__ __launch_bounds__(256) void gemm_in(const float* __restrict__ sp,
                                               const float* __restrict__ w,
                                               __half* __restrict__ fout) {
    int tid = blockIdx.x * 256 + threadIdx.x;
    int row = tid >> 3;
    int c4  = (tid & 7) * 4;
    if (row >= N_PTS_IN) return;
    float4 acc = {0.f, 0.f, 0.f, 0.f};
    const float* sr = sp + (size_t)row * 64;
#pragma unroll
    for (int ci = 0; ci < 64; ci += 4) {
        float4 fv = *(const float4*)(sr + ci);
        const float* wp = w + ci * 32 + c4;
        float4 w0 = *(const float4*)(wp);
        float4 w1 = *(const float4*)(wp + 32);
        float4 w2 = *(const float4*)(wp + 64);
        float4 w3 = *(const float4*)(wp + 96);
        acc.x += fv.x*w0.x + fv.y*w1.x + fv.z*w2.x + fv.w*w3.x;
        acc.y += fv.x*w0.y + fv.y*w1.y + fv.z*w2.y + fv.w*w3.y;
        acc.z += fv.x*w0.z + fv.y*w1.z + fv.z*w2.z + fv.w*w3.z;
        acc.w += fv.x*w0.w + fv.y*w1.w + fv.z*w2.w + fv.w*w3.w;
    }
    __half* fo = fout + (size_t)row * 32 + c4;
    fo[0] = __float2half(acc.x);
    fo[1] = __float2half(acc.y);
    fo[2] = __float2half(acc.z);
    fo[3] = __float2half(acc.w);
}

// ---------------------------------------------------------------------------
// Weight convert+transpose: src f32 [27][CIN][COUT] -> dst f16 [27][COUT][CIN]
__global__ __launch_bounds__(256) void cvt_w(const float* __restrict__ src,
                                             __half* __restrict__ dst,
                                             int CIN, int COUT) {
    int i = blockIdx.x * 256 + threadIdx.x;
    if (i >= 27 * CIN * COUT) return;
    int ci = i % CIN;
    int t  = i / CIN;
    int co = t % COUT;
    int k  = t / COUT;
    dst[i] = __float2half(src[((size_t)k * CIN + ci) * COUT + co]);
}

// ct0_w f32 [320][64] (ci=c*10+z) -> f16 [co][zc=z*32+c]
__global__ __launch_bounds__(256) void cvt_ct0(const float* __restrict__ src,
                                               __half* __restrict__ dst) {
    int i = blockIdx.x * 256 + threadIdx.x;
    if (i >= 64 * 320) return;
    int zc = i % 320, co = i / 320;
    int z = zc >> 5, c = zc & 31;
    dst[i] = __float2half(src[(c * 10 + z) * 64 + co]);
}

// ct1_w f32 [320][64][2][2] (ci=c*5+z) -> f16 [kq][co][zc=z*64+c]
__global__ __launch_bounds__(256) void cvt_ct1(const float* __restrict__ src,
                                               __half* __restrict__ dst) {
    int i = blockIdx.x * 256 + threadIdx.x;
    if (i >= 4 * 64 * 320) return;
    int zc = i % 320;
    int t  = i / 320;
    int co = t & 63;
    int kq = t >> 6;
    int z = zc >> 6, c = zc & 63;
    dst[i] = __float2half(src[((c * 5 + z) * 64 + co) * 4 + kq]);
}

// ---------------------------------------------------------------------------
// Rulebook inversion, TRANSPOSED: nbrT[k*cap + s] = g. Scatter-only.
__global__ __launch_bounds__(256) void build_nbr(const int* __restrict__ g,
                                                 const int* __restrict__ s,
                                                 int* __restrict__ nbrT,
                                                 int P, int cap) {
    int i = blockIdx.x * 256 + threadIdx.x;
    if (i >= 27 * P) return;
    int k = i / P, p = i - k * P;
    int sv = s[(size_t)k * P + p];
    if (sv >= cap) return;              // dummy pair
    nbrT[(size_t)k * cap + sv] = g[(size_t)k * P + p];
}

// ---------------------------------------------------------------------------
// n_act via binary search on the coords pad boundary (z == Zdim marks pad).
__global__ __launch_bounds__(128) void find_nact(const int* __restrict__ c0,
                                                 const int* __restrict__ c1,
                                                 int* __restrict__ nA) {
    int t = threadIdx.x;
    if (t == 0) {
        int lo = 0, hi = CAP0C;
        while (lo < hi) {
            int mid = (lo + hi) >> 1;
            if (c0[4 * mid + 1] >= ZD) hi = mid; else lo = mid + 1;
        }
        nA[0] = lo;
    } else if (t == 64) {
        int lo = 0, hi = CAP1C;
        while (lo < hi) {
            int mid = (lo + hi) >> 1;
            if (c1[4 * mid + 1] >= Z1D) hi = mid; else lo = mid + 1;
        }
        nA[1] = lo;
    }
}

// voxel -> sparse-row index (pad coords have z == Zdim, dropped like JAX OOB)
__global__ __launch_bounds__(256) void build_vox(const int* __restrict__ coords,
                                                 int* __restrict__ v2r,
                                                 int cap, int Zdim, int Ydim, int Xdim) {
    int r = blockIdx.x * 256 + threadIdx.x;
    if (r >= cap) return;
    int b = coords[4*r], z = coords[4*r+1], y = coords[4*r+2], x = coords[4*r+3];
    if (z >= Zdim) return;
    v2r[(((size_t)b * Zdim + z) * Ydim + y) * Xdim + x] = r;
}

// ---------------------------------------------------------------------------
// Implicit-GEMM sparse conv via f16 MFMA 16x16x32, + BN + ReLU.
// v13 structure (weights-via-LDS + dead-block early exit) -- unchanged.
template <int CIN, int COUT>
__global__ __launch_bounds__(256) void spconv_reg(const __half* __restrict__ f,
                                                  const __half* __restrict__ wt,
                                                  const float* __restrict__ bnp,
                                                  const int* __restrict__ nbrT,
                                                  __half* __restrict__ fout,
                                                  int ncap,
                                                  const int* __restrict__ nA) {
    constexpr int NT = COUT / 16;       // 16-col output tiles
    constexpr int KT = CIN / 32;        // K=32 MFMA steps per k-offset
    constexpr int NCHUNK = CIN / 8;     // 16B chunks per weight row
    constexpr int MASK = NCHUNK - 1;
    constexpr int LCH  = (NCHUNK == 8) ? 3 : 2;
    constexpr int TILE_H = COUT * CIN;  // halves per weight tile
    constexpr int TB = TILE_H * 2 / 256; // stage bytes per thread (8/16/32)
    constexpr int OST_H = 4 * 32 * COUT;
    constexpr int SH_H = (2 * TILE_H > OST_H) ? 2 * TILE_H : OST_H;
    __shared__ __align__(16) __half S[SH_H];

    int tid = threadIdx.x;
    int wv = tid >> 6, lane = tid & 63;
    int quad = lane >> 4, l16 = lane & 15;

    // interleaved-group XCD swizzle (live-prefix-safe, bijective)
    int bid = blockIdx.x;
    int nfull = (int)gridDim.x & ~63;
    int sb;
    if (bid < nfull) {
        int grp = bid >> 6, w = bid & 63;
        sb = grp * 64 + (w & 7) * 8 + (w >> 3);
    } else {
        sb = bid;
    }

    // dead-block early exit: rows >= n_act have no pairs for any k
    if (sb * 128 >= *nA) return;

    int m0 = sb * 128 + wv * 32;       // wave's first output row
    int r0 = m0 + l16;                 // this lane's row for m=0
    int r1 = m0 + 16 + l16;            // this lane's row for m=1
    bool ok0 = r0 < ncap, ok1 = r1 < ncap;

    f32x4 acc[2][NT] = {};

    // index pipeline depth 2
    int gC0 = ok0 ? nbrT[r0] : -1;
    int gC1 = ok1 ? nbrT[r1] : -1;
    int gN0 = ok0 ? nbrT[(size_t)ncap + r0] : -1;
    int gN1 = ok1 ? nbrT[(size_t)ncap + r1] : -1;
    bool ever = false;

    // ---- prologue: stage weight tile k=0 into buffer 0 ----
    {
        const char* src = (const char*)(wt) + tid * TB;
        if constexpr (TB == 32) {
            uint4 w0 = *(const uint4*)src;
            uint4 w1 = *(const uint4*)(src + 16);
            int p0 = tid * 2;
#pragma unroll
            for (int j = 0; j < 2; ++j) {
                int p = p0 + j;
                int row = p >> LCH, c = p & MASK;
                *(uint4*)(S + (row * NCHUNK + (c ^ (row & MASK))) * 8) = (j ? w1 : w0);
            }
        } else if constexpr (TB == 16) {
            uint4 w0 = *(const uint4*)src;
            int p = tid;
            int row = p >> LCH, c = p & MASK;
            *(uint4*)(S + (row * NCHUNK + (c ^ (row & MASK))) * 8) = w0;
        } else {
            uint2 w0 = *(const uint2*)src;
            int p = tid >> 1, half = tid & 1;
            int row = p >> LCH, c = p & MASK;
            *(uint2*)(S + (row * NCHUNK + (c ^ (row & MASK))) * 8 + half * 4) = w0;
        }
    }
    __syncthreads();

#pragma unroll 1
    for (int k = 0; k < 27; ++k) {
        // (1) idx k+2 (oldest in-flight: retired before barrier drain)
        int gNN0 = -1, gNN1 = -1;
        if (k + 2 < 27) {
            if (ok0) gNN0 = nbrT[(size_t)(k + 2) * ncap + r0];
            if (ok1) gNN1 = nbrT[(size_t)(k + 2) * ncap + r1];
        }
        // (2) gathers k -> regs
        bool anyC = __ballot((gC0 >= 0) || (gC1 >= 0)) != 0ull;
        f16x8 a0[KT], a1[KT];
        if (anyC) {
            const __half* p0 = f + (size_t)((gC0 < 0) ? 0 : gC0) * CIN + quad * 8;
            const __half* p1 = f + (size_t)((gC1 < 0) ? 0 : gC1) * CIN + quad * 8;
#pragma unroll
            for (int kt = 0; kt < KT; ++kt) {
                uint4 u0 = {0u,0u,0u,0u}, u1 = {0u,0u,0u,0u};
                if (gC0 >= 0) u0 = *(const uint4*)(p0 + kt * 32);
                if (gC1 >= 0) u1 = *(const uint4*)(p1 + kt * 32);
                a0[kt] = *(f16x8*)&u0;
                a1[kt] = *(f16x8*)&u1;
            }
        }
        // (3) stage loads for k+1 -> regs (youngest: stays in flight
        //     across the MFMA's gather-wait)
        bool doStage = (k + 1 < 27);
        uint4 w0{}, w1{}; uint2 w2{};
        if (doStage) {
            const char* src = (const char*)(wt + (size_t)(k + 1) * TILE_H) + tid * TB;
            if constexpr (TB == 32)      { w0 = *(const uint4*)src; w1 = *(const uint4*)(src + 16); }
            else if constexpr (TB == 16) { w0 = *(const uint4*)src; }
            else                         { w2 = *(const uint2*)src; }
        }
        // (4) ds_read B + (5) MFMA
        if (anyC) {
            ever = true;
            const __half* Wb = S + (k & 1) * TILE_H;
#pragma unroll
            for (int kt = 0; kt < KT; ++kt) {
#pragma unroll
                for (int nt = 0; nt < NT; ++nt) {
                    int row = nt * 16 + l16;
                    int c   = kt * 4 + quad;
                    f16x8 b = *(const f16x8*)(Wb + (row * NCHUNK + (c ^ (row & MASK))) * 8);
                    acc[0][nt] = __builtin_amdgcn_mfma_f32_16x16x32_f16(a0[kt], b, acc[0][nt], 0, 0, 0);
                    acc[1][nt] = __builtin_amdgcn_mfma_f32_16x16x32_f16(a1[kt], b, acc[1][nt], 0, 0, 0);
                }
            }
        }
        // (6) ds_write staging into the other buffer
        if (doStage) {
            __half* dst = S + ((k + 1) & 1) * TILE_H;
            if constexpr (TB == 32) {
                int p0 = tid * 2;
#pragma unroll
                for (int j = 0; j < 2; ++j) {
                    int p = p0 + j;
                    int row = p >> LCH, c = p & MASK;
                    *(uint4*)(dst + (row * NCHUNK + (c ^ (row & MASK))) * 8) = (j ? w1 : w0);
                }
            } else if constexpr (TB == 16) {
                int p = tid;
                int row = p >> LCH, c = p & MASK;
                *(uint4*)(dst + (row * NCHUNK + (c ^ (row & MASK))) * 8) = w0;
            } else {
                int p = tid >> 1, half = tid & 1;
                int row = p >> LCH, c = p & MASK;
                *(uint2*)(dst + (row * NCHUNK + (c ^ (row & MASK))) * 8 + half * 4) = w2;
            }
        }
        __syncthreads();
        gC0 = gN0; gC1 = gN1; gN0 = gNN0; gN1 = gNN1;
    }

    // epilogue: BN + ReLU -> wave-private LDS (weight bufs dead) -> store.
    if (!ever) return;
    __half* O = S + wv * (32 * COUT);
#pragma unroll
    for (int nt = 0; nt < NT; ++nt) {
        int co = nt * 16 + l16;
        float g = bnp[co], b = bnp[COUT + co];
        float mn = bnp[2*COUT + co], vv = bnp[3*COUT + co];
        float s  = g * rsqrtf(vv + 1e-5f);
        float sh = b - mn * s;
#pragma unroll
        for (int m = 0; m < 2; ++m)
#pragma unroll
            for (int r_ = 0; r_ < 4; ++r_) {
                int row = m * 16 + quad * 4 + r_;
                O[row * COUT + co] = __float2half(fmaxf(acc[m][nt][r_] * s + sh, 0.f));
            }
    }
    constexpr int OCH = COUT / 8;              // 16B chunks per out row
#pragma unroll
    for (int j = 0; j < 32 * OCH / 64; ++j) {
        int idx = j * 64 + lane;
        int r = idx / OCH, c = idx % OCH;
        if (m0 + r < ncap)
            *(uint4*)(fout + (size_t)(m0 + r) * COUT + c * 8) =
                *(const uint4*)(O + r * COUT + c * 8);
    }
}

// ---------------------------------------------------------------------------
// BEV head 0, v14: registers-only. 64 px per block (2200 blocks). Unchanged.
__global__ __launch_bounds__(256) void bev0_mfma(const __half* __restrict__ f0,
                                                 const __half* __restrict__ wtT,  // [64][320] zc=z*32+c
                                                 const float* __restrict__ bias,
                                                 const float* __restrict__ bnp,
                                                 const int* __restrict__ v2r,
                                                 float* __restrict__ out) {
    __shared__ float Ot[64][66];
    int tid = threadIdx.x;
    int y = blockIdx.x / 11, x0 = (blockIdx.x % 11) * 64;
    int wv = tid >> 6, lane = tid & 63;
    int quad = lane >> 4, l16 = lane & 15;

    // v2r preload: 2 m-tiles x 10 z-slices (static-indexed -> registers)
    int rz[2][10];
#pragma unroll
    for (int m = 0; m < 2; ++m) {
        int row = wv * 32 + m * 16 + l16;
        int b = row & 1, p = row >> 1;
#pragma unroll
        for (int z = 0; z < 10; ++z)
            rz[m][z] = v2r[((b * ZD + z) * YD + y) * XD + x0 + p];
    }

    f32x4 acc[2][4] = {};
#pragma unroll
    for (int ks = 0; ks < 10; ++ks) {
        f16x8 a[2];
#pragma unroll
        for (int m = 0; m < 2; ++m) {
            uint4 u = {0u,0u,0u,0u};
            int r = rz[m][ks];
            if (r >= 0) u = *(const uint4*)(f0 + (size_t)r * 32 + quad * 8);
            a[m] = *(f16x8*)&u;
        }
#pragma unroll
        for (int nt = 0; nt < 4; ++nt) {
            f16x8 b = *(const f16x8*)(wtT + (size_t)(nt * 16 + l16) * 320 + ks * 32 + quad * 8);
            acc[0][nt] = __builtin_amdgcn_mfma_f32_16x16x32_f16(a[0], b, acc[0][nt], 0, 0, 0);
            acc[1][nt] = __builtin_amdgcn_mfma_f32_16x16x32_f16(a[1], b, acc[1][nt], 0, 0, 0);
        }
    }

    // BN + ReLU in-place (channels are lane-local: co = nt*16 + l16)
#pragma unroll
    for (int nt = 0; nt < 4; ++nt) {
        int co = nt * 16 + l16;
        float s  = bnp[co] * rsqrtf(bnp[192 + co] + 1e-5f);
        float sh = (bias[co] - bnp[128 + co]) * s + bnp[64 + co];
#pragma unroll
        for (int m = 0; m < 2; ++m)
#pragma unroll
            for (int r_ = 0; r_ < 4; ++r_)
                acc[m][nt][r_] = fmaxf(acc[m][nt][r_] * s + sh, 0.f);
    }

    // lane-local pair attention: rows 2jj/2jj+1 of each quad-block are the
    // two agents of one pixel; channel sum = 4 lane-local + 16-lane reduce.
#pragma unroll
    for (int m = 0; m < 2; ++m)
#pragma unroll
        for (int jj = 0; jj < 2; ++jj) {
            float s00 = 0.f, s01 = 0.f;
#pragma unroll
            for (int nt = 0; nt < 4; ++nt) {
                float xv0 = acc[m][nt][2 * jj], xv1 = acc[m][nt][2 * jj + 1];
                s00 += xv0 * xv0;
                s01 += xv0 * xv1;
            }
#pragma unroll
            for (int o = 8; o > 0; o >>= 1) {
                s00 += __shfl_xor(s00, o);
                s01 += __shfl_xor(s01, o);
            }
            float a0 = s00 * 0.125f, a1 = s01 * 0.125f;
            float mx = fmaxf(a0, a1);
            float e0 = expf(a0 - mx), e1 = expf(a1 - mx);
            float inv = 1.f / (e0 + e1);
            int pl = wv * 16 + m * 8 + quad * 2 + jj;
#pragma unroll
            for (int nt = 0; nt < 4; ++nt)
                Ot[nt * 16 + l16][pl] =
                    (e0 * acc[m][nt][2 * jj] + e1 * acc[m][nt][2 * jj + 1]) * inv;
        }
    __syncthreads();

#pragma unroll
    for (int i = 0; i < 16; ++i) {
        int idx = i * 256 + tid;
        int co = idx >> 6, px = idx & 63;
        out[(size_t)co * HWOUT + (size_t)y * XD + x0 + px] = Ot[co][px];
    }
}

// ---------------------------------------------------------------------------
// BEV head 1, v15: A gathered ONCE into registers (10 x f16x8), both kx
// positions consume it; ky split across blocks (grid 1100 -> 2200).
// R8 post-mortem: bev1 was per-block-latency-bound (nothing busy, ~all
// blocks co-resident) -- 4 sequential positions x 10 serial gather->MFMA
// chains re-gathered the SAME A 4x. Now: 10 gathers issued together (one
// latency), 3/4 of gathers gone, serial position count 4 -> 2, blocks 2x.
__global__ __launch_bounds__(256) void bev1_mfma(const __half* __restrict__ f1,
                                                 const __half* __restrict__ wtT,  // [4][64][320] zc=z*64+c
                                                 const float* __restrict__ bias,
                                                 const float* __restrict__ bnp,
                                                 const int* __restrict__ v2r,
                                                 float* __restrict__ out) {
    __shared__ float Ot[64][66];
    int tid = threadIdx.x;
    int bid = blockIdx.x;
    int ky = bid & 1;
    int t  = bid >> 1;
    int iy = t / 11, j0 = (t % 11) * 32;
    int wv = tid >> 6, lane = tid & 63;
    int quad = lane >> 4, l16 = lane & 15;

    int row = wv * 16 + l16;
    int b = row & 1, p = row >> 1;
    int rz[5];
#pragma unroll
    for (int z = 0; z < 5; ++z)
        rz[z] = v2r[((b * Z1D + z) * Y1D + iy) * X1D + j0 + p];

    // gather all 10 A fragments once (independent loads, one latency window)
    f16x8 a[10];
#pragma unroll
    for (int ks = 0; ks < 10; ++ks) {
        int z = ks >> 1, hf = ks & 1;
        uint4 u = {0u,0u,0u,0u};
        int r = rz[z];
        if (r >= 0) u = *(const uint4*)(f1 + (size_t)r * 64 + hf * 32 + quad * 8);
        a[ks] = *(f16x8*)&u;
    }

    f32x4 acc[2][4] = {};
#pragma unroll
    for (int kx = 0; kx < 2; ++kx) {
        const __half* wk = wtT + (size_t)(ky * 2 + kx) * 64 * 320;
#pragma unroll
        for (int ks = 0; ks < 10; ++ks)
#pragma unroll
            for (int nt = 0; nt < 4; ++nt) {
                f16x8 bf = *(const f16x8*)(wk + (size_t)(nt * 16 + l16) * 320 + ks * 32 + quad * 8);
                acc[kx][nt] = __builtin_amdgcn_mfma_f32_16x16x32_f16(a[ks], bf, acc[kx][nt], 0, 0, 0);
            }
    }

    // BN + ReLU in-place, then lane-local pair attention per kx
#pragma unroll
    for (int kx = 0; kx < 2; ++kx) {
#pragma unroll
        for (int nt = 0; nt < 4; ++nt) {
            int co = nt * 16 + l16;
            float s  = bnp[co] * rsqrtf(bnp[192 + co] + 1e-5f);
            float sh = (bias[co] - bnp[128 + co]) * s + bnp[64 + co];
#pragma unroll
            for (int r_ = 0; r_ < 4; ++r_)
                acc[kx][nt][r_] = fmaxf(acc[kx][nt][r_] * s + sh, 0.f);
        }
#pragma unroll
        for (int jj = 0; jj < 2; ++jj) {
            float s00 = 0.f, s01 = 0.f;
#pragma unroll
            for (int nt = 0; nt < 4; ++nt) {
                float xv0 = acc[kx][nt][2 * jj], xv1 = acc[kx][nt][2 * jj + 1];
                s00 += xv0 * xv0;
                s01 += xv0 * xv1;
            }
#pragma unroll
            for (int o = 8; o > 0; o >>= 1) {
                s00 += __shfl_xor(s00, o);
                s01 += __shfl_xor(s01, o);
            }
            float a0 = s00 * 0.125f, a1 = s01 * 0.125f;
            float mx = fmaxf(a0, a1);
            float e0 = expf(a0 - mx), e1 = expf(a1 - mx);
            float inv = 1.f / (e0 + e1);
            int pl = wv * 8 + quad * 2 + jj;    // 0..31
#pragma unroll
            for (int nt = 0; nt < 4; ++nt)
                Ot[nt * 16 + l16][2 * pl + kx] =
                    (e0 * acc[kx][nt][2 * jj] + e1 * acc[kx][nt][2 * jj + 1]) * inv;
        }
    }
    __syncthreads();

    int yo = 2 * iy + ky;
#pragma unroll
    for (int i = 0; i < 16; ++i) {
        int idx = i * 256 + tid;
        int co = idx >> 6, xx = idx & 63;
        out[(size_t)co * HWOUT + (size_t)yo * XD + 2 * j0 + xx] = Ot[co][xx];
    }
}

// ---------------------------------------------------------------------------
extern "C" void kernel_launch(void* const* d_in, const int* in_sizes, int n_in,
                              void* d_out, int out_size, void* d_ws, size_t ws_size,
                              hipStream_t stream) {
    const float* sp    = (const float*)d_in[0];
    const float* w_in  = (const float*)d_in[1];
    const float* w0    = (const float*)d_in[2];
    const float* bnp0  = (const float*)d_in[3];
    const float* w0a   = (const float*)d_in[4];
    const float* bnp0a = (const float*)d_in[5];
    const float* w0b   = (const float*)d_in[6];
    const float* bnp0b = (const float*)d_in[7];
    const float* w1    = (const float*)d_in[8];
    const float* bnp1  = (const float*)d_in[9];
    const float* w1a   = (const float*)d_in[10];
    const float* bnp1a = (const float*)d_in[11];
    const float* w1b   = (const float*)d_in[12];
    const float* bnp1b = (const float*)d_in[13];
    const float* ct0w  = (const float*)d_in[14];
    const float* ct0b  = (const float*)d_in[15];
    const float* bnt0  = (const float*)d_in[16];
    const float* ct1w  = (const float*)d_in[17];
    const float* ct1b  = (const float*)d_in[18];
    const float* bnt1  = (const float*)d_in[19];
    const int* coords0 = (const int*)d_in[20];
    const int* coords1 = (const int*)d_in[21];
    const int* g0 = (const int*)d_in[22];
    const int* s0 = (const int*)d_in[23];
    const int* ga = (const int*)d_in[24];
    const int* sa = (const int*)d_in[25];
    const int* g1 = (const int*)d_in[26];
    const int* s1 = (const int*)d_in[27];
    const int* gb = (const int*)d_in[28];
    const int* sb = (const int*)d_in[29];
    float* out = (float*)d_out;

    // -------- workspace carve --------
    __half* fInH = (__half*)d_ws;
    __half* R1h  = fInH + 640000;
    __half* R2h  = R1h + 22528000;
    __half* wt0  = R2h + 22528000;
    __half* wt0a = wt0  + 27648;
    __half* wt0b = wt0a + 27648;
    __half* wt1  = wt0b + 27648;          // [27][64][32]
    __half* wt1a = wt1  + 55296;          // [27][64][64]
    __half* wt1b = wt1a + 110592;
    __half* wtT0 = wt1b + 110592;         // [64][320]
    __half* wtT1 = wtT0 + 20480;          // [4][64][320]
    int*   nbrT = (int*)(wtT1 + 81920);   // 27*CAP0C ints = 14,580,000
    int*   v2r0 = nbrT;                          // 2,816,000 ints (aliases)
    int*   v2r1 = nbrT + 2816000;                //   352,000 ints (aliases)
    int*   nAct = nbrT + 14580000;               // 2 ints, beyond nbrT region

    // 0) weight conversion + n_act (binary search on coords pad boundary)
    find_nact<<<1, 128, 0, stream>>>(coords0, coords1, nAct);
    cvt_w<<<(27*32*32 + 255) / 256, 256, 0, stream>>>(w0,  wt0,  32, 32);
    cvt_w<<<(27*32*32 + 255) / 256, 256, 0, stream>>>(w0a, wt0a, 32, 32);
    cvt_w<<<(27*32*32 + 255) / 256, 256, 0, stream>>>(w0b, wt0b, 32, 32);
    cvt_w<<<(27*32*64 + 255) / 256, 256, 0, stream>>>(w1,  wt1,  32, 64);
    cvt_w<<<(27*64*64 + 255) / 256, 256, 0, stream>>>(w1a, wt1a, 64, 64);
    cvt_w<<<(27*64*64 + 255) / 256, 256, 0, stream>>>(w1b, wt1b, 64, 64);
    cvt_ct0<<<(64*320 + 255) / 256, 256, 0, stream>>>(ct0w, wtT0);
    cvt_ct1<<<(4*64*320 + 255) / 256, 256, 0, stream>>>(ct1w, wtT1);

    // 1) input channel lift (f16 rows out)
    gemm_in<<<(N_PTS_IN * 8 + 255) / 256, 256, 0, stream>>>(sp, w_in, fInH);

    // 2) conv0 (stride-1 spconv, 32->32): fInH -> R1h
    hipMemsetAsync(nbrT, 0xFF, (size_t)CAP0C * 27 * 4, stream);
    build_nbr<<<(27 * N_PTS_IN + 255) / 256, 256, 0, stream>>>(g0, s0, nbrT, N_PTS_IN, CAP0C);
    spconv_reg<32, 32><<<(CAP0C + 127) / 128, 256, 0, stream>>>(fInH, wt0, bnp0, nbrT, R1h, CAP0C, nAct + 0);

    // 3) subm a/b (32->32), shared rulebook: R1h -> R2h -> R1h
    hipMemsetAsync(nbrT, 0xFF, (size_t)CAP0C * 27 * 4, stream);
    build_nbr<<<(27 * CAP0C + 255) / 256, 256, 0, stream>>>(ga, sa, nbrT, CAP0C, CAP0C);
    spconv_reg<32, 32><<<(CAP0C + 127) / 128, 256, 0, stream>>>(R1h, wt0a, bnp0a, nbrT, R2h, CAP0C, nAct + 0);
    spconv_reg<32, 32><<<(CAP0C + 127) / 128, 256, 0, stream>>>(R2h, wt0b, bnp0b, nbrT, R1h, CAP0C, nAct + 0);

    // 4) BEV head 0 (reads R1h) -> out channels [0,64)
    hipMemsetAsync(v2r0, 0xFF, (size_t)2816000 * 4, stream);
    build_vox<<<(CAP0C + 255) / 256, 256, 0, stream>>>(coords0, v2r0, CAP0C, ZD, YD, XD);
    bev0_mfma<<<YD * 11, 256, 0, stream>>>(R1h, wtT0, ct0b, bnt0, v2r0, out);

    // 5) conv1 (stride-2 spconv, 32->64): R1h -> R2h
    hipMemsetAsync(nbrT, 0xFF, (size_t)CAP1C * 27 * 4, stream);
    build_nbr<<<(27 * CAP0C + 255) / 256, 256, 0, stream>>>(g1, s1, nbrT, CAP0C, CAP1C);
    spconv_reg<32, 64><<<(CAP1C + 127) / 128, 256, 0, stream>>>(R1h, wt1, bnp1, nbrT, R2h, CAP1C, nAct + 1);

    // 6) subm 1a/1b (64->64), shared rulebook: R2h -> R1h -> R2h
    hipMemsetAsync(nbrT, 0xFF, (size_t)CAP1C * 27 * 4, stream);
    build_nbr<<<(27 * CAP1C + 255) / 256, 256, 0, stream>>>(gb, sb, nbrT, CAP1C, CAP1C);
    spconv_reg<64, 64><<<(CAP1C + 127) / 128, 256, 0, stream>>>(R2h, wt1a, bnp1a, nbrT, R1h, CAP1C, nAct + 1);
    spconv_reg<64, 64><<<(CAP1C + 127) / 128, 256, 0, stream>>>(R1h, wt1b, bnp1b, nbrT, R2h, CAP1C, nAct + 1);

    // 7) BEV head 1 (reads R2h) -> out channels [64,128)
    hipMemsetAsync(v2r1, 0xFF, (size_t)352000 * 4, stream);
    build_vox<<<(CAP1C + 255) / 256, 256, 0, stream>>>(coords1, v2r1, CAP1C, Z1D, Y1D, X1D);
    bev1_mfma<<<Y1D * 11 * 2, 256, 0, stream>>>(R2h, wtT1, ct1b, bnt1, v2r1, out + (size_t)64 * HWOUT);
}

// Round 12
// 935.764 us; speedup vs baseline: 3.2143x; 1.0103x over previous
//
#include <hip/hip_runtime.h>
#include <hip/hip_bf16.h>
#include <hip/hip_fp16.h>

// Problem constants
#define N_PTS_IN   20000
#define CAP0C      540000
#define CAP1C      352000
#define ZD 10
#define YD 200
#define XD 704
#define Z1D 5
#define Y1D 100
#define X1D 352
#define HWOUT (YD*XD)   // 140800

typedef _Float16 f16x8 __attribute__((ext_vector_type(8)));
typedef float    f32x4 __attribute__((ext_vector_type(4)));

// ---------------------------------------------------------------------------
// f_in = sp_feats @ w_in   (20000x64 @ 64x32), f16 output rows
__global__ __launch_bounds__(256) void gemm_in(const float* __restrict__ sp,
                                               const float* __restrict__ w,
                                               __half* __restrict__ fout) {
    int tid = blockIdx.x * 256 + threadIdx.x;
    int row = tid >> 3;
    int c4  = (tid & 7) * 4;
    if (row >= N_PTS_IN) return;
    float4 acc = {0.f, 0.f, 0.f, 0.f};
    const float* sr = sp + (size_t)row * 64;
#pragma unroll
    for (int ci = 0; ci < 64; ci += 4) {
        float4 fv = *(const float4*)(sr + ci);
        const float* wp = w + ci * 32 + c4;
        float4 w0 = *(const float4*)(wp);
        float4 w1 = *(const float4*)(wp + 32);
        float4 w2 = *(const float4*)(wp + 64);
        float4 w3 = *(const float4*)(wp + 96);
        acc.x += fv.x*w0.x + fv.y*w1.x + fv.z*w2.x + fv.w*w3.x;
        acc.y += fv.x*w0.y + fv.y*w1.y + fv.z*w2.y + fv.w*w3.y;
        acc.z += fv.x*w0.z + fv.y*w1.z + fv.z*w2.z + fv.w*w3.z;
        acc.w += fv.x*w0.w + fv.y*w1.w + fv.z*w2.w + fv.w*w3.w;
    }
    __half* fo = fout + (size_t)row * 32 + c4;
    fo[0] = __float2half(acc.x);
    fo[1] = __float2half(acc.y);
    fo[2] = __float2half(acc.z);
    fo[3] = __float2half(acc.w);
}

// ---------------------------------------------------------------------------
// Weight convert+transpose: src f32 [27][CIN][COUT] -> dst f16 [27][COUT][CIN]
__global__ __launch_bounds__(256) void cvt_w(const float* __restrict__ src,
                                             __half* __restrict__ dst,
                                             int CIN, int COUT) {
    int i = blockIdx.x * 256 + threadIdx.x;
    if (i >= 27 * CIN * COUT) return;
    int ci = i % CIN;
    int t  = i / CIN;
    int co = t % COUT;
    int k  = t / COUT;
    dst[i] = __float2half(src[((size_t)k * CIN + ci) * COUT + co]);
}

// ct0_w f32 [320][64] (ci=c*10+z) -> f16 [co][zc=z*32+c]
__global__ __launch_bounds__(256) void cvt_ct0(const float* __restrict__ src,
                                               __half* __restrict__ dst) {
    int i = blockIdx.x * 256 + threadIdx.x;
    if (i >= 64 * 320) return;
    int zc = i % 320, co = i / 320;
    int z = zc >> 5, c = zc & 31;
    dst[i] = __float2half(src[(c * 10 + z) * 64 + co]);
}

// ct1_w f32 [320][64][2][2] (ci=c*5+z) -> f16 [kq][co][zc=z*64+c]
__global__ __launch_bounds__(256) void cvt_ct1(const float* __restrict__ src,
                                               __half* __restrict__ dst) {
    int i = blockIdx.x * 256 + threadIdx.x;
    if (i >= 4 * 64 * 320) return;
    int zc = i % 320;
    int t  = i / 320;
    int co = t & 63;
    int kq = t >> 6;
    int z = zc >> 6, c = zc & 63;
    dst[i] = __float2half(src[((c * 5 + z) * 64 + co) * 4 + kq]);
}

// ---------------------------------------------------------------------------
// Rulebook inversion, TRANSPOSED: nbrT[k*cap + s] = g. Scatter-only.
__global__ __launch_bounds__(256) void build_nbr(const int* __restrict__ g,
                                                 const int* __restrict__ s,
                                                 int* __restrict__ nbrT,
                                                 int P, int cap) {
    int i = blockIdx.x * 256 + threadIdx.x;
    if (i >= 27 * P) return;
    int k = i / P, p = i - k * P;
    int sv = s[(size_t)k * P + p];
    if (sv >= cap) return;              // dummy pair
    nbrT[(size_t)k * cap + sv] = g[(size_t)k * P + p];
}

// ---------------------------------------------------------------------------
// n_act via binary search on the coords pad boundary (z == Zdim marks pad).
__global__ __launch_bounds__(128) void find_nact(const int* __restrict__ c0,
                                                 const int* __restrict__ c1,
                                                 int* __restrict__ nA) {
    int t = threadIdx.x;
    if (t == 0) {
        int lo = 0, hi = CAP0C;
        while (lo < hi) {
            int mid = (lo + hi) >> 1;
            if (c0[4 * mid + 1] >= ZD) hi = mid; else lo = mid + 1;
        }
        nA[0] = lo;
    } else if (t == 64) {
        int lo = 0, hi = CAP1C;
        while (lo < hi) {
            int mid = (lo + hi) >> 1;
            if (c1[4 * mid + 1] >= Z1D) hi = mid; else lo = mid + 1;
        }
        nA[1] = lo;
    }
}

// voxel -> sparse-row index (pad coords have z == Zdim, dropped like JAX OOB)
__global__ __launch_bounds__(256) void build_vox(const int* __restrict__ coords,
                                                 int* __restrict__ v2r,
                                                 int cap, int Zdim, int Ydim, int Xdim) {
    int r = blockIdx.x * 256 + threadIdx.x;
    if (r >= cap) return;
    int b = coords[4*r], z = coords[4*r+1], y = coords[4*r+2], x = coords[4*r+3];
    if (z >= Zdim) return;
    v2r[(((size_t)b * Zdim + z) * Ydim + y) * Xdim + x] = r;
}

// ---------------------------------------------------------------------------
// Implicit-GEMM sparse conv via f16 MFMA 16x16x32, + BN + ReLU.
// v17 = v13 + feature-prefetch depth-1 ONLY (bisect of v16: BEV lane-linear
// layout reverted to v15's known-good form).
//   R9 arithmetic: ~2600 cy/wave-iter vs ~700 TA/issue floor -- the gap is
//   gather latency on the critical path. Now: gather k+1's rows during
//   iter k; MFMA consumes registers already drained by the PREVIOUS
//   barrier (zero wait); the new gathers retire at this iter's barrier,
//   overlapped with ds_read+MFMA+ds_write.
template <int CIN, int COUT>
__global__ __launch_bounds__(256) void spconv_reg(const __half* __restrict__ f,
                                                  const __half* __restrict__ wt,
                                                  const float* __restrict__ bnp,
                                                  const int* __restrict__ nbrT,
                                                  __half* __restrict__ fout,
                                                  int ncap,
                                                  const int* __restrict__ nA) {
    constexpr int NT = COUT / 16;       // 16-col output tiles
    constexpr int KT = CIN / 32;        // K=32 MFMA steps per k-offset
    constexpr int NCHUNK = CIN / 8;     // 16B chunks per weight row
    constexpr int MASK = NCHUNK - 1;
    constexpr int LCH  = (NCHUNK == 8) ? 3 : 2;
    constexpr int TILE_H = COUT * CIN;  // halves per weight tile
    constexpr int TB = TILE_H * 2 / 256; // stage bytes per thread (8/16/32)
    constexpr int OST_H = 4 * 32 * COUT;
    constexpr int SH_H = (2 * TILE_H > OST_H) ? 2 * TILE_H : OST_H;
    __shared__ __align__(16) __half S[SH_H];

    int tid = threadIdx.x;
    int wv = tid >> 6, lane = tid & 63;
    int quad = lane >> 4, l16 = lane & 15;

    // interleaved-group XCD swizzle (live-prefix-safe, bijective)
    int bid = blockIdx.x;
    int nfull = (int)gridDim.x & ~63;
    int sb;
    if (bid < nfull) {
        int grp = bid >> 6, w = bid & 63;
        sb = grp * 64 + (w & 7) * 8 + (w >> 3);
    } else {
        sb = bid;
    }

    // dead-block early exit: rows >= n_act have no pairs for any k
    if (sb * 128 >= *nA) return;

    int m0 = sb * 128 + wv * 32;       // wave's first output row
    int r0 = m0 + l16;                 // this lane's row for m=0
    int r1 = m0 + 16 + l16;            // this lane's row for m=1
    bool ok0 = r0 < ncap, ok1 = r1 < ncap;

    f32x4 acc[2][NT] = {};

    // index pipeline depth 2
    int gC0 = ok0 ? nbrT[r0] : -1;
    int gC1 = ok1 ? nbrT[r1] : -1;
    int gN0 = ok0 ? nbrT[(size_t)ncap + r0] : -1;
    int gN1 = ok1 ? nbrT[(size_t)ncap + r1] : -1;
    bool anyC = __ballot((gC0 >= 0) || (gC1 >= 0)) != 0ull;
    bool ever = false;

    // ---- feature prologue: gather k=0 rows into registers ----
    f16x8 aC0[KT], aC1[KT];
#pragma unroll
    for (int kt = 0; kt < KT; ++kt) {
        uint4 z4 = {0u,0u,0u,0u};
        aC0[kt] = *(f16x8*)&z4;
        aC1[kt] = *(f16x8*)&z4;
    }
    if (anyC) {
        const __half* p0 = f + (size_t)((gC0 < 0) ? 0 : gC0) * CIN + quad * 8;
        const __half* p1 = f + (size_t)((gC1 < 0) ? 0 : gC1) * CIN + quad * 8;
#pragma unroll
        for (int kt = 0; kt < KT; ++kt) {
            uint4 u0 = {0u,0u,0u,0u}, u1 = {0u,0u,0u,0u};
            if (gC0 >= 0) u0 = *(const uint4*)(p0 + kt * 32);
            if (gC1 >= 0) u1 = *(const uint4*)(p1 + kt * 32);
            aC0[kt] = *(f16x8*)&u0;
            aC1[kt] = *(f16x8*)&u1;
        }
    }

    // ---- weight prologue: stage tile k=0 into buffer 0 ----
    {
        const char* src = (const char*)(wt) + tid * TB;
        if constexpr (TB == 32) {
            uint4 w0 = *(const uint4*)src;
            uint4 w1 = *(const uint4*)(src + 16);
            int p0 = tid * 2;
#pragma unroll
            for (int j = 0; j < 2; ++j) {
                int p = p0 + j;
                int row = p >> LCH, c = p & MASK;
                *(uint4*)(S + (row * NCHUNK + (c ^ (row & MASK))) * 8) = (j ? w1 : w0);
            }
        } else if constexpr (TB == 16) {
            uint4 w0 = *(const uint4*)src;
            int p = tid;
            int row = p >> LCH, c = p & MASK;
            *(uint4*)(S + (row * NCHUNK + (c ^ (row & MASK))) * 8) = w0;
        } else {
            uint2 w0 = *(const uint2*)src;
            int p = tid >> 1, half = tid & 1;
            int row = p >> LCH, c = p & MASK;
            *(uint2*)(S + (row * NCHUNK + (c ^ (row & MASK))) * 8 + half * 4) = w0;
        }
    }
    __syncthreads();

#pragma unroll 1
    for (int k = 0; k < 27; ++k) {
        // (1) idx k+2 (oldest in-flight)
        int gNN0 = -1, gNN1 = -1;
        if (k + 2 < 27) {
            if (ok0) gNN0 = nbrT[(size_t)(k + 2) * ncap + r0];
            if (ok1) gNN1 = nbrT[(size_t)(k + 2) * ncap + r1];
        }
        // (2) gather k+1 rows -> aN (retired at THIS iter's barrier,
        //     overlapped with ds_read+MFMA+ds_write below)
        bool anyN = __ballot((gN0 >= 0) || (gN1 >= 0)) != 0ull;
        f16x8 aN0[KT], aN1[KT];
#pragma unroll
        for (int kt = 0; kt < KT; ++kt) {
            uint4 z4 = {0u,0u,0u,0u};
            aN0[kt] = *(f16x8*)&z4;
            aN1[kt] = *(f16x8*)&z4;
        }
        if (anyN) {
            const __half* p0 = f + (size_t)((gN0 < 0) ? 0 : gN0) * CIN + quad * 8;
            const __half* p1 = f + (size_t)((gN1 < 0) ? 0 : gN1) * CIN + quad * 8;
#pragma unroll
            for (int kt = 0; kt < KT; ++kt) {
                uint4 u0 = {0u,0u,0u,0u}, u1 = {0u,0u,0u,0u};
                if (gN0 >= 0) u0 = *(const uint4*)(p0 + kt * 32);
                if (gN1 >= 0) u1 = *(const uint4*)(p1 + kt * 32);
                aN0[kt] = *(f16x8*)&u0;
                aN1[kt] = *(f16x8*)&u1;
            }
        }
        // (3) stage loads for weight tile k+1 -> regs
        bool doStage = (k + 1 < 27);
        uint4 w0{}, w1{}; uint2 w2{};
        if (doStage) {
            const char* src = (const char*)(wt + (size_t)(k + 1) * TILE_H) + tid * TB;
            if constexpr (TB == 32)      { w0 = *(const uint4*)src; w1 = *(const uint4*)(src + 16); }
            else if constexpr (TB == 16) { w0 = *(const uint4*)src; }
            else                         { w2 = *(const uint2*)src; }
        }
        // (4) ds_read B + (5) MFMA on aC (ready since previous barrier)
        if (anyC) {
            ever = true;
            const __half* Wb = S + (k & 1) * TILE_H;
#pragma unroll
            for (int kt = 0; kt < KT; ++kt) {
#pragma unroll
                for (int nt = 0; nt < NT; ++nt) {
                    int row = nt * 16 + l16;
                    int c   = kt * 4 + quad;
                    f16x8 b = *(const f16x8*)(Wb + (row * NCHUNK + (c ^ (row & MASK))) * 8);
                    acc[0][nt] = __builtin_amdgcn_mfma_f32_16x16x32_f16(aC0[kt], b, acc[0][nt], 0, 0, 0);
                    acc[1][nt] = __builtin_amdgcn_mfma_f32_16x16x32_f16(aC1[kt], b, acc[1][nt], 0, 0, 0);
                }
            }
        }
        // (6) ds_write staging into the other buffer
        if (doStage) {
            __half* dst = S + ((k + 1) & 1) * TILE_H;
            if constexpr (TB == 32) {
                int p0 = tid * 2;
#pragma unroll
                for (int j = 0; j < 2; ++j) {
                    int p = p0 + j;
                    int row = p >> LCH, c = p & MASK;
                    *(uint4*)(dst + (row * NCHUNK + (c ^ (row & MASK))) * 8) = (j ? w1 : w0);
                }
            } else if constexpr (TB == 16) {
                int p = tid;
                int row = p >> LCH, c = p & MASK;
                *(uint4*)(dst + (row * NCHUNK + (c ^ (row & MASK))) * 8) = w0;
            } else {
                int p = tid >> 1, half = tid & 1;
                int row = p >> LCH, c = p & MASK;
                *(uint2*)(dst + (row * NCHUNK + (c ^ (row & MASK))) * 8 + half * 4) = w2;
            }
        }
        __syncthreads();
        // rotate pipelines
#pragma unroll
        for (int kt = 0; kt < KT; ++kt) { aC0[kt] = aN0[kt]; aC1[kt] = aN1[kt]; }
        anyC = anyN;
        gC0 = gN0; gC1 = gN1; gN0 = gNN0; gN1 = gNN1;
    }

    // epilogue: BN + ReLU -> wave-private LDS (weight bufs dead) -> store.
    if (!ever) return;
    __half* O = S + wv * (32 * COUT);
#pragma unroll
    for (int nt = 0; nt < NT; ++nt) {
        int co = nt * 16 + l16;
        float g = bnp[co], b = bnp[COUT + co];
        float mn = bnp[2*COUT + co], vv = bnp[3*COUT + co];
        float s  = g * rsqrtf(vv + 1e-5f);
        float sh = b - mn * s;
#pragma unroll
        for (int m = 0; m < 2; ++m)
#pragma unroll
            for (int r_ = 0; r_ < 4; ++r_) {
                int row = m * 16 + quad * 4 + r_;
                O[row * COUT + co] = __float2half(fmaxf(acc[m][nt][r_] * s + sh, 0.f));
            }
    }
    constexpr int OCH = COUT / 8;              // 16B chunks per out row
#pragma unroll
    for (int j = 0; j < 32 * OCH / 64; ++j) {
        int idx = j * 64 + lane;
        int r = idx / OCH, c = idx % OCH;
        if (m0 + r < ncap)
            *(uint4*)(fout + (size_t)(m0 + r) * COUT + c * 8) =
                *(const uint4*)(O + r * COUT + c * 8);
    }
}

// ---------------------------------------------------------------------------
// BEV head 0, v14 (UNCHANGED from known-good v15): registers-only, 64 px
// per block (2200 blocks), lane-local pair attention.
__global__ __launch_bounds__(256) void bev0_mfma(const __half* __restrict__ f0,
                                                 const __half* __restrict__ wtT,  // [64][320] zc=z*32+c
                                                 const float* __restrict__ bias,
                                                 const float* __restrict__ bnp,
                                                 const int* __restrict__ v2r,
                                                 float* __restrict__ out) {
    __shared__ float Ot[64][66];
    int tid = threadIdx.x;
    int y = blockIdx.x / 11, x0 = (blockIdx.x % 11) * 64;
    int wv = tid >> 6, lane = tid & 63;
    int quad = lane >> 4, l16 = lane & 15;

    // v2r preload: 2 m-tiles x 10 z-slices (static-indexed -> registers)
    int rz[2][10];
#pragma unroll
    for (int m = 0; m < 2; ++m) {
        int row = wv * 32 + m * 16 + l16;
        int b = row & 1, p = row >> 1;
#pragma unroll
        for (int z = 0; z < 10; ++z)
            rz[m][z] = v2r[((b * ZD + z) * YD + y) * XD + x0 + p];
    }

    f32x4 acc[2][4] = {};
#pragma unroll
    for (int ks = 0; ks < 10; ++ks) {
        f16x8 a[2];
#pragma unroll
        for (int m = 0; m < 2; ++m) {
            uint4 u = {0u,0u,0u,0u};
            int r = rz[m][ks];
            if (r >= 0) u = *(const uint4*)(f0 + (size_t)r * 32 + quad * 8);
            a[m] = *(f16x8*)&u;
        }
#pragma unroll
        for (int nt = 0; nt < 4; ++nt) {
            f16x8 b = *(const f16x8*)(wtT + (size_t)(nt * 16 + l16) * 320 + ks * 32 + quad * 8);
            acc[0][nt] = __builtin_amdgcn_mfma_f32_16x16x32_f16(a[0], b, acc[0][nt], 0, 0, 0);
            acc[1][nt] = __builtin_amdgcn_mfma_f32_16x16x32_f16(a[1], b, acc[1][nt], 0, 0, 0);
        }
    }

    // BN + ReLU in-place (channels are lane-local: co = nt*16 + l16)
#pragma unroll
    for (int nt = 0; nt < 4; ++nt) {
        int co = nt * 16 + l16;
        float s  = bnp[co] * rsqrtf(bnp[192 + co] + 1e-5f);
        float sh = (bias[co] - bnp[128 + co]) * s + bnp[64 + co];
#pragma unroll
        for (int m = 0; m < 2; ++m)
#pragma unroll
            for (int r_ = 0; r_ < 4; ++r_)
                acc[m][nt][r_] = fmaxf(acc[m][nt][r_] * s + sh, 0.f);
    }

    // lane-local pair attention
#pragma unroll
    for (int m = 0; m < 2; ++m)
#pragma unroll
        for (int jj = 0; jj < 2; ++jj) {
            float s00 = 0.f, s01 = 0.f;
#pragma unroll
            for (int nt = 0; nt < 4; ++nt) {
                float xv0 = acc[m][nt][2 * jj], xv1 = acc[m][nt][2 * jj + 1];
                s00 += xv0 * xv0;
                s01 += xv0 * xv1;
            }
#pragma unroll
            for (int o = 8; o > 0; o >>= 1) {
                s00 += __shfl_xor(s00, o);
                s01 += __shfl_xor(s01, o);
            }
            float a0 = s00 * 0.125f, a1 = s01 * 0.125f;
            float mx = fmaxf(a0, a1);
            float e0 = expf(a0 - mx), e1 = expf(a1 - mx);
            float inv = 1.f / (e0 + e1);
            int pl = wv * 16 + m * 8 + quad * 2 + jj;
#pragma unroll
            for (int nt = 0; nt < 4; ++nt)
                Ot[nt * 16 + l16][pl] =
                    (e0 * acc[m][nt][2 * jj] + e1 * acc[m][nt][2 * jj + 1]) * inv;
        }
    __syncthreads();

#pragma unroll
    for (int i = 0; i < 16; ++i) {
        int idx = i * 256 + tid;
        int co = idx >> 6, px = idx & 63;
        out[(size_t)co * HWOUT + (size_t)y * XD + x0 + px] = Ot[co][px];
    }
}

// ---------------------------------------------------------------------------
// BEV head 1, v15 (UNCHANGED from known-good v15): A gathered once, ky split
// across blocks.
__global__ __launch_bounds__(256) void bev1_mfma(const __half* __restrict__ f1,
                                                 const __half* __restrict__ wtT,  // [4][64][320] zc=z*64+c
                                                 const float* __restrict__ bias,
                                                 const float* __restrict__ bnp,
                                                 const int* __restrict__ v2r,
                                                 float* __restrict__ out) {
    __shared__ float Ot[64][66];
    int tid = threadIdx.x;
    int bid = blockIdx.x;
    int ky = bid & 1;
    int t  = bid >> 1;
    int iy = t / 11, j0 = (t % 11) * 32;
    int wv = tid >> 6, lane = tid & 63;
    int quad = lane >> 4, l16 = lane & 15;

    int row = wv * 16 + l16;
    int b = row & 1, p = row >> 1;
    int rz[5];
#pragma unroll
    for (int z = 0; z < 5; ++z)
        rz[z] = v2r[((b * Z1D + z) * Y1D + iy) * X1D + j0 + p];

    // gather all 10 A fragments once (independent loads, one latency window)
    f16x8 a[10];
#pragma unroll
    for (int ks = 0; ks < 10; ++ks) {
        int z = ks >> 1, hf = ks & 1;
        uint4 u = {0u,0u,0u,0u};
        int r = rz[z];
        if (r >= 0) u = *(const uint4*)(f1 + (size_t)r * 64 + hf * 32 + quad * 8);
        a[ks] = *(f16x8*)&u;
    }

    f32x4 acc[2][4] = {};
#pragma unroll
    for (int kx = 0; kx < 2; ++kx) {
        const __half* wk = wtT + (size_t)(ky * 2 + kx) * 64 * 320;
#pragma unroll
        for (int ks = 0; ks < 10; ++ks)
#pragma unroll
            for (int nt = 0; nt < 4; ++nt) {
                f16x8 bf = *(const f16x8*)(wk + (size_t)(nt * 16 + l16) * 320 + ks * 32 + quad * 8);
                acc[kx][nt] = __builtin_amdgcn_mfma_f32_16x16x32_f16(a[ks], bf, acc[kx][nt], 0, 0, 0);
            }
    }

    // BN + ReLU in-place, then lane-local pair attention per kx
#pragma unroll
    for (int kx = 0; kx < 2; ++kx) {
#pragma unroll
        for (int nt = 0; nt < 4; ++nt) {
            int co = nt * 16 + l16;
            float s  = bnp[co] * rsqrtf(bnp[192 + co] + 1e-5f);
            float sh = (bias[co] - bnp[128 + co]) * s + bnp[64 + co];
#pragma unroll
            for (int r_ = 0; r_ < 4; ++r_)
                acc[kx][nt][r_] = fmaxf(acc[kx][nt][r_] * s + sh, 0.f);
        }
#pragma unroll
        for (int jj = 0; jj < 2; ++jj) {
            float s00 = 0.f, s01 = 0.f;
#pragma unroll
            for (int nt = 0; nt < 4; ++nt) {
                float xv0 = acc[kx][nt][2 * jj], xv1 = acc[kx][nt][2 * jj + 1];
                s00 += xv0 * xv0;
                s01 += xv0 * xv1;
            }
#pragma unroll
            for (int o = 8; o > 0; o >>= 1) {
                s00 += __shfl_xor(s00, o);
                s01 += __shfl_xor(s01, o);
            }
            float a0 = s00 * 0.125f, a1 = s01 * 0.125f;
            float mx = fmaxf(a0, a1);
            float e0 = expf(a0 - mx), e1 = expf(a1 - mx);
            float inv = 1.f / (e0 + e1);
            int pl = wv * 8 + quad * 2 + jj;    // 0..31
#pragma unroll
            for (int nt = 0; nt < 4; ++nt)
                Ot[nt * 16 + l16][2 * pl + kx] =
                    (e0 * acc[kx][nt][2 * jj] + e1 * acc[kx][nt][2 * jj + 1]) * inv;
        }
    }
    __syncthreads();

    int yo = 2 * iy + ky;
#pragma unroll
    for (int i = 0; i < 16; ++i) {
        int idx = i * 256 + tid;
        int co = idx >> 6, xx = idx & 63;
        out[(size_t)co * HWOUT + (size_t)yo * XD + 2 * j0 + xx] = Ot[co][xx];
    }
}

// ---------------------------------------------------------------------------
extern "C" void kernel_launch(void* const* d_in, const int* in_sizes, int n_in,
                              void* d_out, int out_size, void* d_ws, size_t ws_size,
                              hipStream_t stream) {
    const float* sp    = (const float*)d_in[0];
    const float* w_in  = (const float*)d_in[1];
    const float* w0    = (const float*)d_in[2];
    const float* bnp0  = (const float*)d_in[3];
    const float* w0a   = (const float*)d_in[4];
    const float* bnp0a = (const float*)d_in[5];
    const float* w0b   = (const float*)d_in[6];
    const float* bnp0b = (const float*)d_in[7];
    const float* w1    = (const float*)d_in[8];
    const float* bnp1  = (const float*)d_in[9];
    const float* w1a   = (const float*)d_in[10];
    const float* bnp1a = (const float*)d_in[11];
    const float* w1b   = (const float*)d_in[12];
    const float* bnp1b = (const float*)d_in[13];
    const float* ct0w  = (const float*)d_in[14];
    const float* ct0b  = (const float*)d_in[15];
    const float* bnt0  = (const float*)d_in[16];
    const float* ct1w  = (const float*)d_in[17];
    const float* ct1b  = (const float*)d_in[18];
    const float* bnt1  = (const float*)d_in[19];
    const int* coords0 = (const int*)d_in[20];
    const int* coords1 = (const int*)d_in[21];
    const int* g0 = (const int*)d_in[22];
    const int* s0 = (const int*)d_in[23];
    const int* ga = (const int*)d_in[24];
    const int* sa = (const int*)d_in[25];
    const int* g1 = (const int*)d_in[26];
    const int* s1 = (const int*)d_in[27];
    const int* gb = (const int*)d_in[28];
    const int* sb = (const int*)d_in[29];
    float* out = (float*)d_out;

    // -------- workspace carve --------
    __half* fInH = (__half*)d_ws;
    __half* R1h  = fInH + 640000;
    __half* R2h  = R1h + 22528000;
    __half* wt0  = R2h + 22528000;
    __half* wt0a = wt0  + 27648;
    __half* wt0b = wt0a + 27648;
    __half* wt1  = wt0b + 27648;          // [27][64][32]
    __half* wt1a = wt1  + 55296;          // [27][64][64]
    __half* wt1b = wt1a + 110592;
    __half* wtT0 = wt1b + 110592;         // [64][320]
    __half* wtT1 = wtT0 + 20480;          // [4][64][320]
    int*   nbrT = (int*)(wtT1 + 81920);   // 27*CAP0C ints = 14,580,000
    int*   v2r0 = nbrT;                          // 2,816,000 ints (aliases)
    int*   v2r1 = nbrT + 2816000;                //   352,000 ints (aliases)
    int*   nAct = nbrT + 14580000;               // 2 ints, beyond nbrT region

    // 0) weight conversion + n_act (binary search on coords pad boundary)
    find_nact<<<1, 128, 0, stream>>>(coords0, coords1, nAct);
    cvt_w<<<(27*32*32 + 255) / 256, 256, 0, stream>>>(w0,  wt0,  32, 32);
    cvt_w<<<(27*32*32 + 255) / 256, 256, 0, stream>>>(w0a, wt0a, 32, 32);
    cvt_w<<<(27*32*32 + 255) / 256, 256, 0, stream>>>(w0b, wt0b, 32, 32);
    cvt_w<<<(27*32*64 + 255) / 256, 256, 0, stream>>>(w1,  wt1,  32, 64);
    cvt_w<<<(27*64*64 + 255) / 256, 256, 0, stream>>>(w1a, wt1a, 64, 64);
    cvt_w<<<(27*64*64 + 255) / 256, 256, 0, stream>>>(w1b, wt1b, 64, 64);
    cvt_ct0<<<(64*320 + 255) / 256, 256, 0, stream>>>(ct0w, wtT0);
    cvt_ct1<<<(4*64*320 + 255) / 256, 256, 0, stream>>>(ct1w, wtT1);

    // 1) input channel lift (f16 rows out)
    gemm_in<<<(N_PTS_IN * 8 + 255) / 256, 256, 0, stream>>>(sp, w_in, fInH);

    // 2) conv0 (stride-1 spconv, 32->32): fInH -> R1h
    hipMemsetAsync(nbrT, 0xFF, (size_t)CAP0C * 27 * 4, stream);
    build_nbr<<<(27 * N_PTS_IN + 255) / 256, 256, 0, stream>>>(g0, s0, nbrT, N_PTS_IN, CAP0C);
    spconv_reg<32, 32><<<(CAP0C + 127) / 128, 256, 0, stream>>>(fInH, wt0, bnp0, nbrT, R1h, CAP0C, nAct + 0);

    // 3) subm a/b (32->32), shared rulebook: R1h -> R2h -> R1h
    hipMemsetAsync(nbrT, 0xFF, (size_t)CAP0C * 27 * 4, stream);
    build_nbr<<<(27 * CAP0C + 255) / 256, 256, 0, stream>>>(ga, sa, nbrT, CAP0C, CAP0C);
    spconv_reg<32, 32><<<(CAP0C + 127) / 128, 256, 0, stream>>>(R1h, wt0a, bnp0a, nbrT, R2h, CAP0C, nAct + 0);
    spconv_reg<32, 32><<<(CAP0C + 127) / 128, 256, 0, stream>>>(R2h, wt0b, bnp0b, nbrT, R1h, CAP0C, nAct + 0);

    // 4) BEV head 0 (reads R1h) -> out channels [0,64)
    hipMemsetAsync(v2r0, 0xFF, (size_t)2816000 * 4, stream);
    build_vox<<<(CAP0C + 255) / 256, 256, 0, stream>>>(coords0, v2r0, CAP0C, ZD, YD, XD);
    bev0_mfma<<<YD * 11, 256, 0, stream>>>(R1h, wtT0, ct0b, bnt0, v2r0, out);

    // 5) conv1 (stride-2 spconv, 32->64): R1h -> R2h
    hipMemsetAsync(nbrT, 0xFF, (size_t)CAP1C * 27 * 4, stream);
    build_nbr<<<(27 * CAP0C + 255) / 256, 256, 0, stream>>>(g1, s1, nbrT, CAP0C, CAP1C);
    spconv_reg<32, 64><<<(CAP1C + 127) / 128, 256, 0, stream>>>(R1h, wt1, bnp1, nbrT, R2h, CAP1C, nAct + 1);

    // 6) subm 1a/1b (64->64), shared rulebook: R2h -> R1h -> R2h
    hipMemsetAsync(nbrT, 0xFF, (size_t)CAP1C * 27 * 4, stream);
    build_nbr<<<(27 * CAP1C + 255) / 256, 256, 0, stream>>>(gb, sb, nbrT, CAP1C, CAP1C);
    spconv_reg<64, 64><<<(CAP1C + 127) / 128, 256, 0, stream>>>(R2h, wt1a, bnp1a, nbrT, R1h, CAP1C, nAct + 1);
    spconv_reg<64, 64><<<(CAP1C + 127) / 128, 256, 0, stream>>>(R1h, wt1b, bnp1b, nbrT, R2h, CAP1C, nAct + 1);

    // 7) BEV head 1 (reads R2h) -> out channels [64,128)
    hipMemsetAsync(v2r1, 0xFF, (size_t)352000 * 4, stream);
    build_vox<<<(CAP1C + 255) / 256, 256, 0, stream>>>(coords1, v2r1, CAP1C, Z1D, Y1D, X1D);
    bev1_mfma<<<Y1D * 11 * 2, 256, 0, stream>>>(R2h, wtT1, ct1b, bnt1, v2r1, out + (size_t)64 * HWOUT);
}

// Round 13
// 934.640 us; speedup vs baseline: 3.2182x; 1.0012x over previous
//
#include <hip/hip_runtime.h>
#include <hip/hip_bf16.h>
#include <hip/hip_fp16.h>

// Problem constants
#define N_PTS_IN   20000
#define CAP0C      540000
#define CAP1C      352000
#define ZD 10
#define YD 200
#define XD 704
#define Z1D 5
#define Y1D 100
#define X1D 352
#define HWOUT (YD*XD)   // 140800

typedef _Float16 f16x8 __attribute__((ext_vector_type(8)));
typedef float    f32x4 __attribute__((ext_vector_type(4)));

// ---------------------------------------------------------------------------
// f_in = sp_feats @ w_in   (20000x64 @ 64x32), f16 output rows
__global__ __launch_bounds__(256) void gemm_in(const float* __restrict__ sp,
                                               const float* __restrict__ w,
                                               __half* __restrict__ fout) {
    int tid = blockIdx.x * 256 + threadIdx.x;
    int row = tid >> 3;
    int c4  = (tid & 7) * 4;
    if (row >= N_PTS_IN) return;
    float4 acc = {0.f, 0.f, 0.f, 0.f};
    const float* sr = sp + (size_t)row * 64;
#pragma unroll
    for (int ci = 0; ci < 64; ci += 4) {
        float4 fv = *(const float4*)(sr + ci);
        const float* wp = w + ci * 32 + c4;
        float4 w0 = *(const float4*)(wp);
        float4 w1 = *(const float4*)(wp + 32);
        float4 w2 = *(const float4*)(wp + 64);
        float4 w3 = *(const float4*)(wp + 96);
        acc.x += fv.x*w0.x + fv.y*w1.x + fv.z*w2.x + fv.w*w3.x;
        acc.y += fv.x*w0.y + fv.y*w1.y + fv.z*w2.y + fv.w*w3.y;
        acc.z += fv.x*w0.z + fv.y*w1.z + fv.z*w2.z + fv.w*w3.z;
        acc.w += fv.x*w0.w + fv.y*w1.w + fv.z*w2.w + fv.w*w3.w;
    }
    __half* fo = fout + (size_t)row * 32 + c4;
    fo[0] = __float2half(acc.x);
    fo[1] = __float2half(acc.y);
    fo[2] = __float2half(acc.z);
    fo[3] = __float2half(acc.w);
}

// ---------------------------------------------------------------------------
// Weight convert+transpose: src f32 [27][CIN][COUT] -> dst f16 [27][COUT][CIN]
__global__ __launch_bounds__(256) void cvt_w(const float* __restrict__ src,
                                             __half* __restrict__ dst,
                                             int CIN, int COUT) {
    int i = blockIdx.x * 256 + threadIdx.x;
    if (i >= 27 * CIN * COUT) return;
    int ci = i % CIN;
    int t  = i / CIN;
    int co = t % COUT;
    int k  = t / COUT;
    dst[i] = __float2half(src[((size_t)k * CIN + ci) * COUT + co]);
}

// ct0_w f32 [320][64] (ci=c*10+z) -> f16 [co][zc=z*32+c]
__global__ __launch_bounds__(256) void cvt_ct0(const float* __restrict__ src,
                                               __half* __restrict__ dst) {
    int i = blockIdx.x * 256 + threadIdx.x;
    if (i >= 64 * 320) return;
    int zc = i % 320, co = i / 320;
    int z = zc >> 5, c = zc & 31;
    dst[i] = __float2half(src[(c * 10 + z) * 64 + co]);
}

// ct1_w f32 [320][64][2][2] (ci=c*5+z) -> f16 [kq][co][zc=z*64+c]
__global__ __launch_bounds__(256) void cvt_ct1(const float* __restrict__ src,
                                               __half* __restrict__ dst) {
    int i = blockIdx.x * 256 + threadIdx.x;
    if (i >= 4 * 64 * 320) return;
    int zc = i % 320;
    int t  = i / 320;
    int co = t & 63;
    int kq = t >> 6;
    int z = zc >> 6, c = zc & 63;
    dst[i] = __float2half(src[((c * 5 + z) * 64 + co) * 4 + kq]);
}

// ---------------------------------------------------------------------------
// Rulebook inversion, TRANSPOSED: nbrT[k*cap + s] = g. Scatter-only.
__global__ __launch_bounds__(256) void build_nbr(const int* __restrict__ g,
                                                 const int* __restrict__ s,
                                                 int* __restrict__ nbrT,
                                                 int P, int cap) {
    int i = blockIdx.x * 256 + threadIdx.x;
    if (i >= 27 * P) return;
    int k = i / P, p = i - k * P;
    int sv = s[(size_t)k * P + p];
    if (sv >= cap) return;              // dummy pair
    nbrT[(size_t)k * cap + sv] = g[(size_t)k * P + p];
}

// ---------------------------------------------------------------------------
// n_act via binary search on the coords pad boundary (z == Zdim marks pad).
__global__ __launch_bounds__(128) void find_nact(const int* __restrict__ c0,
                                                 const int* __restrict__ c1,
                                                 int* __restrict__ nA) {
    int t = threadIdx.x;
    if (t == 0) {
        int lo = 0, hi = CAP0C;
        while (lo < hi) {
            int mid = (lo + hi) >> 1;
            if (c0[4 * mid + 1] >= ZD) hi = mid; else lo = mid + 1;
        }
        nA[0] = lo;
    } else if (t == 64) {
        int lo = 0, hi = CAP1C;
        while (lo < hi) {
            int mid = (lo + hi) >> 1;
            if (c1[4 * mid + 1] >= Z1D) hi = mid; else lo = mid + 1;
        }
        nA[1] = lo;
    }
}

// voxel -> sparse-row index (pad coords have z == Zdim, dropped like JAX OOB)
__global__ __launch_bounds__(256) void build_vox(const int* __restrict__ coords,
                                                 int* __restrict__ v2r,
                                                 int cap, int Zdim, int Ydim, int Xdim) {
    int r = blockIdx.x * 256 + threadIdx.x;
    if (r >= cap) return;
    int b = coords[4*r], z = coords[4*r+1], y = coords[4*r+2], x = coords[4*r+3];
    if (z >= Zdim) return;
    v2r[(((size_t)b * Zdim + z) * Ydim + y) * Xdim + x] = r;
}

// ---------------------------------------------------------------------------
// Implicit-GEMM sparse conv via f16 MFMA 16x16x32, + BN + ReLU.
// v18 = v17 + COUNTED-WAIT BARRIER (T4):
//   R12 post-mortem: the depth-1 feature prefetch gained only ~10us because
//   __syncthreads drains vmcnt(0) -- the aN gathers serialized at the
//   barrier instead of at the MFMA. The barrier here only needs to order
//   LDS traffic (weight double-buffer); global loads are register-destined
//   and thread-private. Replace __syncthreads with
//   {s_waitcnt lgkmcnt(0); s_barrier} -- gathers/idx loads stay in flight
//   ACROSS the barrier and retire under the next iter's ds_read+MFMA.
template <int CIN, int COUT>
__global__ __launch_bounds__(256) void spconv_reg(const __half* __restrict__ f,
                                                  const __half* __restrict__ wt,
                                                  const float* __restrict__ bnp,
                                                  const int* __restrict__ nbrT,
                                                  __half* __restrict__ fout,
                                                  int ncap,
                                                  const int* __restrict__ nA) {
    constexpr int NT = COUT / 16;       // 16-col output tiles
    constexpr int KT = CIN / 32;        // K=32 MFMA steps per k-offset
    constexpr int NCHUNK = CIN / 8;     // 16B chunks per weight row
    constexpr int MASK = NCHUNK - 1;
    constexpr int LCH  = (NCHUNK == 8) ? 3 : 2;
    constexpr int TILE_H = COUT * CIN;  // halves per weight tile
    constexpr int TB = TILE_H * 2 / 256; // stage bytes per thread (8/16/32)
    constexpr int OST_H = 4 * 32 * COUT;
    constexpr int SH_H = (2 * TILE_H > OST_H) ? 2 * TILE_H : OST_H;
    __shared__ __align__(16) __half S[SH_H];

    int tid = threadIdx.x;
    int wv = tid >> 6, lane = tid & 63;
    int quad = lane >> 4, l16 = lane & 15;

    // interleaved-group XCD swizzle (live-prefix-safe, bijective)
    int bid = blockIdx.x;
    int nfull = (int)gridDim.x & ~63;
    int sb;
    if (bid < nfull) {
        int grp = bid >> 6, w = bid & 63;
        sb = grp * 64 + (w & 7) * 8 + (w >> 3);
    } else {
        sb = bid;
    }

    // dead-block early exit: rows >= n_act have no pairs for any k
    if (sb * 128 >= *nA) return;

    int m0 = sb * 128 + wv * 32;       // wave's first output row
    int r0 = m0 + l16;                 // this lane's row for m=0
    int r1 = m0 + 16 + l16;            // this lane's row for m=1
    bool ok0 = r0 < ncap, ok1 = r1 < ncap;

    f32x4 acc[2][NT] = {};

    // index pipeline depth 2
    int gC0 = ok0 ? nbrT[r0] : -1;
    int gC1 = ok1 ? nbrT[r1] : -1;
    int gN0 = ok0 ? nbrT[(size_t)ncap + r0] : -1;
    int gN1 = ok1 ? nbrT[(size_t)ncap + r1] : -1;
    bool anyC = __ballot((gC0 >= 0) || (gC1 >= 0)) != 0ull;
    bool ever = false;

    // ---- feature prologue: gather k=0 rows into registers ----
    f16x8 aC0[KT], aC1[KT];
#pragma unroll
    for (int kt = 0; kt < KT; ++kt) {
        uint4 z4 = {0u,0u,0u,0u};
        aC0[kt] = *(f16x8*)&z4;
        aC1[kt] = *(f16x8*)&z4;
    }
    if (anyC) {
        const __half* p0 = f + (size_t)((gC0 < 0) ? 0 : gC0) * CIN + quad * 8;
        const __half* p1 = f + (size_t)((gC1 < 0) ? 0 : gC1) * CIN + quad * 8;
#pragma unroll
        for (int kt = 0; kt < KT; ++kt) {
            uint4 u0 = {0u,0u,0u,0u}, u1 = {0u,0u,0u,0u};
            if (gC0 >= 0) u0 = *(const uint4*)(p0 + kt * 32);
            if (gC1 >= 0) u1 = *(const uint4*)(p1 + kt * 32);
            aC0[kt] = *(f16x8*)&u0;
            aC1[kt] = *(f16x8*)&u1;
        }
    }

    // ---- weight prologue: stage tile k=0 into buffer 0 ----
    {
        const char* src = (const char*)(wt) + tid * TB;
        if constexpr (TB == 32) {
            uint4 w0 = *(const uint4*)src;
            uint4 w1 = *(const uint4*)(src + 16);
            int p0 = tid * 2;
#pragma unroll
            for (int j = 0; j < 2; ++j) {
                int p = p0 + j;
                int row = p >> LCH, c = p & MASK;
                *(uint4*)(S + (row * NCHUNK + (c ^ (row & MASK))) * 8) = (j ? w1 : w0);
            }
        } else if constexpr (TB == 16) {
            uint4 w0 = *(const uint4*)src;
            int p = tid;
            int row = p >> LCH, c = p & MASK;
            *(uint4*)(S + (row * NCHUNK + (c ^ (row & MASK))) * 8) = w0;
        } else {
            uint2 w0 = *(const uint2*)src;
            int p = tid >> 1, half = tid & 1;
            int row = p >> LCH, c = p & MASK;
            *(uint2*)(S + (row * NCHUNK + (c ^ (row & MASK))) * 8 + half * 4) = w0;
        }
    }
    __syncthreads();   // prologue barrier: full drain is fine (once)

#pragma unroll 1
    for (int k = 0; k < 27; ++k) {
        // (1) idx k+2 (oldest in-flight)
        int gNN0 = -1, gNN1 = -1;
        if (k + 2 < 27) {
            if (ok0) gNN0 = nbrT[(size_t)(k + 2) * ncap + r0];
            if (ok1) gNN1 = nbrT[(size_t)(k + 2) * ncap + r1];
        }
        // (2) gather k+1 rows -> aN (vmcnt stays COUNTED across the barrier;
        //     these retire under next iter's ds_read+MFMA)
        bool anyN = __ballot((gN0 >= 0) || (gN1 >= 0)) != 0ull;
        f16x8 aN0[KT], aN1[KT];
#pragma unroll
        for (int kt = 0; kt < KT; ++kt) {
            uint4 z4 = {0u,0u,0u,0u};
            aN0[kt] = *(f16x8*)&z4;
            aN1[kt] = *(f16x8*)&z4;
        }
        if (anyN) {
            const __half* p0 = f + (size_t)((gN0 < 0) ? 0 : gN0) * CIN + quad * 8;
            const __half* p1 = f + (size_t)((gN1 < 0) ? 0 : gN1) * CIN + quad * 8;
#pragma unroll
            for (int kt = 0; kt < KT; ++kt) {
                uint4 u0 = {0u,0u,0u,0u}, u1 = {0u,0u,0u,0u};
                if (gN0 >= 0) u0 = *(const uint4*)(p0 + kt * 32);
                if (gN1 >= 0) u1 = *(const uint4*)(p1 + kt * 32);
                aN0[kt] = *(f16x8*)&u0;
                aN1[kt] = *(f16x8*)&u1;
            }
        }
        // (3) stage loads for weight tile k+1 -> regs
        bool doStage = (k + 1 < 27);
        uint4 w0{}, w1{}; uint2 w2{};
        if (doStage) {
            const char* src = (const char*)(wt + (size_t)(k + 1) * TILE_H) + tid * TB;
            if constexpr (TB == 32)      { w0 = *(const uint4*)src; w1 = *(const uint4*)(src + 16); }
            else if constexpr (TB == 16) { w0 = *(const uint4*)src; }
            else                         { w2 = *(const uint2*)src; }
        }
        // (4) ds_read B + (5) MFMA on aC (ready since previous barrier)
        if (anyC) {
            ever = true;
            const __half* Wb = S + (k & 1) * TILE_H;
#pragma unroll
            for (int kt = 0; kt < KT; ++kt) {
#pragma unroll
                for (int nt = 0; nt < NT; ++nt) {
                    int row = nt * 16 + l16;
                    int c   = kt * 4 + quad;
                    f16x8 b = *(const f16x8*)(Wb + (row * NCHUNK + (c ^ (row & MASK))) * 8);
                    acc[0][nt] = __builtin_amdgcn_mfma_f32_16x16x32_f16(aC0[kt], b, acc[0][nt], 0, 0, 0);
                    acc[1][nt] = __builtin_amdgcn_mfma_f32_16x16x32_f16(aC1[kt], b, acc[1][nt], 0, 0, 0);
                }
            }
        }
        // (6) ds_write staging into the other buffer (data-dep vmcnt wait on
        //     the staged registers is counted & compiler-inserted)
        if (doStage) {
            __half* dst = S + ((k + 1) & 1) * TILE_H;
            if constexpr (TB == 32) {
                int p0 = tid * 2;
#pragma unroll
                for (int j = 0; j < 2; ++j) {
                    int p = p0 + j;
                    int row = p >> LCH, c = p & MASK;
                    *(uint4*)(dst + (row * NCHUNK + (c ^ (row & MASK))) * 8) = (j ? w1 : w0);
                }
            } else if constexpr (TB == 16) {
                int p = tid;
                int row = p >> LCH, c = p & MASK;
                *(uint4*)(dst + (row * NCHUNK + (c ^ (row & MASK))) * 8) = w0;
            } else {
                int p = tid >> 1, half = tid & 1;
                int row = p >> LCH, c = p & MASK;
                *(uint2*)(dst + (row * NCHUNK + (c ^ (row & MASK))) * 8 + half * 4) = w2;
            }
        }
        // COUNTED-WAIT BARRIER: drain LDS only; vmcnt (gathers/idx) stays
        // in flight across the barrier. Correct because global loads here
        // are register-destined (thread-private, no cross-thread visibility).
        asm volatile("s_waitcnt lgkmcnt(0)" ::: "memory");
        __builtin_amdgcn_s_barrier();
        // rotate pipelines
#pragma unroll
        for (int kt = 0; kt < KT; ++kt) { aC0[kt] = aN0[kt]; aC1[kt] = aN1[kt]; }
        anyC = anyN;
        gC0 = gN0; gC1 = gN1; gN0 = gNN0; gN1 = gNN1;
    }

    // epilogue: BN + ReLU -> wave-private LDS (weight bufs dead) -> store.
    if (!ever) return;
    __half* O = S + wv * (32 * COUT);
#pragma unroll
    for (int nt = 0; nt < NT; ++nt) {
        int co = nt * 16 + l16;
        float g = bnp[co], b = bnp[COUT + co];
        float mn = bnp[2*COUT + co], vv = bnp[3*COUT + co];
        float s  = g * rsqrtf(vv + 1e-5f);
        float sh = b - mn * s;
#pragma unroll
        for (int m = 0; m < 2; ++m)
#pragma unroll
            for (int r_ = 0; r_ < 4; ++r_) {
                int row = m * 16 + quad * 4 + r_;
                O[row * COUT + co] = __float2half(fmaxf(acc[m][nt][r_] * s + sh, 0.f));
            }
    }
    constexpr int OCH = COUT / 8;              // 16B chunks per out row
#pragma unroll
    for (int j = 0; j < 32 * OCH / 64; ++j) {
        int idx = j * 64 + lane;
        int r = idx / OCH, c = idx % OCH;
        if (m0 + r < ncap)
            *(uint4*)(fout + (size_t)(m0 + r) * COUT + c * 8) =
                *(const uint4*)(O + r * COUT + c * 8);
    }
}

// ---------------------------------------------------------------------------
// BEV head 0, v14 (UNCHANGED): registers-only, 64 px per block,
// lane-local pair attention.
__global__ __launch_bounds__(256) void bev0_mfma(const __half* __restrict__ f0,
                                                 const __half* __restrict__ wtT,  // [64][320] zc=z*32+c
                                                 const float* __restrict__ bias,
                                                 const float* __restrict__ bnp,
                                                 const int* __restrict__ v2r,
                                                 float* __restrict__ out) {
    __shared__ float Ot[64][66];
    int tid = threadIdx.x;
    int y = blockIdx.x / 11, x0 = (blockIdx.x % 11) * 64;
    int wv = tid >> 6, lane = tid & 63;
    int quad = lane >> 4, l16 = lane & 15;

    // v2r preload: 2 m-tiles x 10 z-slices (static-indexed -> registers)
    int rz[2][10];
#pragma unroll
    for (int m = 0; m < 2; ++m) {
        int row = wv * 32 + m * 16 + l16;
        int b = row & 1, p = row >> 1;
#pragma unroll
        for (int z = 0; z < 10; ++z)
            rz[m][z] = v2r[((b * ZD + z) * YD + y) * XD + x0 + p];
    }

    f32x4 acc[2][4] = {};
#pragma unroll
    for (int ks = 0; ks < 10; ++ks) {
        f16x8 a[2];
#pragma unroll
        for (int m = 0; m < 2; ++m) {
            uint4 u = {0u,0u,0u,0u};
            int r = rz[m][ks];
            if (r >= 0) u = *(const uint4*)(f0 + (size_t)r * 32 + quad * 8);
            a[m] = *(f16x8*)&u;
        }
#pragma unroll
        for (int nt = 0; nt < 4; ++nt) {
            f16x8 b = *(const f16x8*)(wtT + (size_t)(nt * 16 + l16) * 320 + ks * 32 + quad * 8);
            acc[0][nt] = __builtin_amdgcn_mfma_f32_16x16x32_f16(a[0], b, acc[0][nt], 0, 0, 0);
            acc[1][nt] = __builtin_amdgcn_mfma_f32_16x16x32_f16(a[1], b, acc[1][nt], 0, 0, 0);
        }
    }

    // BN + ReLU in-place (channels are lane-local: co = nt*16 + l16)
#pragma unroll
    for (int nt = 0; nt < 4; ++nt) {
        int co = nt * 16 + l16;
        float s  = bnp[co] * rsqrtf(bnp[192 + co] + 1e-5f);
        float sh = (bias[co] - bnp[128 + co]) * s + bnp[64 + co];
#pragma unroll
        for (int m = 0; m < 2; ++m)
#pragma unroll
            for (int r_ = 0; r_ < 4; ++r_)
                acc[m][nt][r_] = fmaxf(acc[m][nt][r_] * s + sh, 0.f);
    }

    // lane-local pair attention
#pragma unroll
    for (int m = 0; m < 2; ++m)
#pragma unroll
        for (int jj = 0; jj < 2; ++jj) {
            float s00 = 0.f, s01 = 0.f;
#pragma unroll
            for (int nt = 0; nt < 4; ++nt) {
                float xv0 = acc[m][nt][2 * jj], xv1 = acc[m][nt][2 * jj + 1];
                s00 += xv0 * xv0;
                s01 += xv0 * xv1;
            }
#pragma unroll
            for (int o = 8; o > 0; o >>= 1) {
                s00 += __shfl_xor(s00, o);
                s01 += __shfl_xor(s01, o);
            }
            float a0 = s00 * 0.125f, a1 = s01 * 0.125f;
            float mx = fmaxf(a0, a1);
            float e0 = expf(a0 - mx), e1 = expf(a1 - mx);
            float inv = 1.f / (e0 + e1);
            int pl = wv * 16 + m * 8 + quad * 2 + jj;
#pragma unroll
            for (int nt = 0; nt < 4; ++nt)
                Ot[nt * 16 + l16][pl] =
                    (e0 * acc[m][nt][2 * jj] + e1 * acc[m][nt][2 * jj + 1]) * inv;
        }
    __syncthreads();

#pragma unroll
    for (int i = 0; i < 16; ++i) {
        int idx = i * 256 + tid;
        int co = idx >> 6, px = idx & 63;
        out[(size_t)co * HWOUT + (size_t)y * XD + x0 + px] = Ot[co][px];
    }
}

// ---------------------------------------------------------------------------
// BEV head 1, v15 (UNCHANGED): A gathered once, ky split across blocks.
__global__ __launch_bounds__(256) void bev1_mfma(const __half* __restrict__ f1,
                                                 const __half* __restrict__ wtT,  // [4][64][320] zc=z*64+c
                                                 const float* __restrict__ bias,
                                                 const float* __restrict__ bnp,
                                                 const int* __restrict__ v2r,
                                                 float* __restrict__ out) {
    __shared__ float Ot[64][66];
    int tid = threadIdx.x;
    int bid = blockIdx.x;
    int ky = bid & 1;
    int t  = bid >> 1;
    int iy = t / 11, j0 = (t % 11) * 32;
    int wv = tid >> 6, lane = tid & 63;
    int quad = lane >> 4, l16 = lane & 15;

    int row = wv * 16 + l16;
    int b = row & 1, p = row >> 1;
    int rz[5];
#pragma unroll
    for (int z = 0; z < 5; ++z)
        rz[z] = v2r[((b * Z1D + z) * Y1D + iy) * X1D + j0 + p];

    // gather all 10 A fragments once (independent loads, one latency window)
    f16x8 a[10];
#pragma unroll
    for (int ks = 0; ks < 10; ++ks) {
        int z = ks >> 1, hf = ks & 1;
        uint4 u = {0u,0u,0u,0u};
        int r = rz[z];
        if (r >= 0) u = *(const uint4*)(f1 + (size_t)r * 64 + hf * 32 + quad * 8);
        a[ks] = *(f16x8*)&u;
    }

    f32x4 acc[2][4] = {};
#pragma unroll
    for (int kx = 0; kx < 2; ++kx) {
        const __half* wk = wtT + (size_t)(ky * 2 + kx) * 64 * 320;
#pragma unroll
        for (int ks = 0; ks < 10; ++ks)
#pragma unroll
            for (int nt = 0; nt < 4; ++nt) {
                f16x8 bf = *(const f16x8*)(wk + (size_t)(nt * 16 + l16) * 320 + ks * 32 + quad * 8);
                acc[kx][nt] = __builtin_amdgcn_mfma_f32_16x16x32_f16(a[ks], bf, acc[kx][nt], 0, 0, 0);
            }
    }

    // BN + ReLU in-place, then lane-local pair attention per kx
#pragma unroll
    for (int kx = 0; kx < 2; ++kx) {
#pragma unroll
        for (int nt = 0; nt < 4; ++nt) {
            int co = nt * 16 + l16;
            float s  = bnp[co] * rsqrtf(bnp[192 + co] + 1e-5f);
            float sh = (bias[co] - bnp[128 + co]) * s + bnp[64 + co];
#pragma unroll
            for (int r_ = 0; r_ < 4; ++r_)
                acc[kx][nt][r_] = fmaxf(acc[kx][nt][r_] * s + sh, 0.f);
        }
#pragma unroll
        for (int jj = 0; jj < 2; ++jj) {
            float s00 = 0.f, s01 = 0.f;
#pragma unroll
            for (int nt = 0; nt < 4; ++nt) {
                float xv0 = acc[kx][nt][2 * jj], xv1 = acc[kx][nt][2 * jj + 1];
                s00 += xv0 * xv0;
                s01 += xv0 * xv1;
            }
#pragma unroll
            for (int o = 8; o > 0; o >>= 1) {
                s00 += __shfl_xor(s00, o);
                s01 += __shfl_xor(s01, o);
            }
            float a0 = s00 * 0.125f, a1 = s01 * 0.125f;
            float mx = fmaxf(a0, a1);
            float e0 = expf(a0 - mx), e1 = expf(a1 - mx);
            float inv = 1.f / (e0 + e1);
            int pl = wv * 8 + quad * 2 + jj;    // 0..31
#pragma unroll
            for (int nt = 0; nt < 4; ++nt)
                Ot[nt * 16 + l16][2 * pl + kx] =
                    (e0 * acc[kx][nt][2 * jj] + e1 * acc[kx][nt][2 * jj + 1]) * inv;
        }
    }
    __syncthreads();

    int yo = 2 * iy + ky;
#pragma unroll
    for (int i = 0; i < 16; ++i) {
        int idx = i * 256 + tid;
        int co = idx >> 6, xx = idx & 63;
        out[(size_t)co * HWOUT + (size_t)yo * XD + 2 * j0 + xx] = Ot[co][xx];
    }
}

// ---------------------------------------------------------------------------
extern "C" void kernel_launch(void* const* d_in, const int* in_sizes, int n_in,
                              void* d_out, int out_size, void* d_ws, size_t ws_size,
                              hipStream_t stream) {
    const float* sp    = (const float*)d_in[0];
    const float* w_in  = (const float*)d_in[1];
    const float* w0    = (const float*)d_in[2];
    const float* bnp0  = (const float*)d_in[3];
    const float* w0a   = (const float*)d_in[4];
    const float* bnp0a = (const float*)d_in[5];
    const float* w0b   = (const float*)d_in[6];
    const float* bnp0b = (const float*)d_in[7];
    const float* w1    = (const float*)d_in[8];
    const float* bnp1  = (const float*)d_in[9];
    const float* w1a   = (const float*)d_in[10];
    const float* bnp1a = (const float*)d_in[11];
    const float* w1b   = (const float*)d_in[12];
    const float* bnp1b = (const float*)d_in[13];
    const float* ct0w  = (const float*)d_in[14];
    const float* ct0b  = (const float*)d_in[15];
    const float* bnt0  = (const float*)d_in[16];
    const float* ct1w  = (const float*)d_in[17];
    const float* ct1b  = (const float*)d_in[18];
    const float* bnt1  = (const float*)d_in[19];
    const int* coords0 = (const int*)d_in[20];
    const int* coords1 = (const int*)d_in[21];
    const int* g0 = (const int*)d_in[22];
    const int* s0 = (const int*)d_in[23];
    const int* ga = (const int*)d_in[24];
    const int* sa = (const int*)d_in[25];
    const int* g1 = (const int*)d_in[26];
    const int* s1 = (const int*)d_in[27];
    const int* gb = (const int*)d_in[28];
    const int* sb = (const int*)d_in[29];
    float* out = (float*)d_out;

    // -------- workspace carve --------
    __half* fInH = (__half*)d_ws;
    __half* R1h  = fInH + 640000;
    __half* R2h  = R1h + 22528000;
    __half* wt0  = R2h + 22528000;
    __half* wt0a = wt0  + 27648;
    __half* wt0b = wt0a + 27648;
    __half* wt1  = wt0b + 27648;          // [27][64][32]
    __half* wt1a = wt1  + 55296;          // [27][64][64]
    __half* wt1b = wt1a + 110592;
    __half* wtT0 = wt1b + 110592;         // [64][320]
    __half* wtT1 = wtT0 + 20480;          // [4][64][320]
    int*   nbrT = (int*)(wtT1 + 81920);   // 27*CAP0C ints = 14,580,000
    int*   v2r0 = nbrT;                          // 2,816,000 ints (aliases)
    int*   v2r1 = nbrT + 2816000;                //   352,000 ints (aliases)
    int*   nAct = nbrT + 14580000;               // 2 ints, beyond nbrT region

    // 0) weight conversion + n_act (binary search on coords pad boundary)
    find_nact<<<1, 128, 0, stream>>>(coords0, coords1, nAct);
    cvt_w<<<(27*32*32 + 255) / 256, 256, 0, stream>>>(w0,  wt0,  32, 32);
    cvt_w<<<(27*32*32 + 255) / 256, 256, 0, stream>>>(w0a, wt0a, 32, 32);
    cvt_w<<<(27*32*32 + 255) / 256, 256, 0, stream>>>(w0b, wt0b, 32, 32);
    cvt_w<<<(27*32*64 + 255) / 256, 256, 0, stream>>>(w1,  wt1,  32, 64);
    cvt_w<<<(27*64*64 + 255) / 256, 256, 0, stream>>>(w1a, wt1a, 64, 64);
    cvt_w<<<(27*64*64 + 255) / 256, 256, 0, stream>>>(w1b, wt1b, 64, 64);
    cvt_ct0<<<(64*320 + 255) / 256, 256, 0, stream>>>(ct0w, wtT0);
    cvt_ct1<<<(4*64*320 + 255) / 256, 256, 0, stream>>>(ct1w, wtT1);

    // 1) input channel lift (f16 rows out)
    gemm_in<<<(N_PTS_IN * 8 + 255) / 256, 256, 0, stream>>>(sp, w_in, fInH);

    // 2) conv0 (stride-1 spconv, 32->32): fInH -> R1h
    hipMemsetAsync(nbrT, 0xFF, (size_t)CAP0C * 27 * 4, stream);
    build_nbr<<<(27 * N_PTS_IN + 255) / 256, 256, 0, stream>>>(g0, s0, nbrT, N_PTS_IN, CAP0C);
    spconv_reg<32, 32><<<(CAP0C + 127) / 128, 256, 0, stream>>>(fInH, wt0, bnp0, nbrT, R1h, CAP0C, nAct + 0);

    // 3) subm a/b (32->32), shared rulebook: R1h -> R2h -> R1h
    hipMemsetAsync(nbrT, 0xFF, (size_t)CAP0C * 27 * 4, stream);
    build_nbr<<<(27 * CAP0C + 255) / 256, 256, 0, stream>>>(ga, sa, nbrT, CAP0C, CAP0C);
    spconv_reg<32, 32><<<(CAP0C + 127) / 128, 256, 0, stream>>>(R1h, wt0a, bnp0a, nbrT, R2h, CAP0C, nAct + 0);
    spconv_reg<32, 32><<<(CAP0C + 127) / 128, 256, 0, stream>>>(R2h, wt0b, bnp0b, nbrT, R1h, CAP0C, nAct + 0);

    // 4) BEV head 0 (reads R1h) -> out channels [0,64)
    hipMemsetAsync(v2r0, 0xFF, (size_t)2816000 * 4, stream);
    build_vox<<<(CAP0C + 255) / 256, 256, 0, stream>>>(coords0, v2r0, CAP0C, ZD, YD, XD);
    bev0_mfma<<<YD * 11, 256, 0, stream>>>(R1h, wtT0, ct0b, bnt0, v2r0, out);

    // 5) conv1 (stride-2 spconv, 32->64): R1h -> R2h
    hipMemsetAsync(nbrT, 0xFF, (size_t)CAP1C * 27 * 4, stream);
    build_nbr<<<(27 * CAP0C + 255) / 256, 256, 0, stream>>>(g1, s1, nbrT, CAP0C, CAP1C);
    spconv_reg<32, 64><<<(CAP1C + 127) / 128, 256, 0, stream>>>(R1h, wt1, bnp1, nbrT, R2h, CAP1C, nAct + 1);

    // 6) subm 1a/1b (64->64), shared rulebook: R2h -> R1h -> R2h
    hipMemsetAsync(nbrT, 0xFF, (size_t)CAP1C * 27 * 4, stream);
    build_nbr<<<(27 * CAP1C + 255) / 256, 256, 0, stream>>>(gb, sb, nbrT, CAP1C, CAP1C);
    spconv_reg<64, 64><<<(CAP1C + 127) / 128, 256, 0, stream>>>(R2h, wt1a, bnp1a, nbrT, R1h, CAP1C, nAct + 1);
    spconv_reg<64, 64><<<(CAP1C + 127) / 128, 256, 0, stream>>>(R1h, wt1b, bnp1b, nbrT, R2h, CAP1C, nAct + 1);

    // 7) BEV head 1 (reads R2h) -> out channels [64,128)
    hipMemsetAsync(v2r1, 0xFF, (size_t)352000 * 4, stream);
    build_vox<<<(CAP1C + 255) / 256, 256, 0, stream>>>(coords1, v2r1, CAP1C, Z1D, Y1D, X1D);
    bev1_mfma<<<Y1D * 11 * 2, 256, 0, stream>>>(R2h, wtT1, ct1b, bnt1, v2r1, out + (size_t)64 * HWOUT);
}

// Round 14
// 933.429 us; speedup vs baseline: 3.2223x; 1.0013x over previous
//
#include <hip/hip_runtime.h>
#include <hip/hip_bf16.h>
#include <hip/hip_fp16.h>

// Problem constants
#define N_PTS_IN   20000
#define CAP0C      540000
#define CAP1C      352000
#define ZD 10
#define YD 200
#define XD 704
#define Z1D 5
#define Y1D 100
#define X1D 352
#define HWOUT (YD*XD)   // 140800

typedef _Float16 f16x8 __attribute__((ext_vector_type(8)));
typedef float    f32x4 __attribute__((ext_vector_type(4)));

// ---------------------------------------------------------------------------
// f_in = sp_feats @ w_in   (20000x64 @ 64x32), f16 output rows
__global__ __launch_bounds__(256) void gemm_in(const float* __restrict__ sp,
                                               const float* __restrict__ w,
                                               __half* __restrict__ fout) {
    int tid = blockIdx.x * 256 + threadIdx.x;
    int row = tid >> 3;
    int c4  = (tid & 7) * 4;
    if (row >= N_PTS_IN) return;
    float4 acc = {0.f, 0.f, 0.f, 0.f};
    const float* sr = sp + (size_t)row * 64;
#pragma unroll
    for (int ci = 0; ci < 64; ci += 4) {
        float4 fv = *(const float4*)(sr + ci);
        const float* wp = w + ci * 32 + c4;
        float4 w0 = *(const float4*)(wp);
        float4 w1 = *(const float4*)(wp + 32);
        float4 w2 = *(const float4*)(wp + 64);
        float4 w3 = *(const float4*)(wp + 96);
        acc.x += fv.x*w0.x + fv.y*w1.x + fv.z*w2.x + fv.w*w3.x;
        acc.y += fv.x*w0.y + fv.y*w1.y + fv.z*w2.y + fv.w*w3.y;
        acc.z += fv.x*w0.z + fv.y*w1.z + fv.z*w2.z + fv.w*w3.z;
        acc.w += fv.x*w0.w + fv.y*w1.w + fv.z*w2.w + fv.w*w3.w;
    }
    __half* fo = fout + (size_t)row * 32 + c4;
    fo[0] = __float2half(acc.x);
    fo[1] = __float2half(acc.y);
    fo[2] = __float2half(acc.z);
    fo[3] = __float2half(acc.w);
}

// ---------------------------------------------------------------------------
// Weight convert+transpose: src f32 [27][CIN][COUT] -> dst f16 [27][COUT][CIN]
__global__ __launch_bounds__(256) void cvt_w(const float* __restrict__ src,
                                             __half* __restrict__ dst,
                                             int CIN, int COUT) {
    int i = blockIdx.x * 256 + threadIdx.x;
    if (i >= 27 * CIN * COUT) return;
    int ci = i % CIN;
    int t  = i / CIN;
    int co = t % COUT;
    int k  = t / COUT;
    dst[i] = __float2half(src[((size_t)k * CIN + ci) * COUT + co]);
}

// ct0_w f32 [320][64] (ci=c*10+z) -> f16 [co][zc=z*32+c]
__global__ __launch_bounds__(256) void cvt_ct0(const float* __restrict__ src,
                                               __half* __restrict__ dst) {
    int i = blockIdx.x * 256 + threadIdx.x;
    if (i >= 64 * 320) return;
    int zc = i % 320, co = i / 320;
    int z = zc >> 5, c = zc & 31;
    dst[i] = __float2half(src[(c * 10 + z) * 64 + co]);
}

// ct1_w f32 [320][64][2][2] (ci=c*5+z) -> f16 [kq][co][zc=z*64+c]
__global__ __launch_bounds__(256) void cvt_ct1(const float* __restrict__ src,
                                               __half* __restrict__ dst) {
    int i = blockIdx.x * 256 + threadIdx.x;
    if (i >= 4 * 64 * 320) return;
    int zc = i % 320;
    int t  = i / 320;
    int co = t & 63;
    int kq = t >> 6;
    int z = zc >> 6, c = zc & 63;
    dst[i] = __float2half(src[((c * 5 + z) * 64 + co) * 4 + kq]);
}

// ---------------------------------------------------------------------------
// Rulebook inversion, TRANSPOSED: nbrT[k*cap + s] = g. Scatter-only.
__global__ __launch_bounds__(256) void build_nbr(const int* __restrict__ g,
                                                 const int* __restrict__ s,
                                                 int* __restrict__ nbrT,
                                                 int P, int cap) {
    int i = blockIdx.x * 256 + threadIdx.x;
    if (i >= 27 * P) return;
    int k = i / P, p = i - k * P;
    int sv = s[(size_t)k * P + p];
    if (sv >= cap) return;              // dummy pair
    nbrT[(size_t)k * cap + sv] = g[(size_t)k * P + p];
}

// ---------------------------------------------------------------------------
// n_act via binary search on the coords pad boundary (z == Zdim marks pad).
__global__ __launch_bounds__(128) void find_nact(const int* __restrict__ c0,
                                                 const int* __restrict__ c1,
                                                 int* __restrict__ nA) {
    int t = threadIdx.x;
    if (t == 0) {
        int lo = 0, hi = CAP0C;
        while (lo < hi) {
            int mid = (lo + hi) >> 1;
            if (c0[4 * mid + 1] >= ZD) hi = mid; else lo = mid + 1;
        }
        nA[0] = lo;
    } else if (t == 64) {
        int lo = 0, hi = CAP1C;
        while (lo < hi) {
            int mid = (lo + hi) >> 1;
            if (c1[4 * mid + 1] >= Z1D) hi = mid; else lo = mid + 1;
        }
        nA[1] = lo;
    }
}

// voxel -> sparse-row index (pad coords have z == Zdim, dropped like JAX OOB)
__global__ __launch_bounds__(256) void build_vox(const int* __restrict__ coords,
                                                 int* __restrict__ v2r,
                                                 int cap, int Zdim, int Ydim, int Xdim) {
    int r = blockIdx.x * 256 + threadIdx.x;
    if (r >= cap) return;
    int b = coords[4*r], z = coords[4*r+1], y = coords[4*r+2], x = coords[4*r+3];
    if (z >= Zdim) return;
    v2r[(((size_t)b * Zdim + z) * Ydim + y) * Xdim + x] = r;
}

// ---------------------------------------------------------------------------
// Implicit-GEMM sparse conv via f16 MFMA 16x16x32, + BN + ReLU.
// v18 structure UNCHANGED (weights-via-LDS + dead-block early exit +
// feature prefetch depth-1 + counted-wait barrier). Three spconv
// micro-predictions missed; frozen until spconv counters resurface.
template <int CIN, int COUT>
__global__ __launch_bounds__(256) void spconv_reg(const __half* __restrict__ f,
                                                  const __half* __restrict__ wt,
                                                  const float* __restrict__ bnp,
                                                  const int* __restrict__ nbrT,
                                                  __half* __restrict__ fout,
                                                  int ncap,
                                                  const int* __restrict__ nA) {
    constexpr int NT = COUT / 16;       // 16-col output tiles
    constexpr int KT = CIN / 32;        // K=32 MFMA steps per k-offset
    constexpr int NCHUNK = CIN / 8;     // 16B chunks per weight row
    constexpr int MASK = NCHUNK - 1;
    constexpr int LCH  = (NCHUNK == 8) ? 3 : 2;
    constexpr int TILE_H = COUT * CIN;  // halves per weight tile
    constexpr int TB = TILE_H * 2 / 256; // stage bytes per thread (8/16/32)
    constexpr int OST_H = 4 * 32 * COUT;
    constexpr int SH_H = (2 * TILE_H > OST_H) ? 2 * TILE_H : OST_H;
    __shared__ __align__(16) __half S[SH_H];

    int tid = threadIdx.x;
    int wv = tid >> 6, lane = tid & 63;
    int quad = lane >> 4, l16 = lane & 15;

    // interleaved-group XCD swizzle (live-prefix-safe, bijective)
    int bid = blockIdx.x;
    int nfull = (int)gridDim.x & ~63;
    int sb;
    if (bid < nfull) {
        int grp = bid >> 6, w = bid & 63;
        sb = grp * 64 + (w & 7) * 8 + (w >> 3);
    } else {
        sb = bid;
    }

    // dead-block early exit: rows >= n_act have no pairs for any k
    if (sb * 128 >= *nA) return;

    int m0 = sb * 128 + wv * 32;       // wave's first output row
    int r0 = m0 + l16;                 // this lane's row for m=0
    int r1 = m0 + 16 + l16;            // this lane's row for m=1
    bool ok0 = r0 < ncap, ok1 = r1 < ncap;

    f32x4 acc[2][NT] = {};

    // index pipeline depth 2
    int gC0 = ok0 ? nbrT[r0] : -1;
    int gC1 = ok1 ? nbrT[r1] : -1;
    int gN0 = ok0 ? nbrT[(size_t)ncap + r0] : -1;
    int gN1 = ok1 ? nbrT[(size_t)ncap + r1] : -1;
    bool anyC = __ballot((gC0 >= 0) || (gC1 >= 0)) != 0ull;
    bool ever = false;

    // ---- feature prologue: gather k=0 rows into registers ----
    f16x8 aC0[KT], aC1[KT];
#pragma unroll
    for (int kt = 0; kt < KT; ++kt) {
        uint4 z4 = {0u,0u,0u,0u};
        aC0[kt] = *(f16x8*)&z4;
        aC1[kt] = *(f16x8*)&z4;
    }
    if (anyC) {
        const __half* p0 = f + (size_t)((gC0 < 0) ? 0 : gC0) * CIN + quad * 8;
        const __half* p1 = f + (size_t)((gC1 < 0) ? 0 : gC1) * CIN + quad * 8;
#pragma unroll
        for (int kt = 0; kt < KT; ++kt) {
            uint4 u0 = {0u,0u,0u,0u}, u1 = {0u,0u,0u,0u};
            if (gC0 >= 0) u0 = *(const uint4*)(p0 + kt * 32);
            if (gC1 >= 0) u1 = *(const uint4*)(p1 + kt * 32);
            aC0[kt] = *(f16x8*)&u0;
            aC1[kt] = *(f16x8*)&u1;
        }
    }

    // ---- weight prologue: stage tile k=0 into buffer 0 ----
    {
        const char* src = (const char*)(wt) + tid * TB;
        if constexpr (TB == 32) {
            uint4 w0 = *(const uint4*)src;
            uint4 w1 = *(const uint4*)(src + 16);
            int p0 = tid * 2;
#pragma unroll
            for (int j = 0; j < 2; ++j) {
                int p = p0 + j;
                int row = p >> LCH, c = p & MASK;
                *(uint4*)(S + (row * NCHUNK + (c ^ (row & MASK))) * 8) = (j ? w1 : w0);
            }
        } else if constexpr (TB == 16) {
            uint4 w0 = *(const uint4*)src;
            int p = tid;
            int row = p >> LCH, c = p & MASK;
            *(uint4*)(S + (row * NCHUNK + (c ^ (row & MASK))) * 8) = w0;
        } else {
            uint2 w0 = *(const uint2*)src;
            int p = tid >> 1, half = tid & 1;
            int row = p >> LCH, c = p & MASK;
            *(uint2*)(S + (row * NCHUNK + (c ^ (row & MASK))) * 8 + half * 4) = w0;
        }
    }
    __syncthreads();   // prologue barrier: full drain is fine (once)

#pragma unroll 1
    for (int k = 0; k < 27; ++k) {
        // (1) idx k+2 (oldest in-flight)
        int gNN0 = -1, gNN1 = -1;
        if (k + 2 < 27) {
            if (ok0) gNN0 = nbrT[(size_t)(k + 2) * ncap + r0];
            if (ok1) gNN1 = nbrT[(size_t)(k + 2) * ncap + r1];
        }
        // (2) gather k+1 rows -> aN (vmcnt stays COUNTED across the barrier)
        bool anyN = __ballot((gN0 >= 0) || (gN1 >= 0)) != 0ull;
        f16x8 aN0[KT], aN1[KT];
#pragma unroll
        for (int kt = 0; kt < KT; ++kt) {
            uint4 z4 = {0u,0u,0u,0u};
            aN0[kt] = *(f16x8*)&z4;
            aN1[kt] = *(f16x8*)&z4;
        }
        if (anyN) {
            const __half* p0 = f + (size_t)((gN0 < 0) ? 0 : gN0) * CIN + quad * 8;
            const __half* p1 = f + (size_t)((gN1 < 0) ? 0 : gN1) * CIN + quad * 8;
#pragma unroll
            for (int kt = 0; kt < KT; ++kt) {
                uint4 u0 = {0u,0u,0u,0u}, u1 = {0u,0u,0u,0u};
                if (gN0 >= 0) u0 = *(const uint4*)(p0 + kt * 32);
                if (gN1 >= 0) u1 = *(const uint4*)(p1 + kt * 32);
                aN0[kt] = *(f16x8*)&u0;
                aN1[kt] = *(f16x8*)&u1;
            }
        }
        // (3) stage loads for weight tile k+1 -> regs
        bool doStage = (k + 1 < 27);
        uint4 w0{}, w1{}; uint2 w2{};
        if (doStage) {
            const char* src = (const char*)(wt + (size_t)(k + 1) * TILE_H) + tid * TB;
            if constexpr (TB == 32)      { w0 = *(const uint4*)src; w1 = *(const uint4*)(src + 16); }
            else if constexpr (TB == 16) { w0 = *(const uint4*)src; }
            else                         { w2 = *(const uint2*)src; }
        }
        // (4) ds_read B + (5) MFMA on aC (ready since previous barrier)
        if (anyC) {
            ever = true;
            const __half* Wb = S + (k & 1) * TILE_H;
#pragma unroll
            for (int kt = 0; kt < KT; ++kt) {
#pragma unroll
                for (int nt = 0; nt < NT; ++nt) {
                    int row = nt * 16 + l16;
                    int c   = kt * 4 + quad;
                    f16x8 b = *(const f16x8*)(Wb + (row * NCHUNK + (c ^ (row & MASK))) * 8);
                    acc[0][nt] = __builtin_amdgcn_mfma_f32_16x16x32_f16(aC0[kt], b, acc[0][nt], 0, 0, 0);
                    acc[1][nt] = __builtin_amdgcn_mfma_f32_16x16x32_f16(aC1[kt], b, acc[1][nt], 0, 0, 0);
                }
            }
        }
        // (6) ds_write staging into the other buffer
        if (doStage) {
            __half* dst = S + ((k + 1) & 1) * TILE_H;
            if constexpr (TB == 32) {
                int p0 = tid * 2;
#pragma unroll
                for (int j = 0; j < 2; ++j) {
                    int p = p0 + j;
                    int row = p >> LCH, c = p & MASK;
                    *(uint4*)(dst + (row * NCHUNK + (c ^ (row & MASK))) * 8) = (j ? w1 : w0);
                }
            } else if constexpr (TB == 16) {
                int p = tid;
                int row = p >> LCH, c = p & MASK;
                *(uint4*)(dst + (row * NCHUNK + (c ^ (row & MASK))) * 8) = w0;
            } else {
                int p = tid >> 1, half = tid & 1;
                int row = p >> LCH, c = p & MASK;
                *(uint2*)(dst + (row * NCHUNK + (c ^ (row & MASK))) * 8 + half * 4) = w2;
            }
        }
        // counted-wait barrier: drain LDS only; vmcnt stays in flight.
        asm volatile("s_waitcnt lgkmcnt(0)" ::: "memory");
        __builtin_amdgcn_s_barrier();
        // rotate pipelines
#pragma unroll
        for (int kt = 0; kt < KT; ++kt) { aC0[kt] = aN0[kt]; aC1[kt] = aN1[kt]; }
        anyC = anyN;
        gC0 = gN0; gC1 = gN1; gN0 = gNN0; gN1 = gNN1;
    }

    // epilogue: BN + ReLU -> wave-private LDS (weight bufs dead) -> store.
    if (!ever) return;
    __half* O = S + wv * (32 * COUT);
#pragma unroll
    for (int nt = 0; nt < NT; ++nt) {
        int co = nt * 16 + l16;
        float g = bnp[co], b = bnp[COUT + co];
        float mn = bnp[2*COUT + co], vv = bnp[3*COUT + co];
        float s  = g * rsqrtf(vv + 1e-5f);
        float sh = b - mn * s;
#pragma unroll
        for (int m = 0; m < 2; ++m)
#pragma unroll
            for (int r_ = 0; r_ < 4; ++r_) {
                int row = m * 16 + quad * 4 + r_;
                O[row * COUT + co] = __float2half(fmaxf(acc[m][nt][r_] * s + sh, 0.f));
            }
    }
    constexpr int OCH = COUT / 8;              // 16B chunks per out row
#pragma unroll
    for (int j = 0; j < 32 * OCH / 64; ++j) {
        int idx = j * 64 + lane;
        int r = idx / OCH, c = idx % OCH;
        if (m0 + r < ncap)
            *(uint4*)(fout + (size_t)(m0 + r) * COUT + c * 8) =
                *(const uint4*)(O + r * COUT + c * 8);
    }
}

// ---------------------------------------------------------------------------
// BEV head 0, v19: SOFTWARE-PIPELINED fragments.
// R13 diagnosis: VGPR_Count 72 -- the compiler had no registers to hoist
// the 80 interleaved {B-load -> MFMA} pairs, so every MFMA's in-order vmcnt
// exposed ~L2 latency. Explicit aN/bN prefetch for ks+1 forces the
// allocation: MFMA consumes registers loaded one iteration earlier
// (already retired); the 6 new loads stay in flight (counted vmcnt).
__global__ __launch_bounds__(256) void bev0_mfma(const __half* __restrict__ f0,
                                                 const __half* __restrict__ wtT,  // [64][320] zc=z*32+c
                                                 const float* __restrict__ bias,
                                                 const float* __restrict__ bnp,
                                                 const int* __restrict__ v2r,
                                                 float* __restrict__ out) {
    __shared__ float Ot[64][66];
    int tid = threadIdx.x;
    int y = blockIdx.x / 11, x0 = (blockIdx.x % 11) * 64;
    int wv = tid >> 6, lane = tid & 63;
    int quad = lane >> 4, l16 = lane & 15;

    // v2r preload: 2 m-tiles x 10 z-slices (static-indexed -> registers)
    int rz[2][10];
#pragma unroll
    for (int m = 0; m < 2; ++m) {
        int row = wv * 32 + m * 16 + l16;
        int b = row & 1, p = row >> 1;
#pragma unroll
        for (int z = 0; z < 10; ++z)
            rz[m][z] = v2r[((b * ZD + z) * YD + y) * XD + x0 + p];
    }

    f32x4 acc[2][4] = {};
    // prologue: load fragments for ks = 0
    f16x8 aC[2], bC[4];
#pragma unroll
    for (int m = 0; m < 2; ++m) {
        uint4 u = {0u,0u,0u,0u};
        int r = rz[m][0];
        if (r >= 0) u = *(const uint4*)(f0 + (size_t)r * 32 + quad * 8);
        aC[m] = *(f16x8*)&u;
    }
#pragma unroll
    for (int nt = 0; nt < 4; ++nt)
        bC[nt] = *(const f16x8*)(wtT + (size_t)(nt * 16 + l16) * 320 + quad * 8);

#pragma unroll
    for (int ks = 0; ks < 10; ++ks) {
        // prefetch ks+1 fragments (stay in flight across this iter's MFMA)
        f16x8 aN[2], bN[4];
        if (ks + 1 < 10) {
#pragma unroll
            for (int m = 0; m < 2; ++m) {
                uint4 u = {0u,0u,0u,0u};
                int r = rz[m][ks + 1];
                if (r >= 0) u = *(const uint4*)(f0 + (size_t)r * 32 + quad * 8);
                aN[m] = *(f16x8*)&u;
            }
#pragma unroll
            for (int nt = 0; nt < 4; ++nt)
                bN[nt] = *(const f16x8*)(wtT + (size_t)(nt * 16 + l16) * 320 + (ks + 1) * 32 + quad * 8);
        } else {
            uint4 z4 = {0u,0u,0u,0u};
#pragma unroll
            for (int m = 0; m < 2; ++m) aN[m] = *(f16x8*)&z4;
#pragma unroll
            for (int nt = 0; nt < 4; ++nt) bN[nt] = *(f16x8*)&z4;
        }
        // MFMA on current fragments (loaded one iteration ago -> retired)
#pragma unroll
        for (int nt = 0; nt < 4; ++nt) {
            acc[0][nt] = __builtin_amdgcn_mfma_f32_16x16x32_f16(aC[0], bC[nt], acc[0][nt], 0, 0, 0);
            acc[1][nt] = __builtin_amdgcn_mfma_f32_16x16x32_f16(aC[1], bC[nt], acc[1][nt], 0, 0, 0);
        }
        aC[0] = aN[0]; aC[1] = aN[1];
#pragma unroll
        for (int nt = 0; nt < 4; ++nt) bC[nt] = bN[nt];
    }

    // BN + ReLU in-place (channels are lane-local: co = nt*16 + l16)
#pragma unroll
    for (int nt = 0; nt < 4; ++nt) {
        int co = nt * 16 + l16;
        float s  = bnp[co] * rsqrtf(bnp[192 + co] + 1e-5f);
        float sh = (bias[co] - bnp[128 + co]) * s + bnp[64 + co];
#pragma unroll
        for (int m = 0; m < 2; ++m)
#pragma unroll
            for (int r_ = 0; r_ < 4; ++r_)
                acc[m][nt][r_] = fmaxf(acc[m][nt][r_] * s + sh, 0.f);
    }

    // lane-local pair attention
#pragma unroll
    for (int m = 0; m < 2; ++m)
#pragma unroll
        for (int jj = 0; jj < 2; ++jj) {
            float s00 = 0.f, s01 = 0.f;
#pragma unroll
            for (int nt = 0; nt < 4; ++nt) {
                float xv0 = acc[m][nt][2 * jj], xv1 = acc[m][nt][2 * jj + 1];
                s00 += xv0 * xv0;
                s01 += xv0 * xv1;
            }
#pragma unroll
            for (int o = 8; o > 0; o >>= 1) {
                s00 += __shfl_xor(s00, o);
                s01 += __shfl_xor(s01, o);
            }
            float a0 = s00 * 0.125f, a1 = s01 * 0.125f;
            float mx = fmaxf(a0, a1);
            float e0 = expf(a0 - mx), e1 = expf(a1 - mx);
            float inv = 1.f / (e0 + e1);
            int pl = wv * 16 + m * 8 + quad * 2 + jj;
#pragma unroll
            for (int nt = 0; nt < 4; ++nt)
                Ot[nt * 16 + l16][pl] =
                    (e0 * acc[m][nt][2 * jj] + e1 * acc[m][nt][2 * jj + 1]) * inv;
        }
    __syncthreads();

#pragma unroll
    for (int i = 0; i < 16; ++i) {
        int idx = i * 256 + tid;
        int co = idx >> 6, px = idx & 63;
        out[(size_t)co * HWOUT + (size_t)y * XD + x0 + px] = Ot[co][px];
    }
}

// ---------------------------------------------------------------------------
// BEV head 1, v19: A gathered once (v15) + B consumed in 5 groups of 8
// fragments with an explicit double buffer -- MFMA group g uses loads
// issued at group g-1 (counted vmcnt(8), never drained).
__global__ __launch_bounds__(256) void bev1_mfma(const __half* __restrict__ f1,
                                                 const __half* __restrict__ wtT,  // [4][64][320] zc=z*64+c
                                                 const float* __restrict__ bias,
                                                 const float* __restrict__ bnp,
                                                 const int* __restrict__ v2r,
                                                 float* __restrict__ out) {
    __shared__ float Ot[64][66];
    int tid = threadIdx.x;
    int bid = blockIdx.x;
    int ky = bid & 1;
    int t  = bid >> 1;
    int iy = t / 11, j0 = (t % 11) * 32;
    int wv = tid >> 6, lane = tid & 63;
    int quad = lane >> 4, l16 = lane & 15;

    int row = wv * 16 + l16;
    int b = row & 1, p = row >> 1;
    int rz[5];
#pragma unroll
    for (int z = 0; z < 5; ++z)
        rz[z] = v2r[((b * Z1D + z) * Y1D + iy) * X1D + j0 + p];

    // gather all 10 A fragments once (independent loads, one latency window)
    f16x8 a[10];
#pragma unroll
    for (int ks = 0; ks < 10; ++ks) {
        int z = ks >> 1, hf = ks & 1;
        uint4 u = {0u,0u,0u,0u};
        int r = rz[z];
        if (r >= 0) u = *(const uint4*)(f1 + (size_t)r * 64 + hf * 32 + quad * 8);
        a[ks] = *(f16x8*)&u;
    }

    f32x4 acc[2][4] = {};
#pragma unroll
    for (int kx = 0; kx < 2; ++kx) {
        const __half* wk = wtT + (size_t)(ky * 2 + kx) * 64 * 320;
        // prologue: group 0 (ks = 0,1)
        f16x8 bC[8];
#pragma unroll
        for (int j = 0; j < 8; ++j) {
            int ks = j >> 2, nt = j & 3;
            bC[j] = *(const f16x8*)(wk + (size_t)(nt * 16 + l16) * 320 + ks * 32 + quad * 8);
        }
#pragma unroll
        for (int g = 0; g < 5; ++g) {
            // prefetch group g+1 (stays in flight across this group's MFMA)
            f16x8 bN[8];
            if (g + 1 < 5) {
#pragma unroll
                for (int j = 0; j < 8; ++j) {
                    int ks = (g + 1) * 2 + (j >> 2), nt = j & 3;
                    bN[j] = *(const f16x8*)(wk + (size_t)(nt * 16 + l16) * 320 + ks * 32 + quad * 8);
                }
            } else {
                uint4 z4 = {0u,0u,0u,0u};
#pragma unroll
                for (int j = 0; j < 8; ++j) bN[j] = *(f16x8*)&z4;
            }
            // MFMA on current group (loads issued at group g-1 -> retired)
#pragma unroll
            for (int j = 0; j < 8; ++j) {
                int ks = g * 2 + (j >> 2), nt = j & 3;
                acc[kx][nt] = __builtin_amdgcn_mfma_f32_16x16x32_f16(a[ks], bC[j], acc[kx][nt], 0, 0, 0);
            }
#pragma unroll
            for (int j = 0; j < 8; ++j) bC[j] = bN[j];
        }
    }

    // BN + ReLU in-place, then lane-local pair attention per kx
#pragma unroll
    for (int kx = 0; kx < 2; ++kx) {
#pragma unroll
        for (int nt = 0; nt < 4; ++nt) {
            int co = nt * 16 + l16;
            float s  = bnp[co] * rsqrtf(bnp[192 + co] + 1e-5f);
            float sh = (bias[co] - bnp[128 + co]) * s + bnp[64 + co];
#pragma unroll
            for (int r_ = 0; r_ < 4; ++r_)
                acc[kx][nt][r_] = fmaxf(acc[kx][nt][r_] * s + sh, 0.f);
        }
#pragma unroll
        for (int jj = 0; jj < 2; ++jj) {
            float s00 = 0.f, s01 = 0.f;
#pragma unroll
            for (int nt = 0; nt < 4; ++nt) {
                float xv0 = acc[kx][nt][2 * jj], xv1 = acc[kx][nt][2 * jj + 1];
                s00 += xv0 * xv0;
                s01 += xv0 * xv1;
            }
#pragma unroll
            for (int o = 8; o > 0; o >>= 1) {
                s00 += __shfl_xor(s00, o);
                s01 += __shfl_xor(s01, o);
            }
            float a0 = s00 * 0.125f, a1 = s01 * 0.125f;
            float mx = fmaxf(a0, a1);
            float e0 = expf(a0 - mx), e1 = expf(a1 - mx);
            float inv = 1.f / (e0 + e1);
            int pl = wv * 8 + quad * 2 + jj;    // 0..31
#pragma unroll
            for (int nt = 0; nt < 4; ++nt)
                Ot[nt * 16 + l16][2 * pl + kx] =
                    (e0 * acc[kx][nt][2 * jj] + e1 * acc[kx][nt][2 * jj + 1]) * inv;
        }
    }
    __syncthreads();

    int yo = 2 * iy + ky;
#pragma unroll
    for (int i = 0; i < 16; ++i) {
        int idx = i * 256 + tid;
        int co = idx >> 6, xx = idx & 63;
        out[(size_t)co * HWOUT + (size_t)yo * XD + 2 * j0 + xx] = Ot[co][xx];
    }
}

// ---------------------------------------------------------------------------
extern "C" void kernel_launch(void* const* d_in, const int* in_sizes, int n_in,
                              void* d_out, int out_size, void* d_ws, size_t ws_size,
                              hipStream_t stream) {
    const float* sp    = (const float*)d_in[0];
    const float* w_in  = (const float*)d_in[1];
    const float* w0    = (const float*)d_in[2];
    const float* bnp0  = (const float*)d_in[3];
    const float* w0a   = (const float*)d_in[4];
    const float* bnp0a = (const float*)d_in[5];
    const float* w0b   = (const float*)d_in[6];
    const float* bnp0b = (const float*)d_in[7];
    const float* w1    = (const float*)d_in[8];
    const float* bnp1  = (const float*)d_in[9];
    const float* w1a   = (const float*)d_in[10];
    const float* bnp1a = (const float*)d_in[11];
    const float* w1b   = (const float*)d_in[12];
    const float* bnp1b = (const float*)d_in[13];
    const float* ct0w  = (const float*)d_in[14];
    const float* ct0b  = (const float*)d_in[15];
    const float* bnt0  = (const float*)d_in[16];
    const float* ct1w  = (const float*)d_in[17];
    const float* ct1b  = (const float*)d_in[18];
    const float* bnt1  = (const float*)d_in[19];
    const int* coords0 = (const int*)d_in[20];
    const int* coords1 = (const int*)d_in[21];
    const int* g0 = (const int*)d_in[22];
    const int* s0 = (const int*)d_in[23];
    const int* ga = (const int*)d_in[24];
    const int* sa = (const int*)d_in[25];
    const int* g1 = (const int*)d_in[26];
    const int* s1 = (const int*)d_in[27];
    const int* gb = (const int*)d_in[28];
    const int* sb = (const int*)d_in[29];
    float* out = (float*)d_out;

    // -------- workspace carve --------
    __half* fInH = (__half*)d_ws;
    __half* R1h  = fInH + 640000;
    __half* R2h  = R1h + 22528000;
    __half* wt0  = R2h + 22528000;
    __half* wt0a = wt0  + 27648;
    __half* wt0b = wt0a + 27648;
    __half* wt1  = wt0b + 27648;          // [27][64][32]
    __half* wt1a = wt1  + 55296;          // [27][64][64]
    __half* wt1b = wt1a + 110592;
    __half* wtT0 = wt1b + 110592;         // [64][320]
    __half* wtT1 = wtT0 + 20480;          // [4][64][320]
    int*   nbrT = (int*)(wtT1 + 81920);   // 27*CAP0C ints = 14,580,000
    int*   v2r0 = nbrT;                          // 2,816,000 ints (aliases)
    int*   v2r1 = nbrT + 2816000;                //   352,000 ints (aliases)
    int*   nAct = nbrT + 14580000;               // 2 ints, beyond nbrT region

    // 0) weight conversion + n_act (binary search on coords pad boundary)
    find_nact<<<1, 128, 0, stream>>>(coords0, coords1, nAct);
    cvt_w<<<(27*32*32 + 255) / 256, 256, 0, stream>>>(w0,  wt0,  32, 32);
    cvt_w<<<(27*32*32 + 255) / 256, 256, 0, stream>>>(w0a, wt0a, 32, 32);
    cvt_w<<<(27*32*32 + 255) / 256, 256, 0, stream>>>(w0b, wt0b, 32, 32);
    cvt_w<<<(27*32*64 + 255) / 256, 256, 0, stream>>>(w1,  wt1,  32, 64);
    cvt_w<<<(27*64*64 + 255) / 256, 256, 0, stream>>>(w1a, wt1a, 64, 64);
    cvt_w<<<(27*64*64 + 255) / 256, 256, 0, stream>>>(w1b, wt1b, 64, 64);
    cvt_ct0<<<(64*320 + 255) / 256, 256, 0, stream>>>(ct0w, wtT0);
    cvt_ct1<<<(4*64*320 + 255) / 256, 256, 0, stream>>>(ct1w, wtT1);

    // 1) input channel lift (f16 rows out)
    gemm_in<<<(N_PTS_IN * 8 + 255) / 256, 256, 0, stream>>>(sp, w_in, fInH);

    // 2) conv0 (stride-1 spconv, 32->32): fInH -> R1h
    hipMemsetAsync(nbrT, 0xFF, (size_t)CAP0C * 27 * 4, stream);
    build_nbr<<<(27 * N_PTS_IN + 255) / 256, 256, 0, stream>>>(g0, s0, nbrT, N_PTS_IN, CAP0C);
    spconv_reg<32, 32><<<(CAP0C + 127) / 128, 256, 0, stream>>>(fInH, wt0, bnp0, nbrT, R1h, CAP0C, nAct + 0);

    // 3) subm a/b (32->32), shared rulebook: R1h -> R2h -> R1h
    hipMemsetAsync(nbrT, 0xFF, (size_t)CAP0C * 27 * 4, stream);
    build_nbr<<<(27 * CAP0C + 255) / 256, 256, 0, stream>>>(ga, sa, nbrT, CAP0C, CAP0C);
    spconv_reg<32, 32><<<(CAP0C + 127) / 128, 256, 0, stream>>>(R1h, wt0a, bnp0a, nbrT, R2h, CAP0C, nAct + 0);
    spconv_reg<32, 32><<<(CAP0C + 127) / 128, 256, 0, stream>>>(R2h, wt0b, bnp0b, nbrT, R1h, CAP0C, nAct + 0);

    // 4) BEV head 0 (reads R1h) -> out channels [0,64)
    hipMemsetAsync(v2r0, 0xFF, (size_t)2816000 * 4, stream);
    build_vox<<<(CAP0C + 255) / 256, 256, 0, stream>>>(coords0, v2r0, CAP0C, ZD, YD, XD);
    bev0_mfma<<<YD * 11, 256, 0, stream>>>(R1h, wtT0, ct0b, bnt0, v2r0, out);

    // 5) conv1 (stride-2 spconv, 32->64): R1h -> R2h
    hipMemsetAsync(nbrT, 0xFF, (size_t)CAP1C * 27 * 4, stream);
    build_nbr<<<(27 * CAP0C + 255) / 256, 256, 0, stream>>>(g1, s1, nbrT, CAP0C, CAP1C);
    spconv_reg<32, 64><<<(CAP1C + 127) / 128, 256, 0, stream>>>(R1h, wt1, bnp1, nbrT, R2h, CAP1C, nAct + 1);

    // 6) subm 1a/1b (64->64), shared rulebook: R2h -> R1h -> R2h
    hipMemsetAsync(nbrT, 0xFF, (size_t)CAP1C * 27 * 4, stream);
    build_nbr<<<(27 * CAP1C + 255) / 256, 256, 0, stream>>>(gb, sb, nbrT, CAP1C, CAP1C);
    spconv_reg<64, 64><<<(CAP1C + 127) / 128, 256, 0, stream>>>(R2h, wt1a, bnp1a, nbrT, R1h, CAP1C, nAct + 1);
    spconv_reg<64, 64><<<(CAP1C + 127) / 128, 256, 0, stream>>>(R1h, wt1b, bnp1b, nbrT, R2h, CAP1C, nAct + 1);

    // 7) BEV head 1 (reads R2h) -> out channels [64,128)
    hipMemsetAsync(v2r1, 0xFF, (size_t)352000 * 4, stream);
    build_vox<<<(CAP1C + 255) / 256, 256, 0, stream>>>(coords1, v2r1, CAP1C, Z1D, Y1D, X1D);
    bev1_mfma<<<Y1D * 11 * 2, 256, 0, stream>>>(R2h, wtT1, ct1b, bnt1, v2r1, out + (size_t)64 * HWOUT);
}

// Round 15
// 914.361 us; speedup vs baseline: 3.2895x; 1.0209x over previous
//
#include <hip/hip_runtime.h>
#include <hip/hip_bf16.h>
#include <hip/hip_fp16.h>

// Problem constants
#define N_PTS_IN   20000
#define CAP0C      540000
#define CAP1C      352000
#define ZD 10
#define YD 200
#define XD 704
#define Z1D 5
#define Y1D 100
#define X1D 352
#define HWOUT (YD*XD)   // 140800

typedef _Float16 f16x8 __attribute__((ext_vector_type(8)));
typedef float    f32x4 __attribute__((ext_vector_type(4)));

// ---------------------------------------------------------------------------
// f_in = sp_feats @ w_in   (20000x64 @ 64x32), f16 output rows
__global__ __launch_bounds__(256) void gemm_in(const float* __restrict__ sp,
                                               const float* __restrict__ w,
                                               __half* __restrict__ fout) {
    int tid = blockIdx.x * 256 + threadIdx.x;
    int row = tid >> 3;
    int c4  = (tid & 7) * 4;
    if (row >= N_PTS_IN) return;
    float4 acc = {0.f, 0.f, 0.f, 0.f};
    const float* sr = sp + (size_t)row * 64;
#pragma unroll
    for (int ci = 0; ci < 64; ci += 4) {
        float4 fv = *(const float4*)(sr + ci);
        const float* wp = w + ci * 32 + c4;
        float4 w0 = *(const float4*)(wp);
        float4 w1 = *(const float4*)(wp + 32);
        float4 w2 = *(const float4*)(wp + 64);
        float4 w3 = *(const float4*)(wp + 96);
        acc.x += fv.x*w0.x + fv.y*w1.x + fv.z*w2.x + fv.w*w3.x;
        acc.y += fv.x*w0.y + fv.y*w1.y + fv.z*w2.y + fv.w*w3.y;
        acc.z += fv.x*w0.z + fv.y*w1.z + fv.z*w2.z + fv.w*w3.z;
        acc.w += fv.x*w0.w + fv.y*w1.w + fv.z*w2.w + fv.w*w3.w;
    }
    __half* fo = fout + (size_t)row * 32 + c4;
    fo[0] = __float2half(acc.x);
    fo[1] = __float2half(acc.y);
    fo[2] = __float2half(acc.z);
    fo[3] = __float2half(acc.w);
}

// ---------------------------------------------------------------------------
// Weight convert+transpose: src f32 [27][CIN][COUT] -> dst f16 [27][COUT][CIN]
__global__ __launch_bounds__(256) void cvt_w(const float* __restrict__ src,
                                             __half* __restrict__ dst,
                                             int CIN, int COUT) {
    int i = blockIdx.x * 256 + threadIdx.x;
    if (i >= 27 * CIN * COUT) return;
    int ci = i % CIN;
    int t  = i / CIN;
    int co = t % COUT;
    int k  = t / COUT;
    dst[i] = __float2half(src[((size_t)k * CIN + ci) * COUT + co]);
}

// ct0_w f32 [320][64] (ci=c*10+z) -> f16 [co][zc=z*32+c]
__global__ __launch_bounds__(256) void cvt_ct0(const float* __restrict__ src,
                                               __half* __restrict__ dst) {
    int i = blockIdx.x * 256 + threadIdx.x;
    if (i >= 64 * 320) return;
    int zc = i % 320, co = i / 320;
    int z = zc >> 5, c = zc & 31;
    dst[i] = __float2half(src[(c * 10 + z) * 64 + co]);
}

// ct1_w f32 [320][64][2][2] (ci=c*5+z) -> f16 [kq][co][zc=z*64+c]
__global__ __launch_bounds__(256) void cvt_ct1(const float* __restrict__ src,
                                               __half* __restrict__ dst) {
    int i = blockIdx.x * 256 + threadIdx.x;
    if (i >= 4 * 64 * 320) return;
    int zc = i % 320;
    int t  = i / 320;
    int co = t & 63;
    int kq = t >> 6;
    int z = zc >> 6, c = zc & 63;
    dst[i] = __float2half(src[((c * 5 + z) * 64 + co) * 4 + kq]);
}

// ---------------------------------------------------------------------------
// Rulebook inversion, TRANSPOSED: nbrT[k*cap + s] = g. Scatter-only.
__global__ __launch_bounds__(256) void build_nbr(const int* __restrict__ g,
                                                 const int* __restrict__ s,
                                                 int* __restrict__ nbrT,
                                                 int P, int cap) {
    int i = blockIdx.x * 256 + threadIdx.x;
    if (i >= 27 * P) return;
    int k = i / P, p = i - k * P;
    int sv = s[(size_t)k * P + p];
    if (sv >= cap) return;              // dummy pair
    nbrT[(size_t)k * cap + sv] = g[(size_t)k * P + p];
}

// ---------------------------------------------------------------------------
// n_act via binary search on the coords pad boundary (z == Zdim marks pad).
__global__ __launch_bounds__(128) void find_nact(const int* __restrict__ c0,
                                                 const int* __restrict__ c1,
                                                 int* __restrict__ nA) {
    int t = threadIdx.x;
    if (t == 0) {
        int lo = 0, hi = CAP0C;
        while (lo < hi) {
            int mid = (lo + hi) >> 1;
            if (c0[4 * mid + 1] >= ZD) hi = mid; else lo = mid + 1;
        }
        nA[0] = lo;
    } else if (t == 64) {
        int lo = 0, hi = CAP1C;
        while (lo < hi) {
            int mid = (lo + hi) >> 1;
            if (c1[4 * mid + 1] >= Z1D) hi = mid; else lo = mid + 1;
        }
        nA[1] = lo;
    }
}

// voxel -> sparse-row index (pad coords have z == Zdim, dropped like JAX OOB)
__global__ __launch_bounds__(256) void build_vox(const int* __restrict__ coords,
                                                 int* __restrict__ v2r,
                                                 int cap, int Zdim, int Ydim, int Xdim) {
    int r = blockIdx.x * 256 + threadIdx.x;
    if (r >= cap) return;
    int b = coords[4*r], z = coords[4*r+1], y = coords[4*r+2], x = coords[4*r+3];
    if (z >= Zdim) return;
    v2r[(((size_t)b * Zdim + z) * Ydim + y) * Xdim + x] = r;
}

// ---------------------------------------------------------------------------
// Implicit-GEMM sparse conv via f16 MFMA 16x16x32, + BN + ReLU.
// v18 structure UNCHANGED (frozen until spconv counters resurface).
template <int CIN, int COUT>
__global__ __launch_bounds__(256) void spconv_reg(const __half* __restrict__ f,
                                                  const __half* __restrict__ wt,
                                                  const float* __restrict__ bnp,
                                                  const int* __restrict__ nbrT,
                                                  __half* __restrict__ fout,
                                                  int ncap,
                                                  const int* __restrict__ nA) {
    constexpr int NT = COUT / 16;       // 16-col output tiles
    constexpr int KT = CIN / 32;        // K=32 MFMA steps per k-offset
    constexpr int NCHUNK = CIN / 8;     // 16B chunks per weight row
    constexpr int MASK = NCHUNK - 1;
    constexpr int LCH  = (NCHUNK == 8) ? 3 : 2;
    constexpr int TILE_H = COUT * CIN;  // halves per weight tile
    constexpr int TB = TILE_H * 2 / 256; // stage bytes per thread (8/16/32)
    constexpr int OST_H = 4 * 32 * COUT;
    constexpr int SH_H = (2 * TILE_H > OST_H) ? 2 * TILE_H : OST_H;
    __shared__ __align__(16) __half S[SH_H];

    int tid = threadIdx.x;
    int wv = tid >> 6, lane = tid & 63;
    int quad = lane >> 4, l16 = lane & 15;

    // interleaved-group XCD swizzle (live-prefix-safe, bijective)
    int bid = blockIdx.x;
    int nfull = (int)gridDim.x & ~63;
    int sb;
    if (bid < nfull) {
        int grp = bid >> 6, w = bid & 63;
        sb = grp * 64 + (w & 7) * 8 + (w >> 3);
    } else {
        sb = bid;
    }

    // dead-block early exit: rows >= n_act have no pairs for any k
    if (sb * 128 >= *nA) return;

    int m0 = sb * 128 + wv * 32;       // wave's first output row
    int r0 = m0 + l16;                 // this lane's row for m=0
    int r1 = m0 + 16 + l16;            // this lane's row for m=1
    bool ok0 = r0 < ncap, ok1 = r1 < ncap;

    f32x4 acc[2][NT] = {};

    // index pipeline depth 2
    int gC0 = ok0 ? nbrT[r0] : -1;
    int gC1 = ok1 ? nbrT[r1] : -1;
    int gN0 = ok0 ? nbrT[(size_t)ncap + r0] : -1;
    int gN1 = ok1 ? nbrT[(size_t)ncap + r1] : -1;
    bool anyC = __ballot((gC0 >= 0) || (gC1 >= 0)) != 0ull;
    bool ever = false;

    // ---- feature prologue: gather k=0 rows into registers ----
    f16x8 aC0[KT], aC1[KT];
#pragma unroll
    for (int kt = 0; kt < KT; ++kt) {
        uint4 z4 = {0u,0u,0u,0u};
        aC0[kt] = *(f16x8*)&z4;
        aC1[kt] = *(f16x8*)&z4;
    }
    if (anyC) {
        const __half* p0 = f + (size_t)((gC0 < 0) ? 0 : gC0) * CIN + quad * 8;
        const __half* p1 = f + (size_t)((gC1 < 0) ? 0 : gC1) * CIN + quad * 8;
#pragma unroll
        for (int kt = 0; kt < KT; ++kt) {
            uint4 u0 = {0u,0u,0u,0u}, u1 = {0u,0u,0u,0u};
            if (gC0 >= 0) u0 = *(const uint4*)(p0 + kt * 32);
            if (gC1 >= 0) u1 = *(const uint4*)(p1 + kt * 32);
            aC0[kt] = *(f16x8*)&u0;
            aC1[kt] = *(f16x8*)&u1;
        }
    }

    // ---- weight prologue: stage tile k=0 into buffer 0 ----
    {
        const char* src = (const char*)(wt) + tid * TB;
        if constexpr (TB == 32) {
            uint4 w0 = *(const uint4*)src;
            uint4 w1 = *(const uint4*)(src + 16);
            int p0 = tid * 2;
#pragma unroll
            for (int j = 0; j < 2; ++j) {
                int p = p0 + j;
                int row = p >> LCH, c = p & MASK;
                *(uint4*)(S + (row * NCHUNK + (c ^ (row & MASK))) * 8) = (j ? w1 : w0);
            }
        } else if constexpr (TB == 16) {
            uint4 w0 = *(const uint4*)src;
            int p = tid;
            int row = p >> LCH, c = p & MASK;
            *(uint4*)(S + (row * NCHUNK + (c ^ (row & MASK))) * 8) = w0;
        } else {
            uint2 w0 = *(const uint2*)src;
            int p = tid >> 1, half = tid & 1;
            int row = p >> LCH, c = p & MASK;
            *(uint2*)(S + (row * NCHUNK + (c ^ (row & MASK))) * 8 + half * 4) = w0;
        }
    }
    __syncthreads();   // prologue barrier: full drain is fine (once)

#pragma unroll 1
    for (int k = 0; k < 27; ++k) {
        // (1) idx k+2 (oldest in-flight)
        int gNN0 = -1, gNN1 = -1;
        if (k + 2 < 27) {
            if (ok0) gNN0 = nbrT[(size_t)(k + 2) * ncap + r0];
            if (ok1) gNN1 = nbrT[(size_t)(k + 2) * ncap + r1];
        }
        // (2) gather k+1 rows -> aN (vmcnt stays COUNTED across the barrier)
        bool anyN = __ballot((gN0 >= 0) || (gN1 >= 0)) != 0ull;
        f16x8 aN0[KT], aN1[KT];
#pragma unroll
        for (int kt = 0; kt < KT; ++kt) {
            uint4 z4 = {0u,0u,0u,0u};
            aN0[kt] = *(f16x8*)&z4;
            aN1[kt] = *(f16x8*)&z4;
        }
        if (anyN) {
            const __half* p0 = f + (size_t)((gN0 < 0) ? 0 : gN0) * CIN + quad * 8;
            const __half* p1 = f + (size_t)((gN1 < 0) ? 0 : gN1) * CIN + quad * 8;
#pragma unroll
            for (int kt = 0; kt < KT; ++kt) {
                uint4 u0 = {0u,0u,0u,0u}, u1 = {0u,0u,0u,0u};
                if (gN0 >= 0) u0 = *(const uint4*)(p0 + kt * 32);
                if (gN1 >= 0) u1 = *(const uint4*)(p1 + kt * 32);
                aN0[kt] = *(f16x8*)&u0;
                aN1[kt] = *(f16x8*)&u1;
            }
        }
        // (3) stage loads for weight tile k+1 -> regs
        bool doStage = (k + 1 < 27);
        uint4 w0{}, w1{}; uint2 w2{};
        if (doStage) {
            const char* src = (const char*)(wt + (size_t)(k + 1) * TILE_H) + tid * TB;
            if constexpr (TB == 32)      { w0 = *(const uint4*)src; w1 = *(const uint4*)(src + 16); }
            else if constexpr (TB == 16) { w0 = *(const uint4*)src; }
            else                         { w2 = *(const uint2*)src; }
        }
        // (4) ds_read B + (5) MFMA on aC (ready since previous barrier)
        if (anyC) {
            ever = true;
            const __half* Wb = S + (k & 1) * TILE_H;
#pragma unroll
            for (int kt = 0; kt < KT; ++kt) {
#pragma unroll
                for (int nt = 0; nt < NT; ++nt) {
                    int row = nt * 16 + l16;
                    int c   = kt * 4 + quad;
                    f16x8 b = *(const f16x8*)(Wb + (row * NCHUNK + (c ^ (row & MASK))) * 8);
                    acc[0][nt] = __builtin_amdgcn_mfma_f32_16x16x32_f16(aC0[kt], b, acc[0][nt], 0, 0, 0);
                    acc[1][nt] = __builtin_amdgcn_mfma_f32_16x16x32_f16(aC1[kt], b, acc[1][nt], 0, 0, 0);
                }
            }
        }
        // (6) ds_write staging into the other buffer
        if (doStage) {
            __half* dst = S + ((k + 1) & 1) * TILE_H;
            if constexpr (TB == 32) {
                int p0 = tid * 2;
#pragma unroll
                for (int j = 0; j < 2; ++j) {
                    int p = p0 + j;
                    int row = p >> LCH, c = p & MASK;
                    *(uint4*)(dst + (row * NCHUNK + (c ^ (row & MASK))) * 8) = (j ? w1 : w0);
                }
            } else if constexpr (TB == 16) {
                int p = tid;
                int row = p >> LCH, c = p & MASK;
                *(uint4*)(dst + (row * NCHUNK + (c ^ (row & MASK))) * 8) = w0;
            } else {
                int p = tid >> 1, half = tid & 1;
                int row = p >> LCH, c = p & MASK;
                *(uint2*)(dst + (row * NCHUNK + (c ^ (row & MASK))) * 8 + half * 4) = w2;
            }
        }
        // counted-wait barrier: drain LDS only; vmcnt stays in flight.
        asm volatile("s_waitcnt lgkmcnt(0)" ::: "memory");
        __builtin_amdgcn_s_barrier();
        // rotate pipelines
#pragma unroll
        for (int kt = 0; kt < KT; ++kt) { aC0[kt] = aN0[kt]; aC1[kt] = aN1[kt]; }
        anyC = anyN;
        gC0 = gN0; gC1 = gN1; gN0 = gNN0; gN1 = gNN1;
    }

    // epilogue: BN + ReLU -> wave-private LDS (weight bufs dead) -> store.
    if (!ever) return;
    __half* O = S + wv * (32 * COUT);
#pragma unroll
    for (int nt = 0; nt < NT; ++nt) {
        int co = nt * 16 + l16;
        float g = bnp[co], b = bnp[COUT + co];
        float mn = bnp[2*COUT + co], vv = bnp[3*COUT + co];
        float s  = g * rsqrtf(vv + 1e-5f);
        float sh = b - mn * s;
#pragma unroll
        for (int m = 0; m < 2; ++m)
#pragma unroll
            for (int r_ = 0; r_ < 4; ++r_) {
                int row = m * 16 + quad * 4 + r_;
                O[row * COUT + co] = __float2half(fmaxf(acc[m][nt][r_] * s + sh, 0.f));
            }
    }
    constexpr int OCH = COUT / 8;              // 16B chunks per out row
#pragma unroll
    for (int j = 0; j < 32 * OCH / 64; ++j) {
        int idx = j * 64 + lane;
        int r = idx / OCH, c = idx % OCH;
        if (m0 + r < ncap)
            *(uint4*)(fout + (size_t)(m0 + r) * COUT + c * 8) =
                *(const uint4*)(O + r * COUT + c * 8);
    }
}

// ---------------------------------------------------------------------------
// BEV head 0 (v19 form, UNCHANGED this round).
__global__ __launch_bounds__(256) void bev0_mfma(const __half* __restrict__ f0,
                                                 const __half* __restrict__ wtT,  // [64][320] zc=z*32+c
                                                 const float* __restrict__ bias,
                                                 const float* __restrict__ bnp,
                                                 const int* __restrict__ v2r,
                                                 float* __restrict__ out) {
    __shared__ float Ot[64][66];
    int tid = threadIdx.x;
    int y = blockIdx.x / 11, x0 = (blockIdx.x % 11) * 64;
    int wv = tid >> 6, lane = tid & 63;
    int quad = lane >> 4, l16 = lane & 15;

    // v2r preload: 2 m-tiles x 10 z-slices (static-indexed -> registers)
    int rz[2][10];
#pragma unroll
    for (int m = 0; m < 2; ++m) {
        int row = wv * 32 + m * 16 + l16;
        int b = row & 1, p = row >> 1;
#pragma unroll
        for (int z = 0; z < 10; ++z)
            rz[m][z] = v2r[((b * ZD + z) * YD + y) * XD + x0 + p];
    }

    f32x4 acc[2][4] = {};
    // prologue: load fragments for ks = 0
    f16x8 aC[2], bC[4];
#pragma unroll
    for (int m = 0; m < 2; ++m) {
        uint4 u = {0u,0u,0u,0u};
        int r = rz[m][0];
        if (r >= 0) u = *(const uint4*)(f0 + (size_t)r * 32 + quad * 8);
        aC[m] = *(f16x8*)&u;
    }
#pragma unroll
    for (int nt = 0; nt < 4; ++nt)
        bC[nt] = *(const f16x8*)(wtT + (size_t)(nt * 16 + l16) * 320 + quad * 8);

#pragma unroll
    for (int ks = 0; ks < 10; ++ks) {
        // prefetch ks+1 fragments
        f16x8 aN[2], bN[4];
        if (ks + 1 < 10) {
#pragma unroll
            for (int m = 0; m < 2; ++m) {
                uint4 u = {0u,0u,0u,0u};
                int r = rz[m][ks + 1];
                if (r >= 0) u = *(const uint4*)(f0 + (size_t)r * 32 + quad * 8);
                aN[m] = *(f16x8*)&u;
            }
#pragma unroll
            for (int nt = 0; nt < 4; ++nt)
                bN[nt] = *(const f16x8*)(wtT + (size_t)(nt * 16 + l16) * 320 + (ks + 1) * 32 + quad * 8);
        } else {
            uint4 z4 = {0u,0u,0u,0u};
#pragma unroll
            for (int m = 0; m < 2; ++m) aN[m] = *(f16x8*)&z4;
#pragma unroll
            for (int nt = 0; nt < 4; ++nt) bN[nt] = *(f16x8*)&z4;
        }
#pragma unroll
        for (int nt = 0; nt < 4; ++nt) {
            acc[0][nt] = __builtin_amdgcn_mfma_f32_16x16x32_f16(aC[0], bC[nt], acc[0][nt], 0, 0, 0);
            acc[1][nt] = __builtin_amdgcn_mfma_f32_16x16x32_f16(aC[1], bC[nt], acc[1][nt], 0, 0, 0);
        }
        aC[0] = aN[0]; aC[1] = aN[1];
#pragma unroll
        for (int nt = 0; nt < 4; ++nt) bC[nt] = bN[nt];
    }

    // BN + ReLU in-place (channels are lane-local: co = nt*16 + l16)
#pragma unroll
    for (int nt = 0; nt < 4; ++nt) {
        int co = nt * 16 + l16;
        float s  = bnp[co] * rsqrtf(bnp[192 + co] + 1e-5f);
        float sh = (bias[co] - bnp[128 + co]) * s + bnp[64 + co];
#pragma unroll
        for (int m = 0; m < 2; ++m)
#pragma unroll
            for (int r_ = 0; r_ < 4; ++r_)
                acc[m][nt][r_] = fmaxf(acc[m][nt][r_] * s + sh, 0.f);
    }

    // lane-local pair attention
#pragma unroll
    for (int m = 0; m < 2; ++m)
#pragma unroll
        for (int jj = 0; jj < 2; ++jj) {
            float s00 = 0.f, s01 = 0.f;
#pragma unroll
            for (int nt = 0; nt < 4; ++nt) {
                float xv0 = acc[m][nt][2 * jj], xv1 = acc[m][nt][2 * jj + 1];
                s00 += xv0 * xv0;
                s01 += xv0 * xv1;
            }
#pragma unroll
            for (int o = 8; o > 0; o >>= 1) {
                s00 += __shfl_xor(s00, o);
                s01 += __shfl_xor(s01, o);
            }
            float a0 = s00 * 0.125f, a1 = s01 * 0.125f;
            float mx = fmaxf(a0, a1);
            float e0 = expf(a0 - mx), e1 = expf(a1 - mx);
            float inv = 1.f / (e0 + e1);
            int pl = wv * 16 + m * 8 + quad * 2 + jj;
#pragma unroll
            for (int nt = 0; nt < 4; ++nt)
                Ot[nt * 16 + l16][pl] =
                    (e0 * acc[m][nt][2 * jj] + e1 * acc[m][nt][2 * jj + 1]) * inv;
        }
    __syncthreads();

#pragma unroll
    for (int i = 0; i < 16; ++i) {
        int idx = i * 256 + tid;
        int co = idx >> 6, px = idx & 63;
        out[(size_t)co * HWOUT + (size_t)y * XD + x0 + px] = Ot[co][px];
    }
}

// ---------------------------------------------------------------------------
// BEV head 1, v20: B WEIGHTS THROUGH LDS.
// R14 diagnosis: v19's reg double-buffer produced IDENTICAL codegen
// (VGPR 72, dur 97us) -- the scheduler re-sinks loads to uses; source-level
// pipelines that don't change memory class get undone. bev0 (40 B-loads)
// = half bev1 (80 B-loads) in time => the 16-line-divergent, latency-
// exposed B path scales the kernel. Fix: stage the 40KB wk tile in LDS
// (padded rows, AST=328 pattern -- balanced banks for the b128 reads),
// per kx: 10 coalesced uint4 stage loads/thread + barrier + ds_read-fed
// MFMA. ~8x fewer TA lines, ds-latency instead of L2-latency.
__global__ __launch_bounds__(256) void bev1_mfma(const __half* __restrict__ f1,
                                                 const __half* __restrict__ wtT,  // [4][64][320] zc=z*64+c
                                                 const float* __restrict__ bias,
                                                 const float* __restrict__ bnp,
                                                 const int* __restrict__ v2r,
                                                 float* __restrict__ out) {
    constexpr int WST = 328;                        // padded row (halves)
    __shared__ __align__(16) __half Wl[64 * WST];   // 41,984 B
    __shared__ float Ot[64][66];                    // 16,896 B
    int tid = threadIdx.x;
    int bid = blockIdx.x;
    int ky = bid & 1;
    int t  = bid >> 1;
    int iy = t / 11, j0 = (t % 11) * 32;
    int wv = tid >> 6, lane = tid & 63;
    int quad = lane >> 4, l16 = lane & 15;

    int row = wv * 16 + l16;
    int b = row & 1, p = row >> 1;
    int rz[5];
#pragma unroll
    for (int z = 0; z < 5; ++z)
        rz[z] = v2r[((b * Z1D + z) * Y1D + iy) * X1D + j0 + p];

    // gather all 10 A fragments once (latency overlaps staging+barrier)
    f16x8 a[10];
#pragma unroll
    for (int ks = 0; ks < 10; ++ks) {
        int z = ks >> 1, hf = ks & 1;
        uint4 u = {0u,0u,0u,0u};
        int r = rz[z];
        if (r >= 0) u = *(const uint4*)(f1 + (size_t)r * 64 + hf * 32 + quad * 8);
        a[ks] = *(f16x8*)&u;
    }

    f32x4 acc[2][4] = {};
#pragma unroll 1
    for (int kx = 0; kx < 2; ++kx) {
        const __half* wk = wtT + (size_t)(ky * 2 + kx) * 64 * 320;
        if (kx) __syncthreads();    // all waves done reading Wl (kx=0)
        // stage wk -> Wl (64 rows x 320 halves, padded to 328):
        // 2560 uint4 chunks / 256 threads = 10 each, coalesced.
#pragma unroll
        for (int c = 0; c < 10; ++c) {
            int idx = c * 256 + tid;
            int r_ = idx / 40, col = idx % 40;
            uint4 v = *(const uint4*)(wk + r_ * 320 + col * 8);
            *(uint4*)(Wl + r_ * WST + col * 8) = v;
        }
        __syncthreads();
        // MFMA: A from regs, B from LDS (ds_read_b128, balanced banks)
#pragma unroll
        for (int ks = 0; ks < 10; ++ks)
#pragma unroll
            for (int nt = 0; nt < 4; ++nt) {
                f16x8 bf = *(const f16x8*)(Wl + (nt * 16 + l16) * WST + ks * 32 + quad * 8);
                acc[kx][nt] = __builtin_amdgcn_mfma_f32_16x16x32_f16(a[ks], bf, acc[kx][nt], 0, 0, 0);
            }
    }

    // BN + ReLU in-place, then lane-local pair attention per kx
#pragma unroll
    for (int kx = 0; kx < 2; ++kx) {
#pragma unroll
        for (int nt = 0; nt < 4; ++nt) {
            int co = nt * 16 + l16;
            float s  = bnp[co] * rsqrtf(bnp[192 + co] + 1e-5f);
            float sh = (bias[co] - bnp[128 + co]) * s + bnp[64 + co];
#pragma unroll
            for (int r_ = 0; r_ < 4; ++r_)
                acc[kx][nt][r_] = fmaxf(acc[kx][nt][r_] * s + sh, 0.f);
        }
#pragma unroll
        for (int jj = 0; jj < 2; ++jj) {
            float s00 = 0.f, s01 = 0.f;
#pragma unroll
            for (int nt = 0; nt < 4; ++nt) {
                float xv0 = acc[kx][nt][2 * jj], xv1 = acc[kx][nt][2 * jj + 1];
                s00 += xv0 * xv0;
                s01 += xv0 * xv1;
            }
#pragma unroll
            for (int o = 8; o > 0; o >>= 1) {
                s00 += __shfl_xor(s00, o);
                s01 += __shfl_xor(s01, o);
            }
            float a0 = s00 * 0.125f, a1 = s01 * 0.125f;
            float mx = fmaxf(a0, a1);
            float e0 = expf(a0 - mx), e1 = expf(a1 - mx);
            float inv = 1.f / (e0 + e1);
            int pl = wv * 8 + quad * 2 + jj;    // 0..31
#pragma unroll
            for (int nt = 0; nt < 4; ++nt)
                Ot[nt * 16 + l16][2 * pl + kx] =
                    (e0 * acc[kx][nt][2 * jj] + e1 * acc[kx][nt][2 * jj + 1]) * inv;
        }
    }
    __syncthreads();

    int yo = 2 * iy + ky;
#pragma unroll
    for (int i = 0; i < 16; ++i) {
        int idx = i * 256 + tid;
        int co = idx >> 6, xx = idx & 63;
        out[(size_t)co * HWOUT + (size_t)yo * XD + 2 * j0 + xx] = Ot[co][xx];
    }
}

// ---------------------------------------------------------------------------
extern "C" void kernel_launch(void* const* d_in, const int* in_sizes, int n_in,
                              void* d_out, int out_size, void* d_ws, size_t ws_size,
                              hipStream_t stream) {
    const float* sp    = (const float*)d_in[0];
    const float* w_in  = (const float*)d_in[1];
    const float* w0    = (const float*)d_in[2];
    const float* bnp0  = (const float*)d_in[3];
    const float* w0a   = (const float*)d_in[4];
    const float* bnp0a = (const float*)d_in[5];
    const float* w0b   = (const float*)d_in[6];
    const float* bnp0b = (const float*)d_in[7];
    const float* w1    = (const float*)d_in[8];
    const float* bnp1  = (const float*)d_in[9];
    const float* w1a   = (const float*)d_in[10];
    const float* bnp1a = (const float*)d_in[11];
    const float* w1b   = (const float*)d_in[12];
    const float* bnp1b = (const float*)d_in[13];
    const float* ct0w  = (const float*)d_in[14];
    const float* ct0b  = (const float*)d_in[15];
    const float* bnt0  = (const float*)d_in[16];
    const float* ct1w  = (const float*)d_in[17];
    const float* ct1b  = (const float*)d_in[18];
    const float* bnt1  = (const float*)d_in[19];
    const int* coords0 = (const int*)d_in[20];
    const int* coords1 = (const int*)d_in[21];
    const int* g0 = (const int*)d_in[22];
    const int* s0 = (const int*)d_in[23];
    const int* ga = (const int*)d_in[24];
    const int* sa = (const int*)d_in[25];
    const int* g1 = (const int*)d_in[26];
    const int* s1 = (const int*)d_in[27];
    const int* gb = (const int*)d_in[28];
    const int* sb = (const int*)d_in[29];
    float* out = (float*)d_out;

    // -------- workspace carve --------
    __half* fInH = (__half*)d_ws;
    __half* R1h  = fInH + 640000;
    __half* R2h  = R1h + 22528000;
    __half* wt0  = R2h + 22528000;
    __half* wt0a = wt0  + 27648;
    __half* wt0b = wt0a + 27648;
    __half* wt1  = wt0b + 27648;          // [27][64][32]
    __half* wt1a = wt1  + 55296;          // [27][64][64]
    __half* wt1b = wt1a + 110592;
    __half* wtT0 = wt1b + 110592;         // [64][320]
    __half* wtT1 = wtT0 + 20480;          // [4][64][320]
    int*   nbrT = (int*)(wtT1 + 81920);   // 27*CAP0C ints = 14,580,000
    int*   v2r0 = nbrT;                          // 2,816,000 ints (aliases)
    int*   v2r1 = nbrT + 2816000;                //   352,000 ints (aliases)
    int*   nAct = nbrT + 14580000;               // 2 ints, beyond nbrT region

    // 0) weight conversion + n_act (binary search on coords pad boundary)
    find_nact<<<1, 128, 0, stream>>>(coords0, coords1, nAct);
    cvt_w<<<(27*32*32 + 255) / 256, 256, 0, stream>>>(w0,  wt0,  32, 32);
    cvt_w<<<(27*32*32 + 255) / 256, 256, 0, stream>>>(w0a, wt0a, 32, 32);
    cvt_w<<<(27*32*32 + 255) / 256, 256, 0, stream>>>(w0b, wt0b, 32, 32);
    cvt_w<<<(27*32*64 + 255) / 256, 256, 0, stream>>>(w1,  wt1,  32, 64);
    cvt_w<<<(27*64*64 + 255) / 256, 256, 0, stream>>>(w1a, wt1a, 64, 64);
    cvt_w<<<(27*64*64 + 255) / 256, 256, 0, stream>>>(w1b, wt1b, 64, 64);
    cvt_ct0<<<(64*320 + 255) / 256, 256, 0, stream>>>(ct0w, wtT0);
    cvt_ct1<<<(4*64*320 + 255) / 256, 256, 0, stream>>>(ct1w, wtT1);

    // 1) input channel lift (f16 rows out)
    gemm_in<<<(N_PTS_IN * 8 + 255) / 256, 256, 0, stream>>>(sp, w_in, fInH);

    // 2) conv0 (stride-1 spconv, 32->32): fInH -> R1h
    hipMemsetAsync(nbrT, 0xFF, (size_t)CAP0C * 27 * 4, stream);
    build_nbr<<<(27 * N_PTS_IN + 255) / 256, 256, 0, stream>>>(g0, s0, nbrT, N_PTS_IN, CAP0C);
    spconv_reg<32, 32><<<(CAP0C + 127) / 128, 256, 0, stream>>>(fInH, wt0, bnp0, nbrT, R1h, CAP0C, nAct + 0);

    // 3) subm a/b (32->32), shared rulebook: R1h -> R2h -> R1h
    hipMemsetAsync(nbrT, 0xFF, (size_t)CAP0C * 27 * 4, stream);
    build_nbr<<<(27 * CAP0C + 255) / 256, 256, 0, stream>>>(ga, sa, nbrT, CAP0C, CAP0C);
    spconv_reg<32, 32><<<(CAP0C + 127) / 128, 256, 0, stream>>>(R1h, wt0a, bnp0a, nbrT, R2h, CAP0C, nAct + 0);
    spconv_reg<32, 32><<<(CAP0C + 127) / 128, 256, 0, stream>>>(R2h, wt0b, bnp0b, nbrT, R1h, CAP0C, nAct + 0);

    // 4) BEV head 0 (reads R1h) -> out channels [0,64)
    hipMemsetAsync(v2r0, 0xFF, (size_t)2816000 * 4, stream);
    build_vox<<<(CAP0C + 255) / 256, 256, 0, stream>>>(coords0, v2r0, CAP0C, ZD, YD, XD);
    bev0_mfma<<<YD * 11, 256, 0, stream>>>(R1h, wtT0, ct0b, bnt0, v2r0, out);

    // 5) conv1 (stride-2 spconv, 32->64): R1h -> R2h
    hipMemsetAsync(nbrT, 0xFF, (size_t)CAP1C * 27 * 4, stream);
    build_nbr<<<(27 * CAP0C + 255) / 256, 256, 0, stream>>>(g1, s1, nbrT, CAP0C, CAP1C);
    spconv_reg<32, 64><<<(CAP1C + 127) / 128, 256, 0, stream>>>(R1h, wt1, bnp1, nbrT, R2h, CAP1C, nAct + 1);

    // 6) subm 1a/1b (64->64), shared rulebook: R2h -> R1h -> R2h
    hipMemsetAsync(nbrT, 0xFF, (size_t)CAP1C * 27 * 4, stream);
    build_nbr<<<(27 * CAP1C + 255) / 256, 256, 0, stream>>>(gb, sb, nbrT, CAP1C, CAP1C);
    spconv_reg<64, 64><<<(CAP1C + 127) / 128, 256, 0, stream>>>(R2h, wt1a, bnp1a, nbrT, R1h, CAP1C, nAct + 1);
    spconv_reg<64, 64><<<(CAP1C + 127) / 128, 256, 0, stream>>>(R1h, wt1b, bnp1b, nbrT, R2h, CAP1C, nAct + 1);

    // 7) BEV head 1 (reads R2h) -> out channels [64,128)
    hipMemsetAsync(v2r1, 0xFF, (size_t)352000 * 4, stream);
    build_vox<<<(CAP1C + 255) / 256, 256, 0, stream>>>(coords1, v2r1, CAP1C, Z1D, Y1D, X1D);
    bev1_mfma<<<Y1D * 11 * 2, 256, 0, stream>>>(R2h, wtT1, ct1b, bnt1, v2r1, out + (size_t)64 * HWOUT);
}